// Round 9
// baseline (653.616 us; speedup 1.0000x reference)
//
#include <hip/hip_runtime.h>
#include <math.h>

#define BB 512
#define NN 128
#define CAND_CAP (512*384)
#define LIMIT 2048
#define EQCAP 16384
#define NBIN1 4096

// ---------------- mask decode (int32 / byte / float32 robustness) -------------
__device__ inline bool read_mask(const void* p, int i, int mode){
  if (mode == 0) return ((const int*)p)[i] != 0;
  if (mode == 1) return ((const unsigned char*)p)[i] != 0;
  return ((const float*)p)[i] != 0.0f;
}

__device__ inline float fast_rcp(float x){ return __builtin_amdgcn_rcpf(x); }
__device__ inline float fast_rsq(float x){ return __builtin_amdgcn_rsqf(x); }

__device__ inline void top3_update(float v, float& a1, float& a2, float& a3){
  if (v > a1){ a3=a2; a2=a1; a1=v; }
  else if (v > a2){ a3=a2; a2=v; }
  else if (v > a3){ a3=v; }
}

// ---------------- fp32 Kabsch, SCALAR-ONLY interface --------------------------
__device__ __forceinline__ void kabsch9(
    float h00, float h01, float h02,
    float h10, float h11, float h12,
    float h20, float h21, float h22,
    float& r00, float& r01, float& r02,
    float& r10, float& r11, float& r12,
    float& r20, float& r21, float& r22)
{
  float s00 = h00*h00 + h10*h10 + h20*h20;
  float s01 = h00*h01 + h10*h11 + h20*h21;
  float s02 = h00*h02 + h10*h12 + h20*h22;
  float s11 = h01*h01 + h11*h11 + h21*h21;
  float s12 = h01*h02 + h11*h12 + h21*h22;
  float s22 = h02*h02 + h12*h12 + h22*h22;
  float v00=1.f,v01=0.f,v02=0.f, v10=0.f,v11=1.f,v12=0.f, v20=0.f,v21=0.f,v22=1.f;
  for (int sweep = 0; sweep < 10; sweep++){
    float off  = s01*s01 + s02*s02 + s12*s12;
    float base = s00*s00 + s11*s11 + s22*s22;
    if (off <= base*1e-14f + 1e-36f) break;
    if (fabsf(s01) > 1e-30f){
      float tau = (s11 - s00) * fast_rcp(2.f*s01);
      float tt  = (tau >= 0.f ? 1.f : -1.f) * fast_rcp(fabsf(tau) + sqrtf(1.f + tau*tau));
      float c = fast_rsq(1.f + tt*tt), s = tt*c;
      float n00 = c*c*s00 - 2.f*c*s*s01 + s*s*s11;
      float n11 = s*s*s00 + 2.f*c*s*s01 + c*c*s11;
      float n02 = c*s02 - s*s12;
      float n12 = s*s02 + c*s12;
      s00=n00; s11=n11; s01=0.f; s02=n02; s12=n12;
      float a,b;
      a=v00; b=v01; v00=c*a-s*b; v01=s*a+c*b;
      a=v10; b=v11; v10=c*a-s*b; v11=s*a+c*b;
      a=v20; b=v21; v20=c*a-s*b; v21=s*a+c*b;
    }
    if (fabsf(s02) > 1e-30f){
      float tau = (s22 - s00) * fast_rcp(2.f*s02);
      float tt  = (tau >= 0.f ? 1.f : -1.f) * fast_rcp(fabsf(tau) + sqrtf(1.f + tau*tau));
      float c = fast_rsq(1.f + tt*tt), s = tt*c;
      float n00 = c*c*s00 - 2.f*c*s*s02 + s*s*s22;
      float n22 = s*s*s00 + 2.f*c*s*s02 + c*c*s22;
      float n01 = c*s01 - s*s12;
      float n12 = s*s01 + c*s12;
      s00=n00; s22=n22; s02=0.f; s01=n01; s12=n12;
      float a,b;
      a=v00; b=v02; v00=c*a-s*b; v02=s*a+c*b;
      a=v10; b=v12; v10=c*a-s*b; v12=s*a+c*b;
      a=v20; b=v22; v20=c*a-s*b; v22=s*a+c*b;
    }
    if (fabsf(s12) > 1e-30f){
      float tau = (s22 - s11) * fast_rcp(2.f*s12);
      float tt  = (tau >= 0.f ? 1.f : -1.f) * fast_rcp(fabsf(tau) + sqrtf(1.f + tau*tau));
      float c = fast_rsq(1.f + tt*tt), s = tt*c;
      float n11 = c*c*s11 - 2.f*c*s*s12 + s*s*s22;
      float n22 = s*s*s11 + 2.f*c*s*s12 + c*c*s22;
      float n01 = c*s01 - s*s02;
      float n02 = s*s01 + c*s02;
      s11=n11; s22=n22; s12=0.f; s01=n01; s02=n02;
      float a,b;
      a=v01; b=v02; v01=c*a-s*b; v02=s*a+c*b;
      a=v11; b=v12; v11=c*a-s*b; v12=s*a+c*b;
      a=v21; b=v22; v21=c*a-s*b; v22=s*a+c*b;
    }
  }
  float l0=s00, l1=s11, l2=s22;
  float a0=v00, a1=v10, a2=v20;
  float b0=v01, b1=v11, b2=v21;
  float c0=v02, c1=v12, c2=v22;
  if (l0 < l1){ float x; x=l0;l0=l1;l1=x; x=a0;a0=b0;b0=x; x=a1;a1=b1;b1=x; x=a2;a2=b2;b2=x; }
  if (l0 < l2){ float x; x=l0;l0=l2;l2=x; x=a0;a0=c0;c0=x; x=a1;a1=c1;c1=x; x=a2;a2=c2;c2=x; }
  if (l1 < l2){ float x; x=l1;l1=l2;l2=x; x=b0;b0=c0;c0=x; x=b1;b1=c1;c1=x; x=b2;b2=c2;c2=x; }
  float sig0 = sqrtf(fmaxf(l0, 0.f));
  if (!(sig0 > 1e-12f)){
    r00=1.f; r01=0.f; r02=0.f; r10=0.f; r11=1.f; r12=0.f; r20=0.f; r21=0.f; r22=1.f;
    return;
  }
  float u0x = h00*a0 + h01*a1 + h02*a2;
  float u0y = h10*a0 + h11*a1 + h12*a2;
  float u0z = h20*a0 + h21*a1 + h22*a2;
  float in0 = fast_rsq(u0x*u0x + u0y*u0y + u0z*u0z);
  u0x *= in0; u0y *= in0; u0z *= in0;
  float u1x = h00*b0 + h01*b1 + h02*b2;
  float u1y = h10*b0 + h11*b1 + h12*b2;
  float u1z = h20*b0 + h21*b1 + h22*b2;
  float dp = u1x*u0x + u1y*u0y + u1z*u0z;
  u1x -= dp*u0x; u1y -= dp*u0y; u1z -= dp*u0z;
  float d1 = u1x*u1x + u1y*u1y + u1z*u1z;
  if (sqrtf(d1) > sig0*1e-5f){
    float in1 = fast_rsq(d1);
    u1x *= in1; u1y *= in1; u1z *= in1;
  } else {
    float au0 = fabsf(u0x), au1 = fabsf(u0y), au2 = fabsf(u0z);
    float e0 = 0.f, e1 = 0.f, e2 = 0.f;
    if (au0 <= au1 && au0 <= au2) e0 = 1.f; else if (au1 <= au2) e1 = 1.f; else e2 = 1.f;
    float d2 = e0*u0x + e1*u0y + e2*u0z;
    u1x = e0 - d2*u0x; u1y = e1 - d2*u0y; u1z = e2 - d2*u0z;
    float nn = fast_rsq(u1x*u1x + u1y*u1y + u1z*u1z);
    u1x *= nn; u1y *= nn; u1z *= nn;
  }
  float u2x = u0y*u1z - u0z*u1y;
  float u2y = u0z*u1x - u0x*u1z;
  float u2z = u0x*u1y - u0y*u1x;
  float cxv = b1*c2 - b2*c1;
  float cyv = b2*c0 - b0*c2;
  float czv = b0*c1 - b1*c0;
  float detV = a0*cxv + a1*cyv + a2*czv;
  float dd = (detV >= 0.f) ? 1.f : -1.f;
  float w2x = dd*u2x, w2y = dd*u2y, w2z = dd*u2z;
  r00=a0*u0x + b0*u1x + c0*w2x;  r01=a0*u0y + b0*u1y + c0*w2y;  r02=a0*u0z + b0*u1z + c0*w2z;
  r10=a1*u0x + b1*u1x + c1*w2x;  r11=a1*u0y + b1*u1y + c1*w2y;  r12=a1*u0z + b1*u1z + c1*w2z;
  r20=a2*u0x + b2*u1x + c2*w2x;  r21=a2*u0y + b2*u1y + c2*w2y;  r22=a2*u0z + b2*u1z + c2*w2z;
}

// ---------------- K1a: column top-3 thresholds (tile-free, coalesced) ---------
__global__ __launch_bounds__(128) void k1a_kernel(
    const float* __restrict__ score, float* __restrict__ c3g)
{
  const int b = blockIdx.x, t = threadIdx.x;
  const float* col = score + (size_t)b*NN*NN + t;
  float a1=-1e30f, a2=-1e30f, a3=-1e30f;
#pragma unroll 8
  for (int n = 0; n < NN; n++){
    float v = col[n*NN];
    top3_update(v, a1, a2, a3);
  }
  c3g[b*NN + t] = a3;
}

// ---------------- K1b: wave-per-rows mutual top-3 + stats + candidates + hist -
// 256 threads = 4 waves; wave w owns rows [w*32, w*32+32). Lane l holds row
// elements at cols l and l+64 IN REGISTERS (single coalesced read of score).
__global__ __launch_bounds__(256) void k1b_kernel(
    const float* __restrict__ score, const float* __restrict__ refp,
    const float* __restrict__ srcp, const void* __restrict__ rmaskp,
    const void* __restrict__ smaskp, const float* __restrict__ c3g,
    int* hdr, float* cand_vals, int* cand_idx, int* hist,
    float* Hsr, int* pcount)
{
  __shared__ float srcsh[NN*3];
  __shared__ float refsh[NN*3];
  __shared__ float c3sh[NN];
  __shared__ unsigned char smk[NN], rmk[NN];
  __shared__ float candv[4][96];
  __shared__ int   candi[4][96];
  __shared__ int   wcnt[4];
  __shared__ float red[4][17];
  __shared__ int smode;
  const int b = blockIdx.x, t = threadIdx.x;
  const int w = t >> 6, l = t & 63;

  if (t < 64){
    unsigned v = ((const unsigned*)rmaskp)[t];
    bool n01 = !(v == 0u || v == 1u);
    bool nf  = !(v == 0u || v == 0x3F800000u);
    unsigned long long b01 = __ballot(n01), bf = __ballot(nf);
    if (t == 0) smode = (b01 == 0ull) ? 0 : ((bf == 0ull) ? 2 : 1);
  }
  if (t < 4) wcnt[t] = 0;
  for (int i = t; i < NN*3; i += 256){
    srcsh[i] = srcp[b*NN*3 + i];
    refsh[i] = refp[b*NN*3 + i];
  }
  if (t < NN) c3sh[t] = c3g[b*NN + t];
  __syncthreads();       // smode ready
  if (t < NN){
    int mode = smode;
    smk[t] = read_mask(smaskp, b*NN + t, mode) ? 1 : 0;
    rmk[t] = read_mask(rmaskp, b*NN + t, mode) ? 1 : 0;
  }
  __syncthreads();

  // per-lane stat accumulators (17)
  float q0=0.f,q1=0.f,q2=0.f,q3=0.f,q4=0.f,q5=0.f,q6=0.f,q7=0.f;
  float q8=0.f,q9=0.f,q10=0.f,q11=0.f,q12=0.f,q13=0.f,q14=0.f,q15=0.f,q16=0.f;

  const float* base = score + (size_t)b*NN*NN;
  for (int rr = 0; rr < 32; rr++){
    const int r = w*32 + rr;
    const float v0 = base[r*NN + l];
    const float v1 = base[r*NN + l + 64];
    // row top-3 via butterfly merge of sorted triples
    float a1 = fmaxf(v0, v1), a2 = fminf(v0, v1), a3 = -1e30f;
#pragma unroll
    for (int st = 0; st < 6; st++){
      const int mask = 1 << st;
      float o1 = __shfl_xor(a1, mask);
      float o2 = __shfl_xor(a2, mask);
      float o3 = __shfl_xor(a3, mask);
      float m1 = fmaxf(a1, o1);
      float m2 = fmaxf(fminf(a1, o1), fmaxf(a2, o2));
      float m3 = fmaxf(fmaxf(fminf(a1, o2), fminf(a2, o1)), fmaxf(a3, o3));
      a1 = m1; a2 = m2; a3 = m3;
    }
    const float r3 = a3;
    const bool rmv = rmk[r] != 0;
    const float rx = refsh[r*3+0], ry = refsh[r*3+1], rz = refsh[r*3+2];
    // element 0 (col l) and element 1 (col l+64)
    float e0 = 0.f, e1 = 0.f;
    bool k0 = false, k1 = false;
    if (rmv && smk[l] && v0 >= r3 && v0 >= c3sh[l]){
      e0 = expf(v0); k0 = (e0 > 0.05f);
    }
    if (rmv && smk[l+64] && v1 >= r3 && v1 >= c3sh[l+64]){
      e1 = expf(v1); k1 = (e1 > 0.05f);
    }
    if (k0){
      float sx = srcsh[l*3+0], sy = srcsh[l*3+1], sz = srcsh[l*3+2];
      q0 += 1.f; q1 += e0;
      q2 += e0*rx; q3 += e0*ry; q4 += e0*rz;
      q5 += e0*sx; q6 += e0*sy; q7 += e0*sz;
      q8 += e0*sx*rx;  q9 += e0*sx*ry;  q10 += e0*sx*rz;
      q11 += e0*sy*rx; q12 += e0*sy*ry; q13 += e0*sy*rz;
      q14 += e0*sz*rx; q15 += e0*sz*ry; q16 += e0*sz*rz;
    }
    if (k1){
      int c = l + 64;
      float sx = srcsh[c*3+0], sy = srcsh[c*3+1], sz = srcsh[c*3+2];
      q0 += 1.f; q1 += e1;
      q2 += e1*rx; q3 += e1*ry; q4 += e1*rz;
      q5 += e1*sx; q6 += e1*sy; q7 += e1*sz;
      q8 += e1*sx*rx;  q9 += e1*sx*ry;  q10 += e1*sx*rz;
      q11 += e1*sy*rx; q12 += e1*sy*ry; q13 += e1*sy*rz;
      q14 += e1*sz*rx; q15 += e1*sz*ry; q16 += e1*sz*rz;
    }
    // wave-compact candidates (<=3 per row barring exact ties)
    unsigned long long B0 = __ballot(k0);
    unsigned long long B1 = __ballot(k1);
    int n0 = __popcll(B0), n1 = __popcll(B1);
    if (n0 + n1 > 0){
      int wb = 0;
      if (l == 0){ wb = wcnt[w]; wcnt[w] = wb + n0 + n1; }
      wb = __shfl(wb, 0);
      unsigned long long lt = (l == 0) ? 0ull : (~0ull >> (64 - l));
      if (k0){
        int pos = wb + (int)__popcll(B0 & lt);
        if (pos < 96){ candv[w][pos] = e0; candi[w][pos] = (b<<14)|(r<<7)|l; }
      }
      if (k1){
        int pos = wb + n0 + (int)__popcll(B1 & lt);
        if (pos < 96){ candv[w][pos] = e1; candi[w][pos] = (b<<14)|(r<<7)|(l+64); }
      }
    }
  }
  // wave copy-out: one global atomic per wave; fused k3a histogram
  {
    int total = wcnt[w]; if (total > 96) total = 96;
    int gbase = 0;
    if (l == 0 && total > 0) gbase = atomicAdd(&hdr[0], total);
    gbase = __shfl(gbase, 0);
    for (int i = l; i < total; i += 64){
      float cv = candv[w][i];
      int pos = gbase + i;
      if (pos < CAND_CAP){
        cand_vals[pos] = cv; cand_idx[pos] = candi[w][i];
        atomicAdd(&hist[__float_as_uint(cv) >> 20], 1);
      }
    }
  }
  // 17-value block reduction
  {
    float qv[17] = {q0,q1,q2,q3,q4,q5,q6,q7,q8,q9,q10,q11,q12,q13,q14,q15,q16};
#pragma unroll
    for (int k = 0; k < 17; k++){
      float v = qv[k];
      for (int off2 = 32; off2 > 0; off2 >>= 1) v += __shfl_down(v, off2);
      if (l == 0) red[w][k] = v;
    }
  }
  __syncthreads();
  if (t == 0){
    float tot[17];
#pragma unroll
    for (int k = 0; k < 17; k++)
      tot[k] = red[0][k] + red[1][k] + red[2][k] + red[3][k];
    float Wm = tot[1];
    float denom = Wm + 1e-5f;
    float idenom = 1.f / denom;
    float s = Wm * idenom;
    float rcv[3] = { tot[2]*idenom, tot[3]*idenom, tot[4]*idenom };
    float scv[3] = { tot[5]*idenom, tot[6]*idenom, tot[7]*idenom };
    float* o = &Hsr[b*15];
#pragma unroll
    for (int c = 0; c < 3; c++)
#pragma unroll
      for (int d = 0; d < 3; d++)
        o[c*3+d] = tot[8 + c*3 + d]*idenom - (2.f - s)*scv[c]*rcv[d];
    o[9]=scv[0]; o[10]=scv[1]; o[11]=scv[2];
    o[12]=rcv[0]; o[13]=rcv[1]; o[14]=rcv[2];
    pcount[b] = (int)(tot[0] + 0.5f);
  }
}

// ---------------- K3c: parallel per-block boundary-find + grid partition ------
__global__ __launch_bounds__(256) void k3c_kernel(
    int* hdr, const int* __restrict__ hist,
    const float* __restrict__ cand_vals, const int* __restrict__ cand_idx,
    float* sel_vals, int* sel_idx, float* eq_vals, int* eq_idx)
{
  __shared__ int wtot[4];
  __shared__ int sb[2];
  const int t = threadIdx.x, lane = t & 63, wv = t >> 6;
  int Nc = hdr[0]; if (Nc > CAND_CAP) Nc = CAND_CAP;
  if (Nc <= LIMIT){
    if (t == 0){ sb[0] = -1; sb[1] = 0; if (blockIdx.x == 0){ hdr[4] = -1; hdr[5] = 0; } }
    __syncthreads();
  } else {
    const int chunkIdx = 255 - t;
    int csum = 0;
    for (int j = 0; j < 16; j++) csum += hist[chunkIdx*16 + j];
    int incl = csum;
    for (int off = 1; off < 64; off <<= 1){ int y = __shfl_up(incl, off); if (lane >= off) incl += y; }
    if (lane == 63) wtot[wv] = incl;
    __syncthreads();
    int wbase = 0;
    for (int w = 0; w < wv; w++) wbase += wtot[w];
    int P = wbase + incl;
    int P_prev = P - csum;
    if (P_prev < LIMIT && P >= LIMIT){
      int cum = P_prev, bin1 = chunkIdx*16, need = 0;
      for (int b2 = chunkIdx*16 + 15; b2 >= chunkIdx*16; b2--){
        int h = hist[b2];
        if (cum + h >= LIMIT){ bin1 = b2; need = LIMIT - cum; break; }
        cum += h;
      }
      sb[0] = bin1; sb[1] = need;
      if (blockIdx.x == 0){ hdr[4] = bin1; hdr[5] = need; }
    }
    __syncthreads();
  }
  int bin1 = sb[0];
  for (int i = blockIdx.x*256 + t; i < Nc; i += gridDim.x*256){
    float v = cand_vals[i];
    if (bin1 < 0){
      int p = atomicAdd(&hdr[2], 1);
      if (p < LIMIT){ sel_vals[p] = v; sel_idx[p] = cand_idx[i]; }
      continue;
    }
    int bin = (int)(__float_as_uint(v) >> 20);
    if (bin > bin1){
      int p = atomicAdd(&hdr[2], 1);
      if (p < LIMIT){ sel_vals[p] = v; sel_idx[p] = cand_idx[i]; }
    } else if (bin == bin1){
      int q = atomicAdd(&hdr[1], 1);
      if (q < EQCAP){ eq_vals[q] = v; eq_idx[q] = cand_idx[i]; }
    }
  }
}

// ---------------- K3d: refine boundary bin + zero-fill + gather ---------------
__global__ __launch_bounds__(1024) void k3d_kernel(
    const int* hdr, const float* __restrict__ eq_vals, const int* __restrict__ eq_idx,
    float* sel_vals, int* sel_idx,
    const float* __restrict__ refp, const float* __restrict__ srcp,
    float* sel_ref, float* sel_src)
{
  __shared__ int hist[2048];
  __shared__ int eqsh[2048];
  __shared__ int wtot[16];
  __shared__ int bpair[2];
  __shared__ int sh[2];
  const int t = threadIdx.x, lane = t & 63, wv = t >> 6;
  const int bin1 = hdr[4];
  int nAbove = hdr[2]; if (nAbove > LIMIT) nAbove = LIMIT;

  auto find_boundary = [&](int need){
    int i0 = 2047 - 2*t, i1 = 2046 - 2*t;
    int g0 = hist[i0], g1 = hist[i1];
    int local = g0 + g1;
    int incl = local;
    for (int off = 1; off < 64; off <<= 1){ int y = __shfl_up(incl, off); if (lane >= off) incl += y; }
    if (lane == 63) wtot[wv] = incl;
    __syncthreads();
    int wbase = 0;
    for (int w = 0; w < wv; w++) wbase += wtot[w];
    int P_prev = wbase + incl - local;
    int P0 = P_prev + g0;
    if (P0 >= need && P_prev < need){ bpair[0] = i0; bpair[1] = need - P_prev; }
    int P1 = P0 + g1;
    if (P1 >= need && P0 < need){ bpair[0] = i1; bpair[1] = need - P0; }
    __syncthreads();
  };

  bool done = false;
  if (bin1 < 0){
    for (int i = t; i < LIMIT; i += 1024)
      if (i >= nAbove){ sel_vals[i] = 0.f; sel_idx[i] = 0; }
    done = true;
  }
  int neq = 0, need = 0;
  if (!done){
    neq = hdr[1]; if (neq > EQCAP) neq = EQCAP;
    need = hdr[5];
    if (need >= neq){
      for (int i = t; i < neq; i += 1024){ sel_vals[nAbove+i] = eq_vals[i]; sel_idx[nAbove+i] = eq_idx[i]; }
      for (int i = t; i < LIMIT; i += 1024)
        if (i >= nAbove + neq){ sel_vals[i] = 0.f; sel_idx[i] = 0; }
      done = true;
    }
  }
  if (!done){
    for (int i = t; i < 2048; i += 1024) hist[i] = 0;
    __syncthreads();
    for (int i = t; i < neq; i += 1024)
      atomicAdd(&hist[(__float_as_uint(eq_vals[i]) >> 9) & 0x7FF], 1);
    __syncthreads();
    find_boundary(need);
    int binA = bpair[0], need2 = bpair[1];
    __syncthreads();
    for (int i = t; i < 2048; i += 1024) hist[i] = 0;
    __syncthreads();
    for (int i = t; i < neq; i += 1024){
      unsigned k = __float_as_uint(eq_vals[i]);
      if ((int)((k >> 9) & 0x7FF) == binA) atomicAdd(&hist[k & 0x1FF], 1);
    }
    __syncthreads();
    find_boundary(need2);
    unsigned Tlow = (((unsigned)binA) << 9) | (unsigned)bpair[0];
    unsigned Tkey = (((unsigned)bin1) << 20) | Tlow;
    if (t == 0){ sh[0] = 0; sh[1] = 0; }
    __syncthreads();
    for (int i = t; i < neq; i += 1024){
      unsigned k = __float_as_uint(eq_vals[i]);
      unsigned k20 = k & 0xFFFFF;
      if (k20 > Tlow){
        int p = atomicAdd(&sh[0], 1);
        sel_vals[nAbove + p] = eq_vals[i]; sel_idx[nAbove + p] = eq_idx[i];
      } else if (k20 == Tlow){
        int q = atomicAdd(&sh[1], 1);
        if (q < 2048) eqsh[q] = eq_idx[i];
      }
    }
    __syncthreads();
    if (t == 0){
      int na2 = sh[0];
      int ne2 = sh[1]; if (ne2 > 2048) ne2 = 2048;
      int take = need - na2; if (take > ne2) take = ne2; if (take < 0) take = 0;
      if (nAbove + na2 + take > LIMIT) take = LIMIT - nAbove - na2;
      for (int j = 0; j < take; j++){
        int mi = j;
        for (int l2 = j+1; l2 < ne2; l2++) if (eqsh[l2] < eqsh[mi]) mi = l2;
        int tmp = eqsh[j]; eqsh[j] = eqsh[mi]; eqsh[mi] = tmp;
        sel_vals[nAbove + na2 + j] = __uint_as_float(Tkey);
        sel_idx[nAbove + na2 + j] = eqsh[j];
      }
      for (int j = nAbove + na2 + take; j < LIMIT; j++){ sel_vals[j] = 0.f; sel_idx[j] = 0; }
    }
  }
  __syncthreads();
  for (int p = t; p < LIMIT; p += 1024){
    int idx = sel_idx[p];
    int b = idx >> 14, rr = (idx >> 7) & 127, ss = idx & 127;
#pragma unroll
    for (int c = 0; c < 3; c++){
      sel_ref[p*3+c] = refp[(b*NN+rr)*3+c];
      sel_src[p*3+c] = srcp[(b*NN+ss)*3+c];
    }
  }
}

// ---------------- K45: per-block Kabsch + inlier counts + last-block refine ---
__global__ __launch_bounds__(256) void k45_kernel(
    const float* __restrict__ Hsr, float* __restrict__ localT,
    const float* __restrict__ sel_vals, const float* __restrict__ sel_ref,
    const float* __restrict__ sel_src, const int* __restrict__ pcount,
    int* counts, int* hdr, float* out)
{
  __shared__ float Tsh[12];
  __shared__ int ired[4];
  __shared__ int lastsh;
  __shared__ double dred[4][16];
  __shared__ long long lred[4];
  __shared__ float RT[12];
  __shared__ int sbest;
  const int b = blockIdx.x, t = threadIdx.x, lane = t & 63, wv = t >> 6;

  if (t == 0){
    const float* o = &Hsr[b*15];
    float r00,r01,r02,r10,r11,r12,r20,r21,r22;
    kabsch9(o[0],o[1],o[2], o[3],o[4],o[5], o[6],o[7],o[8],
            r00,r01,r02,r10,r11,r12,r20,r21,r22);
    Tsh[0]=r00; Tsh[1]=r01; Tsh[2]=r02;
    Tsh[3]=r10; Tsh[4]=r11; Tsh[5]=r12;
    Tsh[6]=r20; Tsh[7]=r21; Tsh[8]=r22;
    Tsh[9]  = o[12] - (r00*o[9] + r01*o[10] + r02*o[11]);
    Tsh[10] = o[13] - (r10*o[9] + r11*o[10] + r12*o[11]);
    Tsh[11] = o[14] - (r20*o[9] + r21*o[10] + r22*o[11]);
  }
  __syncthreads();
  if (t < 12) localT[b*12 + t] = Tsh[t];

  {
    float R00=Tsh[0],R01=Tsh[1],R02=Tsh[2],R10=Tsh[3],R11=Tsh[4],R12=Tsh[5];
    float R20=Tsh[6],R21=Tsh[7],R22=Tsh[8];
    float tx=Tsh[9], ty=Tsh[10], tz=Tsh[11];
    int c = 0;
    for (int p = t; p < LIMIT; p += 256){
      float v = sel_vals[p];
      if (!(v > 0.f)) continue;
      float sx=sel_src[p*3], sy=sel_src[p*3+1], sz=sel_src[p*3+2];
      float rx=sel_ref[p*3], ry=sel_ref[p*3+1], rz=sel_ref[p*3+2];
      float ax = R00*sx + R01*sy + R02*sz + tx;
      float ay = R10*sx + R11*sy + R12*sz + ty;
      float az = R20*sx + R21*sy + R22*sz + tz;
      float dx = rx-ax, dy = ry-ay, dz = rz-az;
      if (sqrtf(dx*dx + dy*dy + dz*dz) < 0.1f) c++;
    }
    for (int off2 = 32; off2 > 0; off2 >>= 1) c += __shfl_down(c, off2);
    if (lane == 0) ired[wv] = c;
    __syncthreads();
    if (t == 0){
      counts[b] = (pcount[b] >= 3) ? (ired[0]+ired[1]+ired[2]+ired[3]) : -1;
      __threadfence();
      int d = atomicAdd(&hdr[6], 1);
      lastsh = (d == BB - 1) ? 1 : 0;
    }
    __syncthreads();
    if (!lastsh) return;
    __threadfence();
  }

  {
    long long key = (long long)0x8000000000000000LL;
    for (int bb = t; bb < BB; bb += 256){
      long long kk = ((long long)(counts[bb] + 2) << 32) | (long long)(511 - bb);
      if (kk > key) key = kk;
    }
    for (int off2 = 32; off2 > 0; off2 >>= 1){ long long o = __shfl_down(key, off2); if (o > key) key = o; }
    if (lane == 0) lred[wv] = key;
    __syncthreads();
    if (t == 0){
      long long m = lred[0];
#pragma unroll
      for (int w = 1; w < 4; w++) if (lred[w] > m) m = lred[w];
      sbest = 511 - (int)(m & 0xFFFFFFFFLL);
    }
    __syncthreads();
    if (t < 12) RT[t] = localT[sbest*12 + t];
    __syncthreads();

    for (int iter = 0; iter < 5; iter++){
      float R00=RT[0],R01=RT[1],R02=RT[2];
      float R10=RT[3],R11=RT[4],R12=RT[5];
      float R20=RT[6],R21=RT[7],R22=RT[8];
      float tx=RT[9], ty=RT[10], tz=RT[11];
      double a[16];
#pragma unroll
      for (int k = 0; k < 16; k++) a[k] = 0.0;
      for (int p = t; p < LIMIT; p += 256){
        float v = sel_vals[p];
        if (!(v > 0.f)) continue;
        float sx=sel_src[p*3], sy=sel_src[p*3+1], sz=sel_src[p*3+2];
        float rx=sel_ref[p*3], ry=sel_ref[p*3+1], rz=sel_ref[p*3+2];
        float ax = R00*sx + R01*sy + R02*sz + tx;
        float ay = R10*sx + R11*sy + R12*sz + ty;
        float az = R20*sx + R21*sy + R22*sz + tz;
        float dx = rx-ax, dy = ry-ay, dz = rz-az;
        if (sqrtf(dx*dx + dy*dy + dz*dz) < 0.1f){
          double w = (double)v;
          a[0] += w;
          a[1] += w*sx; a[2] += w*sy; a[3] += w*sz;
          a[4] += w*rx; a[5] += w*ry; a[6] += w*rz;
          a[7]  += w*sx*rx; a[8]  += w*sx*ry; a[9]  += w*sx*rz;
          a[10] += w*sy*rx; a[11] += w*sy*ry; a[12] += w*sy*rz;
          a[13] += w*sz*rx; a[14] += w*sz*ry; a[15] += w*sz*rz;
        }
      }
#pragma unroll
      for (int k = 0; k < 16; k++){
        double v = a[k];
        for (int off2 = 32; off2 > 0; off2 >>= 1) v += __shfl_down(v, off2);
        if (lane == 0) dred[wv][k] = v;
      }
      __syncthreads();
      if (t == 0){
        double tot[16];
#pragma unroll
        for (int k = 0; k < 16; k++) tot[k] = dred[0][k]+dred[1][k]+dred[2][k]+dred[3][k];
        double W = tot[0], denom = W + 1e-5;
        double inv = 1.0 / denom;
        double s = W * inv;
        double scv[3] = { tot[1]*inv, tot[2]*inv, tot[3]*inv };
        double rcv[3] = { tot[4]*inv, tot[5]*inv, tot[6]*inv };
        float h00 = (float)(tot[7]*inv  - (2.0 - s)*scv[0]*rcv[0]);
        float h01 = (float)(tot[8]*inv  - (2.0 - s)*scv[0]*rcv[1]);
        float h02 = (float)(tot[9]*inv  - (2.0 - s)*scv[0]*rcv[2]);
        float h10 = (float)(tot[10]*inv - (2.0 - s)*scv[1]*rcv[0]);
        float h11 = (float)(tot[11]*inv - (2.0 - s)*scv[1]*rcv[1]);
        float h12 = (float)(tot[12]*inv - (2.0 - s)*scv[1]*rcv[2]);
        float h20 = (float)(tot[13]*inv - (2.0 - s)*scv[2]*rcv[0]);
        float h21 = (float)(tot[14]*inv - (2.0 - s)*scv[2]*rcv[1]);
        float h22 = (float)(tot[15]*inv - (2.0 - s)*scv[2]*rcv[2]);
        float r00,r01,r02,r10,r11,r12,r20,r21,r22;
        kabsch9(h00,h01,h02,h10,h11,h12,h20,h21,h22,
                r00,r01,r02,r10,r11,r12,r20,r21,r22);
        RT[0]=r00; RT[1]=r01; RT[2]=r02;
        RT[3]=r10; RT[4]=r11; RT[5]=r12;
        RT[6]=r20; RT[7]=r21; RT[8]=r22;
        RT[9]  = (float)(rcv[0] - ((double)r00*scv[0] + (double)r01*scv[1] + (double)r02*scv[2]));
        RT[10] = (float)(rcv[1] - ((double)r10*scv[0] + (double)r11*scv[1] + (double)r12*scv[2]));
        RT[11] = (float)(rcv[2] - ((double)r20*scv[0] + (double)r21*scv[1] + (double)r22*scv[2]));
      }
      __syncthreads();
    }
    if (t == 0){
      out[0]=RT[0];  out[1]=RT[1];  out[2]=RT[2];  out[3]=RT[9];
      out[4]=RT[3];  out[5]=RT[4];  out[6]=RT[5];  out[7]=RT[10];
      out[8]=RT[6];  out[9]=RT[7];  out[10]=RT[8]; out[11]=RT[11];
      out[12]=0.f; out[13]=0.f; out[14]=0.f; out[15]=1.f;
    }
  }
}

// ---------------- host launcher -----------------------------------------------
extern "C" void kernel_launch(void* const* d_in, const int* in_sizes, int n_in,
                              void* d_out, int out_size, void* d_ws, size_t ws_size,
                              hipStream_t stream){
  const float* score = (const float*)d_in[0];
  const float* refp  = (const float*)d_in[1];
  const float* srcp  = (const float*)d_in[2];
  const void*  rmask = d_in[3];
  const void*  smask = d_in[4];

  char* ws = (char*)d_ws;
  size_t off = 0;
  int* hdr = (int*)(ws + off);            off += 256;
  int* hist = (int*)(ws + off);           off += (size_t)NBIN1*4;
  float* cand_vals = (float*)(ws + off);  off += (size_t)CAND_CAP*4;
  int* cand_idx = (int*)(ws + off);       off += (size_t)CAND_CAP*4;
  float* eq_vals = (float*)(ws + off);    off += (size_t)EQCAP*4;
  int* eq_idx = (int*)(ws + off);         off += (size_t)EQCAP*4;
  float* c3g = (float*)(ws + off);        off += (size_t)BB*NN*4;
  float* Hsr = (float*)(ws + off);        off += (size_t)BB*15*4;
  int* pcount = (int*)(ws + off);         off += (size_t)BB*4;
  float* localT = (float*)(ws + off);     off += (size_t)BB*12*4;
  float* sel_vals = (float*)(ws + off);   off += (size_t)LIMIT*4;
  int* sel_idx = (int*)(ws + off);        off += (size_t)LIMIT*4;
  float* sel_ref = (float*)(ws + off);    off += (size_t)LIMIT*3*4;
  float* sel_src = (float*)(ws + off);    off += (size_t)LIMIT*3*4;
  int* counts = (int*)(ws + off);         off += (size_t)BB*4;

  hipMemsetAsync(ws, 0, 256 + (size_t)NBIN1*4, stream);
  hipLaunchKernelGGL(k1a_kernel, dim3(BB), dim3(128), 0, stream, score, c3g);
  hipLaunchKernelGGL(k1b_kernel, dim3(BB), dim3(256), 0, stream,
                     score, refp, srcp, rmask, smask, c3g,
                     hdr, cand_vals, cand_idx, hist, Hsr, pcount);
  hipLaunchKernelGGL(k3c_kernel, dim3(64), dim3(256), 0, stream,
                     hdr, hist, cand_vals, cand_idx, sel_vals, sel_idx, eq_vals, eq_idx);
  hipLaunchKernelGGL(k3d_kernel, dim3(1), dim3(1024), 0, stream,
                     hdr, eq_vals, eq_idx, sel_vals, sel_idx, refp, srcp, sel_ref, sel_src);
  hipLaunchKernelGGL(k45_kernel, dim3(BB), dim3(256), 0, stream,
                     Hsr, localT, sel_vals, sel_ref, sel_src, pcount, counts, hdr, (float*)d_out);
}

// Round 10
// 646.712 us; speedup vs baseline: 1.0107x; 1.0107x over previous
//
#include <hip/hip_runtime.h>
#include <math.h>

#define BB 512
#define NN 128
#define CAND_CAP (512*384)
#define LIMIT 2048
#define EQCAP 16384
#define NBIN1 4096

// ---------------- mask decode (int32 / byte / float32 robustness) -------------
__device__ inline bool read_mask(const void* p, int i, int mode){
  if (mode == 0) return ((const int*)p)[i] != 0;
  if (mode == 1) return ((const unsigned char*)p)[i] != 0;
  return ((const float*)p)[i] != 0.0f;
}

__device__ inline float fast_rcp(float x){ return __builtin_amdgcn_rcpf(x); }
__device__ inline float fast_rsq(float x){ return __builtin_amdgcn_rsqf(x); }

__device__ inline void top3_update(float v, float& a1, float& a2, float& a3){
  if (v > a1){ a3=a2; a2=a1; a1=v; }
  else if (v > a2){ a3=a2; a2=v; }
  else if (v > a3){ a3=v; }
}

// ---------------- fp32 Kabsch, SCALAR-ONLY interface --------------------------
__device__ __forceinline__ void kabsch9(
    float h00, float h01, float h02,
    float h10, float h11, float h12,
    float h20, float h21, float h22,
    float& r00, float& r01, float& r02,
    float& r10, float& r11, float& r12,
    float& r20, float& r21, float& r22)
{
  float s00 = h00*h00 + h10*h10 + h20*h20;
  float s01 = h00*h01 + h10*h11 + h20*h21;
  float s02 = h00*h02 + h10*h12 + h20*h22;
  float s11 = h01*h01 + h11*h11 + h21*h21;
  float s12 = h01*h02 + h11*h12 + h21*h22;
  float s22 = h02*h02 + h12*h12 + h22*h22;
  float v00=1.f,v01=0.f,v02=0.f, v10=0.f,v11=1.f,v12=0.f, v20=0.f,v21=0.f,v22=1.f;
  for (int sweep = 0; sweep < 10; sweep++){
    float off  = s01*s01 + s02*s02 + s12*s12;
    float base = s00*s00 + s11*s11 + s22*s22;
    if (off <= base*1e-14f + 1e-36f) break;
    if (fabsf(s01) > 1e-30f){
      float tau = (s11 - s00) * fast_rcp(2.f*s01);
      float tt  = (tau >= 0.f ? 1.f : -1.f) * fast_rcp(fabsf(tau) + sqrtf(1.f + tau*tau));
      float c = fast_rsq(1.f + tt*tt), s = tt*c;
      float n00 = c*c*s00 - 2.f*c*s*s01 + s*s*s11;
      float n11 = s*s*s00 + 2.f*c*s*s01 + c*c*s11;
      float n02 = c*s02 - s*s12;
      float n12 = s*s02 + c*s12;
      s00=n00; s11=n11; s01=0.f; s02=n02; s12=n12;
      float a,b;
      a=v00; b=v01; v00=c*a-s*b; v01=s*a+c*b;
      a=v10; b=v11; v10=c*a-s*b; v11=s*a+c*b;
      a=v20; b=v21; v20=c*a-s*b; v21=s*a+c*b;
    }
    if (fabsf(s02) > 1e-30f){
      float tau = (s22 - s00) * fast_rcp(2.f*s02);
      float tt  = (tau >= 0.f ? 1.f : -1.f) * fast_rcp(fabsf(tau) + sqrtf(1.f + tau*tau));
      float c = fast_rsq(1.f + tt*tt), s = tt*c;
      float n00 = c*c*s00 - 2.f*c*s*s02 + s*s*s22;
      float n22 = s*s*s00 + 2.f*c*s*s02 + c*c*s22;
      float n01 = c*s01 - s*s12;
      float n12 = s*s01 + c*s12;
      s00=n00; s22=n22; s02=0.f; s01=n01; s12=n12;
      float a,b;
      a=v00; b=v02; v00=c*a-s*b; v02=s*a+c*b;
      a=v10; b=v12; v10=c*a-s*b; v12=s*a+c*b;
      a=v20; b=v22; v20=c*a-s*b; v22=s*a+c*b;
    }
    if (fabsf(s12) > 1e-30f){
      float tau = (s22 - s11) * fast_rcp(2.f*s12);
      float tt  = (tau >= 0.f ? 1.f : -1.f) * fast_rcp(fabsf(tau) + sqrtf(1.f + tau*tau));
      float c = fast_rsq(1.f + tt*tt), s = tt*c;
      float n11 = c*c*s11 - 2.f*c*s*s12 + s*s*s22;
      float n22 = s*s*s11 + 2.f*c*s*s12 + c*c*s22;
      float n01 = c*s01 - s*s02;
      float n02 = s*s01 + c*s02;
      s11=n11; s22=n22; s12=0.f; s01=n01; s02=n02;
      float a,b;
      a=v01; b=v02; v01=c*a-s*b; v02=s*a+c*b;
      a=v11; b=v12; v11=c*a-s*b; v12=s*a+c*b;
      a=v21; b=v22; v21=c*a-s*b; v22=s*a+c*b;
    }
  }
  float l0=s00, l1=s11, l2=s22;
  float a0=v00, a1=v10, a2=v20;
  float b0=v01, b1=v11, b2=v21;
  float c0=v02, c1=v12, c2=v22;
  if (l0 < l1){ float x; x=l0;l0=l1;l1=x; x=a0;a0=b0;b0=x; x=a1;a1=b1;b1=x; x=a2;a2=b2;b2=x; }
  if (l0 < l2){ float x; x=l0;l0=l2;l2=x; x=a0;a0=c0;c0=x; x=a1;a1=c1;c1=x; x=a2;a2=c2;c2=x; }
  if (l1 < l2){ float x; x=l1;l1=l2;l2=x; x=b0;b0=c0;c0=x; x=b1;b1=c1;c1=x; x=b2;b2=c2;c2=x; }
  float sig0 = sqrtf(fmaxf(l0, 0.f));
  if (!(sig0 > 1e-12f)){
    r00=1.f; r01=0.f; r02=0.f; r10=0.f; r11=1.f; r12=0.f; r20=0.f; r21=0.f; r22=1.f;
    return;
  }
  float u0x = h00*a0 + h01*a1 + h02*a2;
  float u0y = h10*a0 + h11*a1 + h12*a2;
  float u0z = h20*a0 + h21*a1 + h22*a2;
  float in0 = fast_rsq(u0x*u0x + u0y*u0y + u0z*u0z);
  u0x *= in0; u0y *= in0; u0z *= in0;
  float u1x = h00*b0 + h01*b1 + h02*b2;
  float u1y = h10*b0 + h11*b1 + h12*b2;
  float u1z = h20*b0 + h21*b1 + h22*b2;
  float dp = u1x*u0x + u1y*u0y + u1z*u0z;
  u1x -= dp*u0x; u1y -= dp*u0y; u1z -= dp*u0z;
  float d1 = u1x*u1x + u1y*u1y + u1z*u1z;
  if (sqrtf(d1) > sig0*1e-5f){
    float in1 = fast_rsq(d1);
    u1x *= in1; u1y *= in1; u1z *= in1;
  } else {
    float au0 = fabsf(u0x), au1 = fabsf(u0y), au2 = fabsf(u0z);
    float e0 = 0.f, e1 = 0.f, e2 = 0.f;
    if (au0 <= au1 && au0 <= au2) e0 = 1.f; else if (au1 <= au2) e1 = 1.f; else e2 = 1.f;
    float d2 = e0*u0x + e1*u0y + e2*u0z;
    u1x = e0 - d2*u0x; u1y = e1 - d2*u0y; u1z = e2 - d2*u0z;
    float nn = fast_rsq(u1x*u1x + u1y*u1y + u1z*u1z);
    u1x *= nn; u1y *= nn; u1z *= nn;
  }
  float u2x = u0y*u1z - u0z*u1y;
  float u2y = u0z*u1x - u0x*u1z;
  float u2z = u0x*u1y - u0y*u1x;
  float cxv = b1*c2 - b2*c1;
  float cyv = b2*c0 - b0*c2;
  float czv = b0*c1 - b1*c0;
  float detV = a0*cxv + a1*cyv + a2*czv;
  float dd = (detV >= 0.f) ? 1.f : -1.f;
  float w2x = dd*u2x, w2y = dd*u2y, w2z = dd*u2z;
  r00=a0*u0x + b0*u1x + c0*w2x;  r01=a0*u0y + b0*u1y + c0*w2y;  r02=a0*u0z + b0*u1z + c0*w2z;
  r10=a1*u0x + b1*u1x + c1*w2x;  r11=a1*u0y + b1*u1y + c1*w2y;  r12=a1*u0z + b1*u1z + c1*w2z;
  r20=a2*u0x + b2*u1x + c2*w2x;  r21=a2*u0y + b2*u1y + c2*w2y;  r22=a2*u0z + b2*u1z + c2*w2z;
}

// ---------------- K1a: column top-3 thresholds (tile-free, coalesced) ---------
__global__ __launch_bounds__(128) void k1a_kernel(
    const float* __restrict__ score, float* __restrict__ c3g)
{
  const int b = blockIdx.x, t = threadIdx.x;
  const float* col = score + (size_t)b*NN*NN + t;
  float a1=-1e30f, a2=-1e30f, a3=-1e30f;
#pragma unroll 8
  for (int n = 0; n < NN; n++){
    float v = col[n*NN];
    top3_update(v, a1, a2, a3);
  }
  c3g[b*NN + t] = a3;
}

// ---------------- K1b: wave-per-rows mutual top-3 + stats + candidates + hist -
// 256 threads = 4 waves; wave w owns rows [w*32, w*32+32). Lane l holds cols
// l and l+64 in registers. Stats factored through 5 accumulators per column
// (cnt, A=Σe, R⃗=Σe·ref) — src applied AFTER the loop (lane-invariant), keeping
// live registers low (R9's 17-per-element accumulation spilled: VGPR=32, 417us).
__global__ __launch_bounds__(256) void k1b_kernel(
    const float* __restrict__ score, const float* __restrict__ refp,
    const float* __restrict__ srcp, const void* __restrict__ rmaskp,
    const void* __restrict__ smaskp, const float* __restrict__ c3g,
    int* hdr, float* cand_vals, int* cand_idx, int* hist,
    float* Hsr, int* pcount)
{
  __shared__ float srcsh[NN*3];
  __shared__ float refsh[NN*3];
  __shared__ float c3sh[NN];
  __shared__ unsigned char smk[NN], rmk[NN];
  __shared__ float candv[4][96];
  __shared__ int   candi[4][96];
  __shared__ int   wcnt[4];
  __shared__ float red[4][17];
  __shared__ int smode;
  const int b = blockIdx.x, t = threadIdx.x;
  const int w = t >> 6, l = t & 63;

  if (t < 64){
    unsigned v = ((const unsigned*)rmaskp)[t];
    bool n01 = !(v == 0u || v == 1u);
    bool nf  = !(v == 0u || v == 0x3F800000u);
    unsigned long long b01 = __ballot(n01), bf = __ballot(nf);
    if (t == 0) smode = (b01 == 0ull) ? 0 : ((bf == 0ull) ? 2 : 1);
  }
  if (t < 4) wcnt[t] = 0;
  for (int i = t; i < NN*3; i += 256){
    srcsh[i] = srcp[b*NN*3 + i];
    refsh[i] = refp[b*NN*3 + i];
  }
  if (t < NN) c3sh[t] = c3g[b*NN + t];
  __syncthreads();       // smode ready
  if (t < NN){
    int mode = smode;
    smk[t] = read_mask(smaskp, b*NN + t, mode) ? 1 : 0;
    rmk[t] = read_mask(rmaskp, b*NN + t, mode) ? 1 : 0;
  }
  __syncthreads();

  // 5 accumulators per column slot (10 live floats total)
  float cn0=0.f, A0=0.f, Rx0=0.f, Ry0=0.f, Rz0=0.f;
  float cn1=0.f, A1=0.f, Rx1=0.f, Ry1=0.f, Rz1=0.f;
  const float c3_0 = c3sh[l], c3_1 = c3sh[l + 64];
  const int sm0 = smk[l], sm1 = smk[l + 64];

  const float* base = score + (size_t)b*NN*NN;
  for (int rr = 0; rr < 32; rr++){
    const int r = w*32 + rr;
    const float v0 = base[r*NN + l];
    const float v1 = base[r*NN + l + 64];
    // row top-3 via butterfly merge of sorted triples
    float a1 = fmaxf(v0, v1), a2 = fminf(v0, v1), a3 = -1e30f;
#pragma unroll
    for (int st = 0; st < 6; st++){
      const int mask = 1 << st;
      float o1 = __shfl_xor(a1, mask);
      float o2 = __shfl_xor(a2, mask);
      float o3 = __shfl_xor(a3, mask);
      float m1 = fmaxf(a1, o1);
      float m2 = fmaxf(fminf(a1, o1), fmaxf(a2, o2));
      float m3 = fmaxf(fmaxf(fminf(a1, o2), fminf(a2, o1)), fmaxf(a3, o3));
      a1 = m1; a2 = m2; a3 = m3;
    }
    const float r3 = a3;
    const bool rmv = rmk[r] != 0;
    const float rx = refsh[r*3+0], ry = refsh[r*3+1], rz = refsh[r*3+2];
    float e0 = 0.f, e1 = 0.f;
    bool k0 = false, k1 = false;
    if (rmv && sm0 && v0 >= r3 && v0 >= c3_0){
      e0 = expf(v0); k0 = (e0 > 0.05f);
    }
    if (rmv && sm1 && v1 >= r3 && v1 >= c3_1){
      e1 = expf(v1); k1 = (e1 > 0.05f);
    }
    if (k0){ cn0 += 1.f; A0 += e0; Rx0 += e0*rx; Ry0 += e0*ry; Rz0 += e0*rz; }
    if (k1){ cn1 += 1.f; A1 += e1; Rx1 += e1*rx; Ry1 += e1*ry; Rz1 += e1*rz; }
    // wave-compact candidates (<=3 per row barring exact ties)
    unsigned long long B0 = __ballot(k0);
    unsigned long long B1 = __ballot(k1);
    int n0 = __popcll(B0), n1 = __popcll(B1);
    if (n0 + n1 > 0){
      int wb = 0;
      if (l == 0){ wb = wcnt[w]; wcnt[w] = wb + n0 + n1; }
      wb = __shfl(wb, 0);
      unsigned long long lt = (l == 0) ? 0ull : (~0ull >> (64 - l));
      if (k0){
        int pos = wb + (int)__popcll(B0 & lt);
        if (pos < 96){ candv[w][pos] = e0; candi[w][pos] = (b<<14)|(r<<7)|l; }
      }
      if (k1){
        int pos = wb + n0 + (int)__popcll(B1 & lt);
        if (pos < 96){ candv[w][pos] = e1; candi[w][pos] = (b<<14)|(r<<7)|(l+64); }
      }
    }
  }
  // wave copy-out: one global atomic per wave; fused k3a histogram
  {
    int total = wcnt[w]; if (total > 96) total = 96;
    int gbase = 0;
    if (l == 0 && total > 0) gbase = atomicAdd(&hdr[0], total);
    gbase = __shfl(gbase, 0);
    for (int i = l; i < total; i += 64){
      float cv = candv[w][i];
      int pos = gbase + i;
      if (pos < CAND_CAP){
        cand_vals[pos] = cv; cand_idx[pos] = candi[w][i];
        atomicAdd(&hist[__float_as_uint(cv) >> 20], 1);
      }
    }
  }
  // expand 10 accumulators -> 17 stats (src is lane-invariant per column slot)
  {
    const float sx0 = srcsh[l*3+0], sy0 = srcsh[l*3+1], sz0 = srcsh[l*3+2];
    const float sx1 = srcsh[(l+64)*3+0], sy1 = srcsh[(l+64)*3+1], sz1 = srcsh[(l+64)*3+2];
#define WSUM(VAL, IDX) { float v_ = (VAL); \
    for (int o_ = 32; o_ > 0; o_ >>= 1) v_ += __shfl_down(v_, o_); \
    if (l == 0) red[w][IDX] = v_; }
    WSUM(cn0 + cn1, 0)
    WSUM(A0 + A1, 1)
    WSUM(Rx0 + Rx1, 2)
    WSUM(Ry0 + Ry1, 3)
    WSUM(Rz0 + Rz1, 4)
    WSUM(A0*sx0 + A1*sx1, 5)
    WSUM(A0*sy0 + A1*sy1, 6)
    WSUM(A0*sz0 + A1*sz1, 7)
    WSUM(sx0*Rx0 + sx1*Rx1, 8)
    WSUM(sx0*Ry0 + sx1*Ry1, 9)
    WSUM(sx0*Rz0 + sx1*Rz1, 10)
    WSUM(sy0*Rx0 + sy1*Rx1, 11)
    WSUM(sy0*Ry0 + sy1*Ry1, 12)
    WSUM(sy0*Rz0 + sy1*Rz1, 13)
    WSUM(sz0*Rx0 + sz1*Rx1, 14)
    WSUM(sz0*Ry0 + sz1*Ry1, 15)
    WSUM(sz0*Rz0 + sz1*Rz1, 16)
#undef WSUM
  }
  __syncthreads();
  if (t == 0){
    float tot[17];
#pragma unroll
    for (int k = 0; k < 17; k++)
      tot[k] = red[0][k] + red[1][k] + red[2][k] + red[3][k];
    float Wm = tot[1];
    float denom = Wm + 1e-5f;
    float idenom = 1.f / denom;
    float s = Wm * idenom;
    float rcv[3] = { tot[2]*idenom, tot[3]*idenom, tot[4]*idenom };
    float scv[3] = { tot[5]*idenom, tot[6]*idenom, tot[7]*idenom };
    float* o = &Hsr[b*15];
#pragma unroll
    for (int c = 0; c < 3; c++)
#pragma unroll
      for (int d = 0; d < 3; d++)
        o[c*3+d] = tot[8 + c*3 + d]*idenom - (2.f - s)*scv[c]*rcv[d];
    o[9]=scv[0]; o[10]=scv[1]; o[11]=scv[2];
    o[12]=rcv[0]; o[13]=rcv[1]; o[14]=rcv[2];
    pcount[b] = (int)(tot[0] + 0.5f);
  }
}

// ---------------- K3c: parallel per-block boundary-find + grid partition ------
__global__ __launch_bounds__(256) void k3c_kernel(
    int* hdr, const int* __restrict__ hist,
    const float* __restrict__ cand_vals, const int* __restrict__ cand_idx,
    float* sel_vals, int* sel_idx, float* eq_vals, int* eq_idx)
{
  __shared__ int wtot[4];
  __shared__ int sb[2];
  const int t = threadIdx.x, lane = t & 63, wv = t >> 6;
  int Nc = hdr[0]; if (Nc > CAND_CAP) Nc = CAND_CAP;
  if (Nc <= LIMIT){
    if (t == 0){ sb[0] = -1; sb[1] = 0; if (blockIdx.x == 0){ hdr[4] = -1; hdr[5] = 0; } }
    __syncthreads();
  } else {
    const int chunkIdx = 255 - t;
    int csum = 0;
    for (int j = 0; j < 16; j++) csum += hist[chunkIdx*16 + j];
    int incl = csum;
    for (int off = 1; off < 64; off <<= 1){ int y = __shfl_up(incl, off); if (lane >= off) incl += y; }
    if (lane == 63) wtot[wv] = incl;
    __syncthreads();
    int wbase = 0;
    for (int w = 0; w < wv; w++) wbase += wtot[w];
    int P = wbase + incl;
    int P_prev = P - csum;
    if (P_prev < LIMIT && P >= LIMIT){
      int cum = P_prev, bin1 = chunkIdx*16, need = 0;
      for (int b2 = chunkIdx*16 + 15; b2 >= chunkIdx*16; b2--){
        int h = hist[b2];
        if (cum + h >= LIMIT){ bin1 = b2; need = LIMIT - cum; break; }
        cum += h;
      }
      sb[0] = bin1; sb[1] = need;
      if (blockIdx.x == 0){ hdr[4] = bin1; hdr[5] = need; }
    }
    __syncthreads();
  }
  int bin1 = sb[0];
  for (int i = blockIdx.x*256 + t; i < Nc; i += gridDim.x*256){
    float v = cand_vals[i];
    if (bin1 < 0){
      int p = atomicAdd(&hdr[2], 1);
      if (p < LIMIT){ sel_vals[p] = v; sel_idx[p] = cand_idx[i]; }
      continue;
    }
    int bin = (int)(__float_as_uint(v) >> 20);
    if (bin > bin1){
      int p = atomicAdd(&hdr[2], 1);
      if (p < LIMIT){ sel_vals[p] = v; sel_idx[p] = cand_idx[i]; }
    } else if (bin == bin1){
      int q = atomicAdd(&hdr[1], 1);
      if (q < EQCAP){ eq_vals[q] = v; eq_idx[q] = cand_idx[i]; }
    }
  }
}

// ---------------- K3d: refine boundary bin + zero-fill + gather ---------------
__global__ __launch_bounds__(1024) void k3d_kernel(
    const int* hdr, const float* __restrict__ eq_vals, const int* __restrict__ eq_idx,
    float* sel_vals, int* sel_idx,
    const float* __restrict__ refp, const float* __restrict__ srcp,
    float* sel_ref, float* sel_src)
{
  __shared__ int hist[2048];
  __shared__ int eqsh[2048];
  __shared__ int wtot[16];
  __shared__ int bpair[2];
  __shared__ int sh[2];
  const int t = threadIdx.x, lane = t & 63, wv = t >> 6;
  const int bin1 = hdr[4];
  int nAbove = hdr[2]; if (nAbove > LIMIT) nAbove = LIMIT;

  auto find_boundary = [&](int need){
    int i0 = 2047 - 2*t, i1 = 2046 - 2*t;
    int g0 = hist[i0], g1 = hist[i1];
    int local = g0 + g1;
    int incl = local;
    for (int off = 1; off < 64; off <<= 1){ int y = __shfl_up(incl, off); if (lane >= off) incl += y; }
    if (lane == 63) wtot[wv] = incl;
    __syncthreads();
    int wbase = 0;
    for (int w = 0; w < wv; w++) wbase += wtot[w];
    int P_prev = wbase + incl - local;
    int P0 = P_prev + g0;
    if (P0 >= need && P_prev < need){ bpair[0] = i0; bpair[1] = need - P_prev; }
    int P1 = P0 + g1;
    if (P1 >= need && P0 < need){ bpair[0] = i1; bpair[1] = need - P0; }
    __syncthreads();
  };

  bool done = false;
  if (bin1 < 0){
    for (int i = t; i < LIMIT; i += 1024)
      if (i >= nAbove){ sel_vals[i] = 0.f; sel_idx[i] = 0; }
    done = true;
  }
  int neq = 0, need = 0;
  if (!done){
    neq = hdr[1]; if (neq > EQCAP) neq = EQCAP;
    need = hdr[5];
    if (need >= neq){
      for (int i = t; i < neq; i += 1024){ sel_vals[nAbove+i] = eq_vals[i]; sel_idx[nAbove+i] = eq_idx[i]; }
      for (int i = t; i < LIMIT; i += 1024)
        if (i >= nAbove + neq){ sel_vals[i] = 0.f; sel_idx[i] = 0; }
      done = true;
    }
  }
  if (!done){
    for (int i = t; i < 2048; i += 1024) hist[i] = 0;
    __syncthreads();
    for (int i = t; i < neq; i += 1024)
      atomicAdd(&hist[(__float_as_uint(eq_vals[i]) >> 9) & 0x7FF], 1);
    __syncthreads();
    find_boundary(need);
    int binA = bpair[0], need2 = bpair[1];
    __syncthreads();
    for (int i = t; i < 2048; i += 1024) hist[i] = 0;
    __syncthreads();
    for (int i = t; i < neq; i += 1024){
      unsigned k = __float_as_uint(eq_vals[i]);
      if ((int)((k >> 9) & 0x7FF) == binA) atomicAdd(&hist[k & 0x1FF], 1);
    }
    __syncthreads();
    find_boundary(need2);
    unsigned Tlow = (((unsigned)binA) << 9) | (unsigned)bpair[0];
    unsigned Tkey = (((unsigned)bin1) << 20) | Tlow;
    if (t == 0){ sh[0] = 0; sh[1] = 0; }
    __syncthreads();
    for (int i = t; i < neq; i += 1024){
      unsigned k = __float_as_uint(eq_vals[i]);
      unsigned k20 = k & 0xFFFFF;
      if (k20 > Tlow){
        int p = atomicAdd(&sh[0], 1);
        sel_vals[nAbove + p] = eq_vals[i]; sel_idx[nAbove + p] = eq_idx[i];
      } else if (k20 == Tlow){
        int q = atomicAdd(&sh[1], 1);
        if (q < 2048) eqsh[q] = eq_idx[i];
      }
    }
    __syncthreads();
    if (t == 0){
      int na2 = sh[0];
      int ne2 = sh[1]; if (ne2 > 2048) ne2 = 2048;
      int take = need - na2; if (take > ne2) take = ne2; if (take < 0) take = 0;
      if (nAbove + na2 + take > LIMIT) take = LIMIT - nAbove - na2;
      for (int j = 0; j < take; j++){
        int mi = j;
        for (int l2 = j+1; l2 < ne2; l2++) if (eqsh[l2] < eqsh[mi]) mi = l2;
        int tmp = eqsh[j]; eqsh[j] = eqsh[mi]; eqsh[mi] = tmp;
        sel_vals[nAbove + na2 + j] = __uint_as_float(Tkey);
        sel_idx[nAbove + na2 + j] = eqsh[j];
      }
      for (int j = nAbove + na2 + take; j < LIMIT; j++){ sel_vals[j] = 0.f; sel_idx[j] = 0; }
    }
  }
  __syncthreads();
  for (int p = t; p < LIMIT; p += 1024){
    int idx = sel_idx[p];
    int b = idx >> 14, rr = (idx >> 7) & 127, ss = idx & 127;
#pragma unroll
    for (int c = 0; c < 3; c++){
      sel_ref[p*3+c] = refp[(b*NN+rr)*3+c];
      sel_src[p*3+c] = srcp[(b*NN+ss)*3+c];
    }
  }
}

// ---------------- K45: per-block Kabsch + inlier counts + last-block refine ---
__global__ __launch_bounds__(256) void k45_kernel(
    const float* __restrict__ Hsr, float* __restrict__ localT,
    const float* __restrict__ sel_vals, const float* __restrict__ sel_ref,
    const float* __restrict__ sel_src, const int* __restrict__ pcount,
    int* counts, int* hdr, float* out)
{
  __shared__ float Tsh[12];
  __shared__ int ired[4];
  __shared__ int lastsh;
  __shared__ double dred[4][16];
  __shared__ long long lred[4];
  __shared__ float RT[12];
  __shared__ int sbest;
  const int b = blockIdx.x, t = threadIdx.x, lane = t & 63, wv = t >> 6;

  if (t == 0){
    const float* o = &Hsr[b*15];
    float r00,r01,r02,r10,r11,r12,r20,r21,r22;
    kabsch9(o[0],o[1],o[2], o[3],o[4],o[5], o[6],o[7],o[8],
            r00,r01,r02,r10,r11,r12,r20,r21,r22);
    Tsh[0]=r00; Tsh[1]=r01; Tsh[2]=r02;
    Tsh[3]=r10; Tsh[4]=r11; Tsh[5]=r12;
    Tsh[6]=r20; Tsh[7]=r21; Tsh[8]=r22;
    Tsh[9]  = o[12] - (r00*o[9] + r01*o[10] + r02*o[11]);
    Tsh[10] = o[13] - (r10*o[9] + r11*o[10] + r12*o[11]);
    Tsh[11] = o[14] - (r20*o[9] + r21*o[10] + r22*o[11]);
  }
  __syncthreads();
  if (t < 12) localT[b*12 + t] = Tsh[t];

  {
    float R00=Tsh[0],R01=Tsh[1],R02=Tsh[2],R10=Tsh[3],R11=Tsh[4],R12=Tsh[5];
    float R20=Tsh[6],R21=Tsh[7],R22=Tsh[8];
    float tx=Tsh[9], ty=Tsh[10], tz=Tsh[11];
    int c = 0;
    for (int p = t; p < LIMIT; p += 256){
      float v = sel_vals[p];
      if (!(v > 0.f)) continue;
      float sx=sel_src[p*3], sy=sel_src[p*3+1], sz=sel_src[p*3+2];
      float rx=sel_ref[p*3], ry=sel_ref[p*3+1], rz=sel_ref[p*3+2];
      float ax = R00*sx + R01*sy + R02*sz + tx;
      float ay = R10*sx + R11*sy + R12*sz + ty;
      float az = R20*sx + R21*sy + R22*sz + tz;
      float dx = rx-ax, dy = ry-ay, dz = rz-az;
      if (sqrtf(dx*dx + dy*dy + dz*dz) < 0.1f) c++;
    }
    for (int off2 = 32; off2 > 0; off2 >>= 1) c += __shfl_down(c, off2);
    if (lane == 0) ired[wv] = c;
    __syncthreads();
    if (t == 0){
      counts[b] = (pcount[b] >= 3) ? (ired[0]+ired[1]+ired[2]+ired[3]) : -1;
      __threadfence();
      int d = atomicAdd(&hdr[6], 1);
      lastsh = (d == BB - 1) ? 1 : 0;
    }
    __syncthreads();
    if (!lastsh) return;
    __threadfence();
  }

  {
    long long key = (long long)0x8000000000000000LL;
    for (int bb = t; bb < BB; bb += 256){
      long long kk = ((long long)(counts[bb] + 2) << 32) | (long long)(511 - bb);
      if (kk > key) key = kk;
    }
    for (int off2 = 32; off2 > 0; off2 >>= 1){ long long o = __shfl_down(key, off2); if (o > key) key = o; }
    if (lane == 0) lred[wv] = key;
    __syncthreads();
    if (t == 0){
      long long m = lred[0];
#pragma unroll
      for (int w = 1; w < 4; w++) if (lred[w] > m) m = lred[w];
      sbest = 511 - (int)(m & 0xFFFFFFFFLL);
    }
    __syncthreads();
    if (t < 12) RT[t] = localT[sbest*12 + t];
    __syncthreads();

    for (int iter = 0; iter < 5; iter++){
      float R00=RT[0],R01=RT[1],R02=RT[2];
      float R10=RT[3],R11=RT[4],R12=RT[5];
      float R20=RT[6],R21=RT[7],R22=RT[8];
      float tx=RT[9], ty=RT[10], tz=RT[11];
      double a[16];
#pragma unroll
      for (int k = 0; k < 16; k++) a[k] = 0.0;
      for (int p = t; p < LIMIT; p += 256){
        float v = sel_vals[p];
        if (!(v > 0.f)) continue;
        float sx=sel_src[p*3], sy=sel_src[p*3+1], sz=sel_src[p*3+2];
        float rx=sel_ref[p*3], ry=sel_ref[p*3+1], rz=sel_ref[p*3+2];
        float ax = R00*sx + R01*sy + R02*sz + tx;
        float ay = R10*sx + R11*sy + R12*sz + ty;
        float az = R20*sx + R21*sy + R22*sz + tz;
        float dx = rx-ax, dy = ry-ay, dz = rz-az;
        if (sqrtf(dx*dx + dy*dy + dz*dz) < 0.1f){
          double w = (double)v;
          a[0] += w;
          a[1] += w*sx; a[2] += w*sy; a[3] += w*sz;
          a[4] += w*rx; a[5] += w*ry; a[6] += w*rz;
          a[7]  += w*sx*rx; a[8]  += w*sx*ry; a[9]  += w*sx*rz;
          a[10] += w*sy*rx; a[11] += w*sy*ry; a[12] += w*sy*rz;
          a[13] += w*sz*rx; a[14] += w*sz*ry; a[15] += w*sz*rz;
        }
      }
#pragma unroll
      for (int k = 0; k < 16; k++){
        double v = a[k];
        for (int off2 = 32; off2 > 0; off2 >>= 1) v += __shfl_down(v, off2);
        if (lane == 0) dred[wv][k] = v;
      }
      __syncthreads();
      if (t == 0){
        double tot[16];
#pragma unroll
        for (int k = 0; k < 16; k++) tot[k] = dred[0][k]+dred[1][k]+dred[2][k]+dred[3][k];
        double W = tot[0], denom = W + 1e-5;
        double inv = 1.0 / denom;
        double s = W * inv;
        double scv[3] = { tot[1]*inv, tot[2]*inv, tot[3]*inv };
        double rcv[3] = { tot[4]*inv, tot[5]*inv, tot[6]*inv };
        float h00 = (float)(tot[7]*inv  - (2.0 - s)*scv[0]*rcv[0]);
        float h01 = (float)(tot[8]*inv  - (2.0 - s)*scv[0]*rcv[1]);
        float h02 = (float)(tot[9]*inv  - (2.0 - s)*scv[0]*rcv[2]);
        float h10 = (float)(tot[10]*inv - (2.0 - s)*scv[1]*rcv[0]);
        float h11 = (float)(tot[11]*inv - (2.0 - s)*scv[1]*rcv[1]);
        float h12 = (float)(tot[12]*inv - (2.0 - s)*scv[1]*rcv[2]);
        float h20 = (float)(tot[13]*inv - (2.0 - s)*scv[2]*rcv[0]);
        float h21 = (float)(tot[14]*inv - (2.0 - s)*scv[2]*rcv[1]);
        float h22 = (float)(tot[15]*inv - (2.0 - s)*scv[2]*rcv[2]);
        float r00,r01,r02,r10,r11,r12,r20,r21,r22;
        kabsch9(h00,h01,h02,h10,h11,h12,h20,h21,h22,
                r00,r01,r02,r10,r11,r12,r20,r21,r22);
        RT[0]=r00; RT[1]=r01; RT[2]=r02;
        RT[3]=r10; RT[4]=r11; RT[5]=r12;
        RT[6]=r20; RT[7]=r21; RT[8]=r22;
        RT[9]  = (float)(rcv[0] - ((double)r00*scv[0] + (double)r01*scv[1] + (double)r02*scv[2]));
        RT[10] = (float)(rcv[1] - ((double)r10*scv[0] + (double)r11*scv[1] + (double)r12*scv[2]));
        RT[11] = (float)(rcv[2] - ((double)r20*scv[0] + (double)r21*scv[1] + (double)r22*scv[2]));
      }
      __syncthreads();
    }
    if (t == 0){
      out[0]=RT[0];  out[1]=RT[1];  out[2]=RT[2];  out[3]=RT[9];
      out[4]=RT[3];  out[5]=RT[4];  out[6]=RT[5];  out[7]=RT[10];
      out[8]=RT[6];  out[9]=RT[7];  out[10]=RT[8]; out[11]=RT[11];
      out[12]=0.f; out[13]=0.f; out[14]=0.f; out[15]=1.f;
    }
  }
}

// ---------------- host launcher -----------------------------------------------
extern "C" void kernel_launch(void* const* d_in, const int* in_sizes, int n_in,
                              void* d_out, int out_size, void* d_ws, size_t ws_size,
                              hipStream_t stream){
  const float* score = (const float*)d_in[0];
  const float* refp  = (const float*)d_in[1];
  const float* srcp  = (const float*)d_in[2];
  const void*  rmask = d_in[3];
  const void*  smask = d_in[4];

  char* ws = (char*)d_ws;
  size_t off = 0;
  int* hdr = (int*)(ws + off);            off += 256;
  int* hist = (int*)(ws + off);           off += (size_t)NBIN1*4;
  float* cand_vals = (float*)(ws + off);  off += (size_t)CAND_CAP*4;
  int* cand_idx = (int*)(ws + off);       off += (size_t)CAND_CAP*4;
  float* eq_vals = (float*)(ws + off);    off += (size_t)EQCAP*4;
  int* eq_idx = (int*)(ws + off);         off += (size_t)EQCAP*4;
  float* c3g = (float*)(ws + off);        off += (size_t)BB*NN*4;
  float* Hsr = (float*)(ws + off);        off += (size_t)BB*15*4;
  int* pcount = (int*)(ws + off);         off += (size_t)BB*4;
  float* localT = (float*)(ws + off);     off += (size_t)BB*12*4;
  float* sel_vals = (float*)(ws + off);   off += (size_t)LIMIT*4;
  int* sel_idx = (int*)(ws + off);        off += (size_t)LIMIT*4;
  float* sel_ref = (float*)(ws + off);    off += (size_t)LIMIT*3*4;
  float* sel_src = (float*)(ws + off);    off += (size_t)LIMIT*3*4;
  int* counts = (int*)(ws + off);         off += (size_t)BB*4;

  hipMemsetAsync(ws, 0, 256 + (size_t)NBIN1*4, stream);
  hipLaunchKernelGGL(k1a_kernel, dim3(BB), dim3(128), 0, stream, score, c3g);
  hipLaunchKernelGGL(k1b_kernel, dim3(BB), dim3(256), 0, stream,
                     score, refp, srcp, rmask, smask, c3g,
                     hdr, cand_vals, cand_idx, hist, Hsr, pcount);
  hipLaunchKernelGGL(k3c_kernel, dim3(64), dim3(256), 0, stream,
                     hdr, hist, cand_vals, cand_idx, sel_vals, sel_idx, eq_vals, eq_idx);
  hipLaunchKernelGGL(k3d_kernel, dim3(1), dim3(1024), 0, stream,
                     hdr, eq_vals, eq_idx, sel_vals, sel_idx, refp, srcp, sel_ref, sel_src);
  hipLaunchKernelGGL(k45_kernel, dim3(BB), dim3(256), 0, stream,
                     Hsr, localT, sel_vals, sel_ref, sel_src, pcount, counts, hdr, (float*)d_out);
}

// Round 11
// 285.130 us; speedup vs baseline: 2.2923x; 2.2681x over previous
//
#include <hip/hip_runtime.h>
#include <math.h>

#define BB 512
#define NN 128
#define CAND_CAP (512*384)
#define LIMIT 2048
#define EQCAP 16384
#define NBIN1 4096

// ---------------- mask decode (int32 / byte / float32 robustness) -------------
__device__ inline bool read_mask(const void* p, int i, int mode){
  if (mode == 0) return ((const int*)p)[i] != 0;
  if (mode == 1) return ((const unsigned char*)p)[i] != 0;
  return ((const float*)p)[i] != 0.0f;
}

__device__ inline float fast_rcp(float x){ return __builtin_amdgcn_rcpf(x); }
__device__ inline float fast_rsq(float x){ return __builtin_amdgcn_rsqf(x); }

__device__ inline void top3_update(float v, float& a1, float& a2, float& a3){
  if (v > a1){ a3=a2; a2=a1; a1=v; }
  else if (v > a2){ a3=a2; a2=v; }
  else if (v > a3){ a3=v; }
}

// ---------------- fp32 Kabsch, SCALAR-ONLY interface --------------------------
__device__ __forceinline__ void kabsch9(
    float h00, float h01, float h02,
    float h10, float h11, float h12,
    float h20, float h21, float h22,
    float& r00, float& r01, float& r02,
    float& r10, float& r11, float& r12,
    float& r20, float& r21, float& r22)
{
  float s00 = h00*h00 + h10*h10 + h20*h20;
  float s01 = h00*h01 + h10*h11 + h20*h21;
  float s02 = h00*h02 + h10*h12 + h20*h22;
  float s11 = h01*h01 + h11*h11 + h21*h21;
  float s12 = h01*h02 + h11*h12 + h21*h22;
  float s22 = h02*h02 + h12*h12 + h22*h22;
  float v00=1.f,v01=0.f,v02=0.f, v10=0.f,v11=1.f,v12=0.f, v20=0.f,v21=0.f,v22=1.f;
  for (int sweep = 0; sweep < 10; sweep++){
    float off  = s01*s01 + s02*s02 + s12*s12;
    float base = s00*s00 + s11*s11 + s22*s22;
    if (off <= base*1e-14f + 1e-36f) break;
    if (fabsf(s01) > 1e-30f){
      float tau = (s11 - s00) * fast_rcp(2.f*s01);
      float tt  = (tau >= 0.f ? 1.f : -1.f) * fast_rcp(fabsf(tau) + sqrtf(1.f + tau*tau));
      float c = fast_rsq(1.f + tt*tt), s = tt*c;
      float n00 = c*c*s00 - 2.f*c*s*s01 + s*s*s11;
      float n11 = s*s*s00 + 2.f*c*s*s01 + c*c*s11;
      float n02 = c*s02 - s*s12;
      float n12 = s*s02 + c*s12;
      s00=n00; s11=n11; s01=0.f; s02=n02; s12=n12;
      float a,b;
      a=v00; b=v01; v00=c*a-s*b; v01=s*a+c*b;
      a=v10; b=v11; v10=c*a-s*b; v11=s*a+c*b;
      a=v20; b=v21; v20=c*a-s*b; v21=s*a+c*b;
    }
    if (fabsf(s02) > 1e-30f){
      float tau = (s22 - s00) * fast_rcp(2.f*s02);
      float tt  = (tau >= 0.f ? 1.f : -1.f) * fast_rcp(fabsf(tau) + sqrtf(1.f + tau*tau));
      float c = fast_rsq(1.f + tt*tt), s = tt*c;
      float n00 = c*c*s00 - 2.f*c*s*s02 + s*s*s22;
      float n22 = s*s*s00 + 2.f*c*s*s02 + c*c*s22;
      float n01 = c*s01 - s*s12;
      float n12 = s*s01 + c*s12;
      s00=n00; s22=n22; s02=0.f; s01=n01; s12=n12;
      float a,b;
      a=v00; b=v02; v00=c*a-s*b; v02=s*a+c*b;
      a=v10; b=v12; v10=c*a-s*b; v12=s*a+c*b;
      a=v20; b=v22; v20=c*a-s*b; v22=s*a+c*b;
    }
    if (fabsf(s12) > 1e-30f){
      float tau = (s22 - s11) * fast_rcp(2.f*s12);
      float tt  = (tau >= 0.f ? 1.f : -1.f) * fast_rcp(fabsf(tau) + sqrtf(1.f + tau*tau));
      float c = fast_rsq(1.f + tt*tt), s = tt*c;
      float n11 = c*c*s11 - 2.f*c*s*s12 + s*s*s22;
      float n22 = s*s*s11 + 2.f*c*s*s12 + c*c*s22;
      float n01 = c*s01 - s*s02;
      float n02 = s*s01 + c*s02;
      s11=n11; s22=n22; s12=0.f; s01=n01; s02=n02;
      float a,b;
      a=v01; b=v02; v01=c*a-s*b; v02=s*a+c*b;
      a=v11; b=v12; v11=c*a-s*b; v12=s*a+c*b;
      a=v21; b=v22; v21=c*a-s*b; v22=s*a+c*b;
    }
  }
  float l0=s00, l1=s11, l2=s22;
  float a0=v00, a1=v10, a2=v20;
  float b0=v01, b1=v11, b2=v21;
  float c0=v02, c1=v12, c2=v22;
  if (l0 < l1){ float x; x=l0;l0=l1;l1=x; x=a0;a0=b0;b0=x; x=a1;a1=b1;b1=x; x=a2;a2=b2;b2=x; }
  if (l0 < l2){ float x; x=l0;l0=l2;l2=x; x=a0;a0=c0;c0=x; x=a1;a1=c1;c1=x; x=a2;a2=c2;c2=x; }
  if (l1 < l2){ float x; x=l1;l1=l2;l2=x; x=b0;b0=c0;c0=x; x=b1;b1=c1;c1=x; x=b2;b2=c2;c2=x; }
  float sig0 = sqrtf(fmaxf(l0, 0.f));
  if (!(sig0 > 1e-12f)){
    r00=1.f; r01=0.f; r02=0.f; r10=0.f; r11=1.f; r12=0.f; r20=0.f; r21=0.f; r22=1.f;
    return;
  }
  float u0x = h00*a0 + h01*a1 + h02*a2;
  float u0y = h10*a0 + h11*a1 + h12*a2;
  float u0z = h20*a0 + h21*a1 + h22*a2;
  float in0 = fast_rsq(u0x*u0x + u0y*u0y + u0z*u0z);
  u0x *= in0; u0y *= in0; u0z *= in0;
  float u1x = h00*b0 + h01*b1 + h02*b2;
  float u1y = h10*b0 + h11*b1 + h12*b2;
  float u1z = h20*b0 + h21*b1 + h22*b2;
  float dp = u1x*u0x + u1y*u0y + u1z*u0z;
  u1x -= dp*u0x; u1y -= dp*u0y; u1z -= dp*u0z;
  float d1 = u1x*u1x + u1y*u1y + u1z*u1z;
  if (sqrtf(d1) > sig0*1e-5f){
    float in1 = fast_rsq(d1);
    u1x *= in1; u1y *= in1; u1z *= in1;
  } else {
    float au0 = fabsf(u0x), au1 = fabsf(u0y), au2 = fabsf(u0z);
    float e0 = 0.f, e1 = 0.f, e2 = 0.f;
    if (au0 <= au1 && au0 <= au2) e0 = 1.f; else if (au1 <= au2) e1 = 1.f; else e2 = 1.f;
    float d2 = e0*u0x + e1*u0y + e2*u0z;
    u1x = e0 - d2*u0x; u1y = e1 - d2*u0y; u1z = e2 - d2*u0z;
    float nn = fast_rsq(u1x*u1x + u1y*u1y + u1z*u1z);
    u1x *= nn; u1y *= nn; u1z *= nn;
  }
  float u2x = u0y*u1z - u0z*u1y;
  float u2y = u0z*u1x - u0x*u1z;
  float u2z = u0x*u1y - u0y*u1x;
  float cxv = b1*c2 - b2*c1;
  float cyv = b2*c0 - b0*c2;
  float czv = b0*c1 - b1*c0;
  float detV = a0*cxv + a1*cyv + a2*czv;
  float dd = (detV >= 0.f) ? 1.f : -1.f;
  float w2x = dd*u2x, w2y = dd*u2y, w2z = dd*u2z;
  r00=a0*u0x + b0*u1x + c0*w2x;  r01=a0*u0y + b0*u1y + c0*w2y;  r02=a0*u0z + b0*u1z + c0*w2z;
  r10=a1*u0x + b1*u1x + c1*w2x;  r11=a1*u0y + b1*u1y + c1*w2y;  r12=a1*u0z + b1*u1z + c1*w2z;
  r20=a2*u0x + b2*u1x + c2*w2x;  r21=a2*u0y + b2*u1y + c2*w2y;  r22=a2*u0z + b2*u1z + c2*w2z;
}

// ---------------- K1a: column top-3 thresholds (tile-free, coalesced) ---------
__global__ __launch_bounds__(128) void k1a_kernel(
    const float* __restrict__ score, float* __restrict__ c3g)
{
  const int b = blockIdx.x, t = threadIdx.x;
  const float* col = score + (size_t)b*NN*NN + t;
  float a1=-1e30f, a2=-1e30f, a3=-1e30f;
#pragma unroll 8
  for (int n = 0; n < NN; n++){
    float v = col[n*NN];
    top3_update(v, a1, a2, a3);
  }
  c3g[b*NN + t] = a3;
}

// ---------------- K1b: wave-per-rows mutual top-3 + stats + candidates --------
// 256 threads = 4 waves; wave w owns rows [w*32, w*32+32). Lane l holds cols
// l and l+64 in registers. NO per-candidate global histogram here — R9/R10's
// fused hist atomics (~75k device atomics into few hot lines) serialized at
// ~17cyc each = the 415us. Hist restored as separate LDS-local k3a.
// ONE hdr[0] atomic per BLOCK (R1 lesson: hot-line atomics serialize).
__global__ __launch_bounds__(256) void k1b_kernel(
    const float* __restrict__ score, const float* __restrict__ refp,
    const float* __restrict__ srcp, const void* __restrict__ rmaskp,
    const void* __restrict__ smaskp, const float* __restrict__ c3g,
    int* hdr, float* cand_vals, int* cand_idx,
    float* Hsr, int* pcount)
{
  __shared__ float srcsh[NN*3];
  __shared__ float refsh[NN*3];
  __shared__ float c3sh[NN];
  __shared__ unsigned char smk[NN], rmk[NN];
  __shared__ float candv[4][96];
  __shared__ int   candi[4][96];
  __shared__ int   wcnt[4];
  __shared__ int   woff[4];
  __shared__ int   bbase;
  __shared__ float red[4][17];
  __shared__ int smode;
  const int b = blockIdx.x, t = threadIdx.x;
  const int w = t >> 6, l = t & 63;

  if (t < 64){
    unsigned v = ((const unsigned*)rmaskp)[t];
    bool n01 = !(v == 0u || v == 1u);
    bool nf  = !(v == 0u || v == 0x3F800000u);
    unsigned long long b01 = __ballot(n01), bf = __ballot(nf);
    if (t == 0) smode = (b01 == 0ull) ? 0 : ((bf == 0ull) ? 2 : 1);
  }
  if (t < 4) wcnt[t] = 0;
  for (int i = t; i < NN*3; i += 256){
    srcsh[i] = srcp[b*NN*3 + i];
    refsh[i] = refp[b*NN*3 + i];
  }
  if (t < NN) c3sh[t] = c3g[b*NN + t];
  __syncthreads();       // smode ready
  if (t < NN){
    int mode = smode;
    smk[t] = read_mask(smaskp, b*NN + t, mode) ? 1 : 0;
    rmk[t] = read_mask(rmaskp, b*NN + t, mode) ? 1 : 0;
  }
  __syncthreads();

  // 5 accumulators per column slot (10 live floats total)
  float cn0=0.f, A0=0.f, Rx0=0.f, Ry0=0.f, Rz0=0.f;
  float cn1=0.f, A1=0.f, Rx1=0.f, Ry1=0.f, Rz1=0.f;
  const float c3_0 = c3sh[l], c3_1 = c3sh[l + 64];
  const int sm0 = smk[l], sm1 = smk[l + 64];

  const float* base = score + (size_t)b*NN*NN;
  for (int rr = 0; rr < 32; rr++){
    const int r = w*32 + rr;
    const float v0 = base[r*NN + l];
    const float v1 = base[r*NN + l + 64];
    // row top-3 via butterfly merge of sorted triples
    float a1 = fmaxf(v0, v1), a2 = fminf(v0, v1), a3 = -1e30f;
#pragma unroll
    for (int st = 0; st < 6; st++){
      const int mask = 1 << st;
      float o1 = __shfl_xor(a1, mask);
      float o2 = __shfl_xor(a2, mask);
      float o3 = __shfl_xor(a3, mask);
      float m1 = fmaxf(a1, o1);
      float m2 = fmaxf(fminf(a1, o1), fmaxf(a2, o2));
      float m3 = fmaxf(fmaxf(fminf(a1, o2), fminf(a2, o1)), fmaxf(a3, o3));
      a1 = m1; a2 = m2; a3 = m3;
    }
    const float r3 = a3;
    const bool rmv = rmk[r] != 0;
    const float rx = refsh[r*3+0], ry = refsh[r*3+1], rz = refsh[r*3+2];
    float e0 = 0.f, e1 = 0.f;
    bool k0 = false, k1 = false;
    if (rmv && sm0 && v0 >= r3 && v0 >= c3_0){
      e0 = expf(v0); k0 = (e0 > 0.05f);
    }
    if (rmv && sm1 && v1 >= r3 && v1 >= c3_1){
      e1 = expf(v1); k1 = (e1 > 0.05f);
    }
    if (k0){ cn0 += 1.f; A0 += e0; Rx0 += e0*rx; Ry0 += e0*ry; Rz0 += e0*rz; }
    if (k1){ cn1 += 1.f; A1 += e1; Rx1 += e1*rx; Ry1 += e1*ry; Rz1 += e1*rz; }
    // wave-compact candidates into per-wave LDS buffer (<=3/row barring ties)
    unsigned long long B0 = __ballot(k0);
    unsigned long long B1 = __ballot(k1);
    int n0 = __popcll(B0), n1 = __popcll(B1);
    if (n0 + n1 > 0){
      int wb = 0;
      if (l == 0){ wb = wcnt[w]; wcnt[w] = wb + n0 + n1; }
      wb = __shfl(wb, 0);
      unsigned long long lt = (l == 0) ? 0ull : (~0ull >> (64 - l));
      if (k0){
        int pos = wb + (int)__popcll(B0 & lt);
        if (pos < 96){ candv[w][pos] = e0; candi[w][pos] = (b<<14)|(r<<7)|l; }
      }
      if (k1){
        int pos = wb + n0 + (int)__popcll(B1 & lt);
        if (pos < 96){ candv[w][pos] = e1; candi[w][pos] = (b<<14)|(r<<7)|(l+64); }
      }
    }
  }
  // block-level candidate copy-out: ONE global atomic per block
  __syncthreads();
  if (t == 0){
    int c0 = wcnt[0] > 96 ? 96 : wcnt[0];
    int c1 = wcnt[1] > 96 ? 96 : wcnt[1];
    int c2 = wcnt[2] > 96 ? 96 : wcnt[2];
    int c3 = wcnt[3] > 96 ? 96 : wcnt[3];
    woff[0] = 0; woff[1] = c0; woff[2] = c0 + c1; woff[3] = c0 + c1 + c2;
    bbase = atomicAdd(&hdr[0], c0 + c1 + c2 + c3);
  }
  __syncthreads();
  {
    int total = wcnt[w]; if (total > 96) total = 96;
    int gbase = bbase + woff[w];
    for (int i = l; i < total; i += 64){
      int pos = gbase + i;
      if (pos < CAND_CAP){ cand_vals[pos] = candv[w][i]; cand_idx[pos] = candi[w][i]; }
    }
  }
  // expand 10 accumulators -> 17 stats (src is lane-invariant per column slot)
  {
    const float sx0 = srcsh[l*3+0], sy0 = srcsh[l*3+1], sz0 = srcsh[l*3+2];
    const float sx1 = srcsh[(l+64)*3+0], sy1 = srcsh[(l+64)*3+1], sz1 = srcsh[(l+64)*3+2];
#define WSUM(VAL, IDX) { float v_ = (VAL); \
    for (int o_ = 32; o_ > 0; o_ >>= 1) v_ += __shfl_down(v_, o_); \
    if (l == 0) red[w][IDX] = v_; }
    WSUM(cn0 + cn1, 0)
    WSUM(A0 + A1, 1)
    WSUM(Rx0 + Rx1, 2)
    WSUM(Ry0 + Ry1, 3)
    WSUM(Rz0 + Rz1, 4)
    WSUM(A0*sx0 + A1*sx1, 5)
    WSUM(A0*sy0 + A1*sy1, 6)
    WSUM(A0*sz0 + A1*sz1, 7)
    WSUM(sx0*Rx0 + sx1*Rx1, 8)
    WSUM(sx0*Ry0 + sx1*Ry1, 9)
    WSUM(sx0*Rz0 + sx1*Rz1, 10)
    WSUM(sy0*Rx0 + sy1*Rx1, 11)
    WSUM(sy0*Ry0 + sy1*Ry1, 12)
    WSUM(sy0*Rz0 + sy1*Rz1, 13)
    WSUM(sz0*Rx0 + sz1*Rx1, 14)
    WSUM(sz0*Ry0 + sz1*Ry1, 15)
    WSUM(sz0*Rz0 + sz1*Rz1, 16)
#undef WSUM
  }
  __syncthreads();
  if (t == 0){
    float tot[17];
#pragma unroll
    for (int k = 0; k < 17; k++)
      tot[k] = red[0][k] + red[1][k] + red[2][k] + red[3][k];
    float Wm = tot[1];
    float denom = Wm + 1e-5f;
    float idenom = 1.f / denom;
    float s = Wm * idenom;
    float rcv[3] = { tot[2]*idenom, tot[3]*idenom, tot[4]*idenom };
    float scv[3] = { tot[5]*idenom, tot[6]*idenom, tot[7]*idenom };
    float* o = &Hsr[b*15];
#pragma unroll
    for (int c = 0; c < 3; c++)
#pragma unroll
      for (int d = 0; d < 3; d++)
        o[c*3+d] = tot[8 + c*3 + d]*idenom - (2.f - s)*scv[c]*rcv[d];
    o[9]=scv[0]; o[10]=scv[1]; o[11]=scv[2];
    o[12]=rcv[0]; o[13]=rcv[1]; o[14]=rcv[2];
    pcount[b] = (int)(tot[0] + 0.5f);
  }
}

// ---------------- K3a: grid histogram of top-12 key bits (LDS-local first) ----
__global__ __launch_bounds__(256) void k3a_kernel(
    const int* hdr, const float* __restrict__ cand_vals, int* hist)
{
  __shared__ int lh[NBIN1];
  int t = threadIdx.x;
  int Nc = hdr[0]; if (Nc > CAND_CAP) Nc = CAND_CAP;
  for (int j = t; j < NBIN1; j += 256) lh[j] = 0;
  __syncthreads();
  for (int i = blockIdx.x*256 + t; i < Nc; i += gridDim.x*256)
    atomicAdd(&lh[__float_as_uint(cand_vals[i]) >> 20], 1);
  __syncthreads();
  for (int j = t; j < NBIN1; j += 256)
    if (lh[j]) atomicAdd(&hist[j], lh[j]);
}

// ---------------- K3c: parallel per-block boundary-find + grid partition ------
__global__ __launch_bounds__(256) void k3c_kernel(
    int* hdr, const int* __restrict__ hist,
    const float* __restrict__ cand_vals, const int* __restrict__ cand_idx,
    float* sel_vals, int* sel_idx, float* eq_vals, int* eq_idx)
{
  __shared__ int wtot[4];
  __shared__ int sb[2];
  const int t = threadIdx.x, lane = t & 63, wv = t >> 6;
  int Nc = hdr[0]; if (Nc > CAND_CAP) Nc = CAND_CAP;
  if (Nc <= LIMIT){
    if (t == 0){ sb[0] = -1; sb[1] = 0; if (blockIdx.x == 0){ hdr[4] = -1; hdr[5] = 0; } }
    __syncthreads();
  } else {
    const int chunkIdx = 255 - t;
    int csum = 0;
    for (int j = 0; j < 16; j++) csum += hist[chunkIdx*16 + j];
    int incl = csum;
    for (int off = 1; off < 64; off <<= 1){ int y = __shfl_up(incl, off); if (lane >= off) incl += y; }
    if (lane == 63) wtot[wv] = incl;
    __syncthreads();
    int wbase = 0;
    for (int w = 0; w < wv; w++) wbase += wtot[w];
    int P = wbase + incl;
    int P_prev = P - csum;
    if (P_prev < LIMIT && P >= LIMIT){
      int cum = P_prev, bin1 = chunkIdx*16, need = 0;
      for (int b2 = chunkIdx*16 + 15; b2 >= chunkIdx*16; b2--){
        int h = hist[b2];
        if (cum + h >= LIMIT){ bin1 = b2; need = LIMIT - cum; break; }
        cum += h;
      }
      sb[0] = bin1; sb[1] = need;
      if (blockIdx.x == 0){ hdr[4] = bin1; hdr[5] = need; }
    }
    __syncthreads();
  }
  int bin1 = sb[0];
  for (int i = blockIdx.x*256 + t; i < Nc; i += gridDim.x*256){
    float v = cand_vals[i];
    if (bin1 < 0){
      int p = atomicAdd(&hdr[2], 1);
      if (p < LIMIT){ sel_vals[p] = v; sel_idx[p] = cand_idx[i]; }
      continue;
    }
    int bin = (int)(__float_as_uint(v) >> 20);
    if (bin > bin1){
      int p = atomicAdd(&hdr[2], 1);
      if (p < LIMIT){ sel_vals[p] = v; sel_idx[p] = cand_idx[i]; }
    } else if (bin == bin1){
      int q = atomicAdd(&hdr[1], 1);
      if (q < EQCAP){ eq_vals[q] = v; eq_idx[q] = cand_idx[i]; }
    }
  }
}

// ---------------- K3d: refine boundary bin + zero-fill + gather ---------------
__global__ __launch_bounds__(1024) void k3d_kernel(
    const int* hdr, const float* __restrict__ eq_vals, const int* __restrict__ eq_idx,
    float* sel_vals, int* sel_idx,
    const float* __restrict__ refp, const float* __restrict__ srcp,
    float* sel_ref, float* sel_src)
{
  __shared__ int hist[2048];
  __shared__ int eqsh[2048];
  __shared__ int wtot[16];
  __shared__ int bpair[2];
  __shared__ int sh[2];
  const int t = threadIdx.x, lane = t & 63, wv = t >> 6;
  const int bin1 = hdr[4];
  int nAbove = hdr[2]; if (nAbove > LIMIT) nAbove = LIMIT;

  auto find_boundary = [&](int need){
    int i0 = 2047 - 2*t, i1 = 2046 - 2*t;
    int g0 = hist[i0], g1 = hist[i1];
    int local = g0 + g1;
    int incl = local;
    for (int off = 1; off < 64; off <<= 1){ int y = __shfl_up(incl, off); if (lane >= off) incl += y; }
    if (lane == 63) wtot[wv] = incl;
    __syncthreads();
    int wbase = 0;
    for (int w = 0; w < wv; w++) wbase += wtot[w];
    int P_prev = wbase + incl - local;
    int P0 = P_prev + g0;
    if (P0 >= need && P_prev < need){ bpair[0] = i0; bpair[1] = need - P_prev; }
    int P1 = P0 + g1;
    if (P1 >= need && P0 < need){ bpair[0] = i1; bpair[1] = need - P0; }
    __syncthreads();
  };

  bool done = false;
  if (bin1 < 0){
    for (int i = t; i < LIMIT; i += 1024)
      if (i >= nAbove){ sel_vals[i] = 0.f; sel_idx[i] = 0; }
    done = true;
  }
  int neq = 0, need = 0;
  if (!done){
    neq = hdr[1]; if (neq > EQCAP) neq = EQCAP;
    need = hdr[5];
    if (need >= neq){
      for (int i = t; i < neq; i += 1024){ sel_vals[nAbove+i] = eq_vals[i]; sel_idx[nAbove+i] = eq_idx[i]; }
      for (int i = t; i < LIMIT; i += 1024)
        if (i >= nAbove + neq){ sel_vals[i] = 0.f; sel_idx[i] = 0; }
      done = true;
    }
  }
  if (!done){
    for (int i = t; i < 2048; i += 1024) hist[i] = 0;
    __syncthreads();
    for (int i = t; i < neq; i += 1024)
      atomicAdd(&hist[(__float_as_uint(eq_vals[i]) >> 9) & 0x7FF], 1);
    __syncthreads();
    find_boundary(need);
    int binA = bpair[0], need2 = bpair[1];
    __syncthreads();
    for (int i = t; i < 2048; i += 1024) hist[i] = 0;
    __syncthreads();
    for (int i = t; i < neq; i += 1024){
      unsigned k = __float_as_uint(eq_vals[i]);
      if ((int)((k >> 9) & 0x7FF) == binA) atomicAdd(&hist[k & 0x1FF], 1);
    }
    __syncthreads();
    find_boundary(need2);
    unsigned Tlow = (((unsigned)binA) << 9) | (unsigned)bpair[0];
    unsigned Tkey = (((unsigned)bin1) << 20) | Tlow;
    if (t == 0){ sh[0] = 0; sh[1] = 0; }
    __syncthreads();
    for (int i = t; i < neq; i += 1024){
      unsigned k = __float_as_uint(eq_vals[i]);
      unsigned k20 = k & 0xFFFFF;
      if (k20 > Tlow){
        int p = atomicAdd(&sh[0], 1);
        sel_vals[nAbove + p] = eq_vals[i]; sel_idx[nAbove + p] = eq_idx[i];
      } else if (k20 == Tlow){
        int q = atomicAdd(&sh[1], 1);
        if (q < 2048) eqsh[q] = eq_idx[i];
      }
    }
    __syncthreads();
    if (t == 0){
      int na2 = sh[0];
      int ne2 = sh[1]; if (ne2 > 2048) ne2 = 2048;
      int take = need - na2; if (take > ne2) take = ne2; if (take < 0) take = 0;
      if (nAbove + na2 + take > LIMIT) take = LIMIT - nAbove - na2;
      for (int j = 0; j < take; j++){
        int mi = j;
        for (int l2 = j+1; l2 < ne2; l2++) if (eqsh[l2] < eqsh[mi]) mi = l2;
        int tmp = eqsh[j]; eqsh[j] = eqsh[mi]; eqsh[mi] = tmp;
        sel_vals[nAbove + na2 + j] = __uint_as_float(Tkey);
        sel_idx[nAbove + na2 + j] = eqsh[j];
      }
      for (int j = nAbove + na2 + take; j < LIMIT; j++){ sel_vals[j] = 0.f; sel_idx[j] = 0; }
    }
  }
  __syncthreads();
  for (int p = t; p < LIMIT; p += 1024){
    int idx = sel_idx[p];
    int b = idx >> 14, rr = (idx >> 7) & 127, ss = idx & 127;
#pragma unroll
    for (int c = 0; c < 3; c++){
      sel_ref[p*3+c] = refp[(b*NN+rr)*3+c];
      sel_src[p*3+c] = srcp[(b*NN+ss)*3+c];
    }
  }
}

// ---------------- K45: per-block Kabsch + inlier counts + last-block refine ---
__global__ __launch_bounds__(256) void k45_kernel(
    const float* __restrict__ Hsr, float* __restrict__ localT,
    const float* __restrict__ sel_vals, const float* __restrict__ sel_ref,
    const float* __restrict__ sel_src, const int* __restrict__ pcount,
    int* counts, int* hdr, float* out)
{
  __shared__ float Tsh[12];
  __shared__ int ired[4];
  __shared__ int lastsh;
  __shared__ double dred[4][16];
  __shared__ long long lred[4];
  __shared__ float RT[12];
  __shared__ int sbest;
  const int b = blockIdx.x, t = threadIdx.x, lane = t & 63, wv = t >> 6;

  if (t == 0){
    const float* o = &Hsr[b*15];
    float r00,r01,r02,r10,r11,r12,r20,r21,r22;
    kabsch9(o[0],o[1],o[2], o[3],o[4],o[5], o[6],o[7],o[8],
            r00,r01,r02,r10,r11,r12,r20,r21,r22);
    Tsh[0]=r00; Tsh[1]=r01; Tsh[2]=r02;
    Tsh[3]=r10; Tsh[4]=r11; Tsh[5]=r12;
    Tsh[6]=r20; Tsh[7]=r21; Tsh[8]=r22;
    Tsh[9]  = o[12] - (r00*o[9] + r01*o[10] + r02*o[11]);
    Tsh[10] = o[13] - (r10*o[9] + r11*o[10] + r12*o[11]);
    Tsh[11] = o[14] - (r20*o[9] + r21*o[10] + r22*o[11]);
  }
  __syncthreads();
  if (t < 12) localT[b*12 + t] = Tsh[t];

  {
    float R00=Tsh[0],R01=Tsh[1],R02=Tsh[2],R10=Tsh[3],R11=Tsh[4],R12=Tsh[5];
    float R20=Tsh[6],R21=Tsh[7],R22=Tsh[8];
    float tx=Tsh[9], ty=Tsh[10], tz=Tsh[11];
    int c = 0;
    for (int p = t; p < LIMIT; p += 256){
      float v = sel_vals[p];
      if (!(v > 0.f)) continue;
      float sx=sel_src[p*3], sy=sel_src[p*3+1], sz=sel_src[p*3+2];
      float rx=sel_ref[p*3], ry=sel_ref[p*3+1], rz=sel_ref[p*3+2];
      float ax = R00*sx + R01*sy + R02*sz + tx;
      float ay = R10*sx + R11*sy + R12*sz + ty;
      float az = R20*sx + R21*sy + R22*sz + tz;
      float dx = rx-ax, dy = ry-ay, dz = rz-az;
      if (sqrtf(dx*dx + dy*dy + dz*dz) < 0.1f) c++;
    }
    for (int off2 = 32; off2 > 0; off2 >>= 1) c += __shfl_down(c, off2);
    if (lane == 0) ired[wv] = c;
    __syncthreads();
    if (t == 0){
      counts[b] = (pcount[b] >= 3) ? (ired[0]+ired[1]+ired[2]+ired[3]) : -1;
      __threadfence();
      int d = atomicAdd(&hdr[6], 1);
      lastsh = (d == BB - 1) ? 1 : 0;
    }
    __syncthreads();
    if (!lastsh) return;
    __threadfence();
  }

  {
    long long key = (long long)0x8000000000000000LL;
    for (int bb = t; bb < BB; bb += 256){
      long long kk = ((long long)(counts[bb] + 2) << 32) | (long long)(511 - bb);
      if (kk > key) key = kk;
    }
    for (int off2 = 32; off2 > 0; off2 >>= 1){ long long o = __shfl_down(key, off2); if (o > key) key = o; }
    if (lane == 0) lred[wv] = key;
    __syncthreads();
    if (t == 0){
      long long m = lred[0];
#pragma unroll
      for (int w = 1; w < 4; w++) if (lred[w] > m) m = lred[w];
      sbest = 511 - (int)(m & 0xFFFFFFFFLL);
    }
    __syncthreads();
    if (t < 12) RT[t] = localT[sbest*12 + t];
    __syncthreads();

    for (int iter = 0; iter < 5; iter++){
      float R00=RT[0],R01=RT[1],R02=RT[2];
      float R10=RT[3],R11=RT[4],R12=RT[5];
      float R20=RT[6],R21=RT[7],R22=RT[8];
      float tx=RT[9], ty=RT[10], tz=RT[11];
      double a[16];
#pragma unroll
      for (int k = 0; k < 16; k++) a[k] = 0.0;
      for (int p = t; p < LIMIT; p += 256){
        float v = sel_vals[p];
        if (!(v > 0.f)) continue;
        float sx=sel_src[p*3], sy=sel_src[p*3+1], sz=sel_src[p*3+2];
        float rx=sel_ref[p*3], ry=sel_ref[p*3+1], rz=sel_ref[p*3+2];
        float ax = R00*sx + R01*sy + R02*sz + tx;
        float ay = R10*sx + R11*sy + R12*sz + ty;
        float az = R20*sx + R21*sy + R22*sz + tz;
        float dx = rx-ax, dy = ry-ay, dz = rz-az;
        if (sqrtf(dx*dx + dy*dy + dz*dz) < 0.1f){
          double w = (double)v;
          a[0] += w;
          a[1] += w*sx; a[2] += w*sy; a[3] += w*sz;
          a[4] += w*rx; a[5] += w*ry; a[6] += w*rz;
          a[7]  += w*sx*rx; a[8]  += w*sx*ry; a[9]  += w*sx*rz;
          a[10] += w*sy*rx; a[11] += w*sy*ry; a[12] += w*sy*rz;
          a[13] += w*sz*rx; a[14] += w*sz*ry; a[15] += w*sz*rz;
        }
      }
#pragma unroll
      for (int k = 0; k < 16; k++){
        double v = a[k];
        for (int off2 = 32; off2 > 0; off2 >>= 1) v += __shfl_down(v, off2);
        if (lane == 0) dred[wv][k] = v;
      }
      __syncthreads();
      if (t == 0){
        double tot[16];
#pragma unroll
        for (int k = 0; k < 16; k++) tot[k] = dred[0][k]+dred[1][k]+dred[2][k]+dred[3][k];
        double W = tot[0], denom = W + 1e-5;
        double inv = 1.0 / denom;
        double s = W * inv;
        double scv[3] = { tot[1]*inv, tot[2]*inv, tot[3]*inv };
        double rcv[3] = { tot[4]*inv, tot[5]*inv, tot[6]*inv };
        float h00 = (float)(tot[7]*inv  - (2.0 - s)*scv[0]*rcv[0]);
        float h01 = (float)(tot[8]*inv  - (2.0 - s)*scv[0]*rcv[1]);
        float h02 = (float)(tot[9]*inv  - (2.0 - s)*scv[0]*rcv[2]);
        float h10 = (float)(tot[10]*inv - (2.0 - s)*scv[1]*rcv[0]);
        float h11 = (float)(tot[11]*inv - (2.0 - s)*scv[1]*rcv[1]);
        float h12 = (float)(tot[12]*inv - (2.0 - s)*scv[1]*rcv[2]);
        float h20 = (float)(tot[13]*inv - (2.0 - s)*scv[2]*rcv[0]);
        float h21 = (float)(tot[14]*inv - (2.0 - s)*scv[2]*rcv[1]);
        float h22 = (float)(tot[15]*inv - (2.0 - s)*scv[2]*rcv[2]);
        float r00,r01,r02,r10,r11,r12,r20,r21,r22;
        kabsch9(h00,h01,h02,h10,h11,h12,h20,h21,h22,
                r00,r01,r02,r10,r11,r12,r20,r21,r22);
        RT[0]=r00; RT[1]=r01; RT[2]=r02;
        RT[3]=r10; RT[4]=r11; RT[5]=r12;
        RT[6]=r20; RT[7]=r21; RT[8]=r22;
        RT[9]  = (float)(rcv[0] - ((double)r00*scv[0] + (double)r01*scv[1] + (double)r02*scv[2]));
        RT[10] = (float)(rcv[1] - ((double)r10*scv[0] + (double)r11*scv[1] + (double)r12*scv[2]));
        RT[11] = (float)(rcv[2] - ((double)r20*scv[0] + (double)r21*scv[1] + (double)r22*scv[2]));
      }
      __syncthreads();
    }
    if (t == 0){
      out[0]=RT[0];  out[1]=RT[1];  out[2]=RT[2];  out[3]=RT[9];
      out[4]=RT[3];  out[5]=RT[4];  out[6]=RT[5];  out[7]=RT[10];
      out[8]=RT[6];  out[9]=RT[7];  out[10]=RT[8]; out[11]=RT[11];
      out[12]=0.f; out[13]=0.f; out[14]=0.f; out[15]=1.f;
    }
  }
}

// ---------------- host launcher -----------------------------------------------
extern "C" void kernel_launch(void* const* d_in, const int* in_sizes, int n_in,
                              void* d_out, int out_size, void* d_ws, size_t ws_size,
                              hipStream_t stream){
  const float* score = (const float*)d_in[0];
  const float* refp  = (const float*)d_in[1];
  const float* srcp  = (const float*)d_in[2];
  const void*  rmask = d_in[3];
  const void*  smask = d_in[4];

  char* ws = (char*)d_ws;
  size_t off = 0;
  int* hdr = (int*)(ws + off);            off += 256;
  int* hist = (int*)(ws + off);           off += (size_t)NBIN1*4;
  float* cand_vals = (float*)(ws + off);  off += (size_t)CAND_CAP*4;
  int* cand_idx = (int*)(ws + off);       off += (size_t)CAND_CAP*4;
  float* eq_vals = (float*)(ws + off);    off += (size_t)EQCAP*4;
  int* eq_idx = (int*)(ws + off);         off += (size_t)EQCAP*4;
  float* c3g = (float*)(ws + off);        off += (size_t)BB*NN*4;
  float* Hsr = (float*)(ws + off);        off += (size_t)BB*15*4;
  int* pcount = (int*)(ws + off);         off += (size_t)BB*4;
  float* localT = (float*)(ws + off);     off += (size_t)BB*12*4;
  float* sel_vals = (float*)(ws + off);   off += (size_t)LIMIT*4;
  int* sel_idx = (int*)(ws + off);        off += (size_t)LIMIT*4;
  float* sel_ref = (float*)(ws + off);    off += (size_t)LIMIT*3*4;
  float* sel_src = (float*)(ws + off);    off += (size_t)LIMIT*3*4;
  int* counts = (int*)(ws + off);         off += (size_t)BB*4;

  hipMemsetAsync(ws, 0, 256 + (size_t)NBIN1*4, stream);
  hipLaunchKernelGGL(k1a_kernel, dim3(BB), dim3(128), 0, stream, score, c3g);
  hipLaunchKernelGGL(k1b_kernel, dim3(BB), dim3(256), 0, stream,
                     score, refp, srcp, rmask, smask, c3g,
                     hdr, cand_vals, cand_idx, Hsr, pcount);
  hipLaunchKernelGGL(k3a_kernel, dim3(64), dim3(256), 0, stream, hdr, cand_vals, hist);
  hipLaunchKernelGGL(k3c_kernel, dim3(64), dim3(256), 0, stream,
                     hdr, hist, cand_vals, cand_idx, sel_vals, sel_idx, eq_vals, eq_idx);
  hipLaunchKernelGGL(k3d_kernel, dim3(1), dim3(1024), 0, stream,
                     hdr, eq_vals, eq_idx, sel_vals, sel_idx, refp, srcp, sel_ref, sel_src);
  hipLaunchKernelGGL(k45_kernel, dim3(BB), dim3(256), 0, stream,
                     Hsr, localT, sel_vals, sel_ref, sel_src, pcount, counts, hdr, (float*)d_out);
}

// Round 12
// 281.945 us; speedup vs baseline: 2.3182x; 1.0113x over previous
//
#include <hip/hip_runtime.h>
#include <math.h>

#define BB 512
#define NN 128
#define CAND_CAP (512*384)
#define LIMIT 2048
#define EQCAP 16384
#define NBIN1 4096

// ---------------- mask decode (int32 / byte / float32 robustness) -------------
__device__ inline bool read_mask(const void* p, int i, int mode){
  if (mode == 0) return ((const int*)p)[i] != 0;
  if (mode == 1) return ((const unsigned char*)p)[i] != 0;
  return ((const float*)p)[i] != 0.0f;
}

__device__ inline float fast_rcp(float x){ return __builtin_amdgcn_rcpf(x); }
__device__ inline float fast_rsq(float x){ return __builtin_amdgcn_rsqf(x); }

__device__ inline void top3_update(float v, float& a1, float& a2, float& a3){
  if (v > a1){ a3=a2; a2=a1; a1=v; }
  else if (v > a2){ a3=a2; a2=v; }
  else if (v > a3){ a3=v; }
}

// ---------------- fp32 Kabsch, SCALAR-ONLY interface --------------------------
__device__ __forceinline__ void kabsch9(
    float h00, float h01, float h02,
    float h10, float h11, float h12,
    float h20, float h21, float h22,
    float& r00, float& r01, float& r02,
    float& r10, float& r11, float& r12,
    float& r20, float& r21, float& r22)
{
  float s00 = h00*h00 + h10*h10 + h20*h20;
  float s01 = h00*h01 + h10*h11 + h20*h21;
  float s02 = h00*h02 + h10*h12 + h20*h22;
  float s11 = h01*h01 + h11*h11 + h21*h21;
  float s12 = h01*h02 + h11*h12 + h21*h22;
  float s22 = h02*h02 + h12*h12 + h22*h22;
  float v00=1.f,v01=0.f,v02=0.f, v10=0.f,v11=1.f,v12=0.f, v20=0.f,v21=0.f,v22=1.f;
  for (int sweep = 0; sweep < 10; sweep++){
    float off  = s01*s01 + s02*s02 + s12*s12;
    float base = s00*s00 + s11*s11 + s22*s22;
    if (off <= base*1e-14f + 1e-36f) break;
    if (fabsf(s01) > 1e-30f){
      float tau = (s11 - s00) * fast_rcp(2.f*s01);
      float tt  = (tau >= 0.f ? 1.f : -1.f) * fast_rcp(fabsf(tau) + sqrtf(1.f + tau*tau));
      float c = fast_rsq(1.f + tt*tt), s = tt*c;
      float n00 = c*c*s00 - 2.f*c*s*s01 + s*s*s11;
      float n11 = s*s*s00 + 2.f*c*s*s01 + c*c*s11;
      float n02 = c*s02 - s*s12;
      float n12 = s*s02 + c*s12;
      s00=n00; s11=n11; s01=0.f; s02=n02; s12=n12;
      float a,b;
      a=v00; b=v01; v00=c*a-s*b; v01=s*a+c*b;
      a=v10; b=v11; v10=c*a-s*b; v11=s*a+c*b;
      a=v20; b=v21; v20=c*a-s*b; v21=s*a+c*b;
    }
    if (fabsf(s02) > 1e-30f){
      float tau = (s22 - s00) * fast_rcp(2.f*s02);
      float tt  = (tau >= 0.f ? 1.f : -1.f) * fast_rcp(fabsf(tau) + sqrtf(1.f + tau*tau));
      float c = fast_rsq(1.f + tt*tt), s = tt*c;
      float n00 = c*c*s00 - 2.f*c*s*s02 + s*s*s22;
      float n22 = s*s*s00 + 2.f*c*s*s02 + c*c*s22;
      float n01 = c*s01 - s*s12;
      float n12 = s*s01 + c*s12;
      s00=n00; s22=n22; s02=0.f; s01=n01; s12=n12;
      float a,b;
      a=v00; b=v02; v00=c*a-s*b; v02=s*a+c*b;
      a=v10; b=v12; v10=c*a-s*b; v12=s*a+c*b;
      a=v20; b=v22; v20=c*a-s*b; v22=s*a+c*b;
    }
    if (fabsf(s12) > 1e-30f){
      float tau = (s22 - s11) * fast_rcp(2.f*s12);
      float tt  = (tau >= 0.f ? 1.f : -1.f) * fast_rcp(fabsf(tau) + sqrtf(1.f + tau*tau));
      float c = fast_rsq(1.f + tt*tt), s = tt*c;
      float n11 = c*c*s11 - 2.f*c*s*s12 + s*s*s22;
      float n22 = s*s*s11 + 2.f*c*s*s12 + c*c*s22;
      float n01 = c*s01 - s*s02;
      float n02 = s*s01 + c*s02;
      s11=n11; s22=n22; s12=0.f; s01=n01; s02=n02;
      float a,b;
      a=v01; b=v02; v01=c*a-s*b; v02=s*a+c*b;
      a=v11; b=v12; v11=c*a-s*b; v12=s*a+c*b;
      a=v21; b=v22; v21=c*a-s*b; v22=s*a+c*b;
    }
  }
  float l0=s00, l1=s11, l2=s22;
  float a0=v00, a1=v10, a2=v20;
  float b0=v01, b1=v11, b2=v21;
  float c0=v02, c1=v12, c2=v22;
  if (l0 < l1){ float x; x=l0;l0=l1;l1=x; x=a0;a0=b0;b0=x; x=a1;a1=b1;b1=x; x=a2;a2=b2;b2=x; }
  if (l0 < l2){ float x; x=l0;l0=l2;l2=x; x=a0;a0=c0;c0=x; x=a1;a1=c1;c1=x; x=a2;a2=c2;c2=x; }
  if (l1 < l2){ float x; x=l1;l1=l2;l2=x; x=b0;b0=c0;c0=x; x=b1;b1=c1;c1=x; x=b2;b2=c2;c2=x; }
  float sig0 = sqrtf(fmaxf(l0, 0.f));
  if (!(sig0 > 1e-12f)){
    r00=1.f; r01=0.f; r02=0.f; r10=0.f; r11=1.f; r12=0.f; r20=0.f; r21=0.f; r22=1.f;
    return;
  }
  float u0x = h00*a0 + h01*a1 + h02*a2;
  float u0y = h10*a0 + h11*a1 + h12*a2;
  float u0z = h20*a0 + h21*a1 + h22*a2;
  float in0 = fast_rsq(u0x*u0x + u0y*u0y + u0z*u0z);
  u0x *= in0; u0y *= in0; u0z *= in0;
  float u1x = h00*b0 + h01*b1 + h02*b2;
  float u1y = h10*b0 + h11*b1 + h12*b2;
  float u1z = h20*b0 + h21*b1 + h22*b2;
  float dp = u1x*u0x + u1y*u0y + u1z*u0z;
  u1x -= dp*u0x; u1y -= dp*u0y; u1z -= dp*u0z;
  float d1 = u1x*u1x + u1y*u1y + u1z*u1z;
  if (sqrtf(d1) > sig0*1e-5f){
    float in1 = fast_rsq(d1);
    u1x *= in1; u1y *= in1; u1z *= in1;
  } else {
    float au0 = fabsf(u0x), au1 = fabsf(u0y), au2 = fabsf(u0z);
    float e0 = 0.f, e1 = 0.f, e2 = 0.f;
    if (au0 <= au1 && au0 <= au2) e0 = 1.f; else if (au1 <= au2) e1 = 1.f; else e2 = 1.f;
    float d2 = e0*u0x + e1*u0y + e2*u0z;
    u1x = e0 - d2*u0x; u1y = e1 - d2*u0y; u1z = e2 - d2*u0z;
    float nn = fast_rsq(u1x*u1x + u1y*u1y + u1z*u1z);
    u1x *= nn; u1y *= nn; u1z *= nn;
  }
  float u2x = u0y*u1z - u0z*u1y;
  float u2y = u0z*u1x - u0x*u1z;
  float u2z = u0x*u1y - u0y*u1x;
  float cxv = b1*c2 - b2*c1;
  float cyv = b2*c0 - b0*c2;
  float czv = b0*c1 - b1*c0;
  float detV = a0*cxv + a1*cyv + a2*czv;
  float dd = (detV >= 0.f) ? 1.f : -1.f;
  float w2x = dd*u2x, w2y = dd*u2y, w2z = dd*u2z;
  r00=a0*u0x + b0*u1x + c0*w2x;  r01=a0*u0y + b0*u1y + c0*w2y;  r02=a0*u0z + b0*u1z + c0*w2z;
  r10=a1*u0x + b1*u1x + c1*w2x;  r11=a1*u0y + b1*u1y + c1*w2y;  r12=a1*u0z + b1*u1z + c1*w2z;
  r20=a2*u0x + b2*u1x + c2*w2x;  r21=a2*u0y + b2*u1y + c2*w2y;  r22=a2*u0z + b2*u1z + c2*w2z;
}

// ---------------- K1a: column top-3 thresholds (tile-free, coalesced) ---------
__global__ __launch_bounds__(128) void k1a_kernel(
    const float* __restrict__ score, float* __restrict__ c3g)
{
  const int b = blockIdx.x, t = threadIdx.x;
  const float* col = score + (size_t)b*NN*NN + t;
  float a1=-1e30f, a2=-1e30f, a3=-1e30f;
#pragma unroll 8
  for (int n = 0; n < NN; n++){
    float v = col[n*NN];
    top3_update(v, a1, a2, a3);
  }
  c3g[b*NN + t] = a3;
}

// ---------------- K1b: wave-per-rows mutual top-3 + stats + candidates --------
__global__ __launch_bounds__(256) void k1b_kernel(
    const float* __restrict__ score, const float* __restrict__ refp,
    const float* __restrict__ srcp, const void* __restrict__ rmaskp,
    const void* __restrict__ smaskp, const float* __restrict__ c3g,
    int* hdr, float* cand_vals, int* cand_idx,
    float* Hsr, int* pcount)
{
  __shared__ float srcsh[NN*3];
  __shared__ float refsh[NN*3];
  __shared__ float c3sh[NN];
  __shared__ unsigned char smk[NN], rmk[NN];
  __shared__ float candv[4][96];
  __shared__ int   candi[4][96];
  __shared__ int   wcnt[4];
  __shared__ int   woff[4];
  __shared__ int   bbase;
  __shared__ float red[4][17];
  __shared__ int smode;
  const int b = blockIdx.x, t = threadIdx.x;
  const int w = t >> 6, l = t & 63;

  if (t < 64){
    unsigned v = ((const unsigned*)rmaskp)[t];
    bool n01 = !(v == 0u || v == 1u);
    bool nf  = !(v == 0u || v == 0x3F800000u);
    unsigned long long b01 = __ballot(n01), bf = __ballot(nf);
    if (t == 0) smode = (b01 == 0ull) ? 0 : ((bf == 0ull) ? 2 : 1);
  }
  if (t < 4) wcnt[t] = 0;
  for (int i = t; i < NN*3; i += 256){
    srcsh[i] = srcp[b*NN*3 + i];
    refsh[i] = refp[b*NN*3 + i];
  }
  if (t < NN) c3sh[t] = c3g[b*NN + t];
  __syncthreads();       // smode ready
  if (t < NN){
    int mode = smode;
    smk[t] = read_mask(smaskp, b*NN + t, mode) ? 1 : 0;
    rmk[t] = read_mask(rmaskp, b*NN + t, mode) ? 1 : 0;
  }
  __syncthreads();

  // 5 accumulators per column slot (10 live floats total)
  float cn0=0.f, A0=0.f, Rx0=0.f, Ry0=0.f, Rz0=0.f;
  float cn1=0.f, A1=0.f, Rx1=0.f, Ry1=0.f, Rz1=0.f;
  const float c3_0 = c3sh[l], c3_1 = c3sh[l + 64];
  const int sm0 = smk[l], sm1 = smk[l + 64];

  const float* base = score + (size_t)b*NN*NN;
  for (int rr = 0; rr < 32; rr++){
    const int r = w*32 + rr;
    const float v0 = base[r*NN + l];
    const float v1 = base[r*NN + l + 64];
    // row top-3 via butterfly merge of sorted triples
    float a1 = fmaxf(v0, v1), a2 = fminf(v0, v1), a3 = -1e30f;
#pragma unroll
    for (int st = 0; st < 6; st++){
      const int mask = 1 << st;
      float o1 = __shfl_xor(a1, mask);
      float o2 = __shfl_xor(a2, mask);
      float o3 = __shfl_xor(a3, mask);
      float m1 = fmaxf(a1, o1);
      float m2 = fmaxf(fminf(a1, o1), fmaxf(a2, o2));
      float m3 = fmaxf(fmaxf(fminf(a1, o2), fminf(a2, o1)), fmaxf(a3, o3));
      a1 = m1; a2 = m2; a3 = m3;
    }
    const float r3 = a3;
    const bool rmv = rmk[r] != 0;
    const float rx = refsh[r*3+0], ry = refsh[r*3+1], rz = refsh[r*3+2];
    float e0 = 0.f, e1 = 0.f;
    bool k0 = false, k1 = false;
    if (rmv && sm0 && v0 >= r3 && v0 >= c3_0){
      e0 = expf(v0); k0 = (e0 > 0.05f);
    }
    if (rmv && sm1 && v1 >= r3 && v1 >= c3_1){
      e1 = expf(v1); k1 = (e1 > 0.05f);
    }
    if (k0){ cn0 += 1.f; A0 += e0; Rx0 += e0*rx; Ry0 += e0*ry; Rz0 += e0*rz; }
    if (k1){ cn1 += 1.f; A1 += e1; Rx1 += e1*rx; Ry1 += e1*ry; Rz1 += e1*rz; }
    unsigned long long B0 = __ballot(k0);
    unsigned long long B1 = __ballot(k1);
    int n0 = __popcll(B0), n1 = __popcll(B1);
    if (n0 + n1 > 0){
      int wb = 0;
      if (l == 0){ wb = wcnt[w]; wcnt[w] = wb + n0 + n1; }
      wb = __shfl(wb, 0);
      unsigned long long lt = (l == 0) ? 0ull : (~0ull >> (64 - l));
      if (k0){
        int pos = wb + (int)__popcll(B0 & lt);
        if (pos < 96){ candv[w][pos] = e0; candi[w][pos] = (b<<14)|(r<<7)|l; }
      }
      if (k1){
        int pos = wb + n0 + (int)__popcll(B1 & lt);
        if (pos < 96){ candv[w][pos] = e1; candi[w][pos] = (b<<14)|(r<<7)|(l+64); }
      }
    }
  }
  // block-level candidate copy-out: ONE global atomic per block
  __syncthreads();
  if (t == 0){
    int c0 = wcnt[0] > 96 ? 96 : wcnt[0];
    int c1 = wcnt[1] > 96 ? 96 : wcnt[1];
    int c2 = wcnt[2] > 96 ? 96 : wcnt[2];
    int c3 = wcnt[3] > 96 ? 96 : wcnt[3];
    woff[0] = 0; woff[1] = c0; woff[2] = c0 + c1; woff[3] = c0 + c1 + c2;
    bbase = atomicAdd(&hdr[0], c0 + c1 + c2 + c3);
  }
  __syncthreads();
  {
    int total = wcnt[w]; if (total > 96) total = 96;
    int gbase = bbase + woff[w];
    for (int i = l; i < total; i += 64){
      int pos = gbase + i;
      if (pos < CAND_CAP){ cand_vals[pos] = candv[w][i]; cand_idx[pos] = candi[w][i]; }
    }
  }
  // expand 10 accumulators -> 17 stats (src is lane-invariant per column slot)
  {
    const float sx0 = srcsh[l*3+0], sy0 = srcsh[l*3+1], sz0 = srcsh[l*3+2];
    const float sx1 = srcsh[(l+64)*3+0], sy1 = srcsh[(l+64)*3+1], sz1 = srcsh[(l+64)*3+2];
#define WSUM(VAL, IDX) { float v_ = (VAL); \
    for (int o_ = 32; o_ > 0; o_ >>= 1) v_ += __shfl_down(v_, o_); \
    if (l == 0) red[w][IDX] = v_; }
    WSUM(cn0 + cn1, 0)
    WSUM(A0 + A1, 1)
    WSUM(Rx0 + Rx1, 2)
    WSUM(Ry0 + Ry1, 3)
    WSUM(Rz0 + Rz1, 4)
    WSUM(A0*sx0 + A1*sx1, 5)
    WSUM(A0*sy0 + A1*sy1, 6)
    WSUM(A0*sz0 + A1*sz1, 7)
    WSUM(sx0*Rx0 + sx1*Rx1, 8)
    WSUM(sx0*Ry0 + sx1*Ry1, 9)
    WSUM(sx0*Rz0 + sx1*Rz1, 10)
    WSUM(sy0*Rx0 + sy1*Rx1, 11)
    WSUM(sy0*Ry0 + sy1*Ry1, 12)
    WSUM(sy0*Rz0 + sy1*Rz1, 13)
    WSUM(sz0*Rx0 + sz1*Rx1, 14)
    WSUM(sz0*Ry0 + sz1*Ry1, 15)
    WSUM(sz0*Rz0 + sz1*Rz1, 16)
#undef WSUM
  }
  __syncthreads();
  if (t == 0){
    float tot[17];
#pragma unroll
    for (int k = 0; k < 17; k++)
      tot[k] = red[0][k] + red[1][k] + red[2][k] + red[3][k];
    float Wm = tot[1];
    float denom = Wm + 1e-5f;
    float idenom = 1.f / denom;
    float s = Wm * idenom;
    float rcv[3] = { tot[2]*idenom, tot[3]*idenom, tot[4]*idenom };
    float scv[3] = { tot[5]*idenom, tot[6]*idenom, tot[7]*idenom };
    float* o = &Hsr[b*15];
#pragma unroll
    for (int c = 0; c < 3; c++)
#pragma unroll
      for (int d = 0; d < 3; d++)
        o[c*3+d] = tot[8 + c*3 + d]*idenom - (2.f - s)*scv[c]*rcv[d];
    o[9]=scv[0]; o[10]=scv[1]; o[11]=scv[2];
    o[12]=rcv[0]; o[13]=rcv[1]; o[14]=rcv[2];
    pcount[b] = (int)(tot[0] + 0.5f);
  }
}

// ---------------- K3a: grid histogram of top-12 key bits (LDS-local first) ----
__global__ __launch_bounds__(256) void k3a_kernel(
    const int* hdr, const float* __restrict__ cand_vals, int* hist)
{
  __shared__ int lh[NBIN1];
  int t = threadIdx.x;
  int Nc = hdr[0]; if (Nc > CAND_CAP) Nc = CAND_CAP;
  for (int j = t; j < NBIN1; j += 256) lh[j] = 0;
  __syncthreads();
  for (int i = blockIdx.x*256 + t; i < Nc; i += gridDim.x*256)
    atomicAdd(&lh[__float_as_uint(cand_vals[i]) >> 20], 1);
  __syncthreads();
  for (int j = t; j < NBIN1; j += 256)
    if (lh[j]) atomicAdd(&hist[j], lh[j]);
}

// ---------------- K3c: parallel per-block boundary-find + grid partition ------
__global__ __launch_bounds__(256) void k3c_kernel(
    int* hdr, const int* __restrict__ hist,
    const float* __restrict__ cand_vals, const int* __restrict__ cand_idx,
    float* sel_vals, int* sel_idx, float* eq_vals, int* eq_idx)
{
  __shared__ int wtot[4];
  __shared__ int sb[2];
  const int t = threadIdx.x, lane = t & 63, wv = t >> 6;
  int Nc = hdr[0]; if (Nc > CAND_CAP) Nc = CAND_CAP;
  if (Nc <= LIMIT){
    if (t == 0){ sb[0] = -1; sb[1] = 0; if (blockIdx.x == 0){ hdr[4] = -1; hdr[5] = 0; } }
    __syncthreads();
  } else {
    const int chunkIdx = 255 - t;
    int csum = 0;
    for (int j = 0; j < 16; j++) csum += hist[chunkIdx*16 + j];
    int incl = csum;
    for (int off = 1; off < 64; off <<= 1){ int y = __shfl_up(incl, off); if (lane >= off) incl += y; }
    if (lane == 63) wtot[wv] = incl;
    __syncthreads();
    int wbase = 0;
    for (int w = 0; w < wv; w++) wbase += wtot[w];
    int P = wbase + incl;
    int P_prev = P - csum;
    if (P_prev < LIMIT && P >= LIMIT){
      int cum = P_prev, bin1 = chunkIdx*16, need = 0;
      for (int b2 = chunkIdx*16 + 15; b2 >= chunkIdx*16; b2--){
        int h = hist[b2];
        if (cum + h >= LIMIT){ bin1 = b2; need = LIMIT - cum; break; }
        cum += h;
      }
      sb[0] = bin1; sb[1] = need;
      if (blockIdx.x == 0){ hdr[4] = bin1; hdr[5] = need; }
    }
    __syncthreads();
  }
  int bin1 = sb[0];
  for (int i = blockIdx.x*256 + t; i < Nc; i += gridDim.x*256){
    float v = cand_vals[i];
    if (bin1 < 0){
      int p = atomicAdd(&hdr[2], 1);
      if (p < LIMIT){ sel_vals[p] = v; sel_idx[p] = cand_idx[i]; }
      continue;
    }
    int bin = (int)(__float_as_uint(v) >> 20);
    if (bin > bin1){
      int p = atomicAdd(&hdr[2], 1);
      if (p < LIMIT){ sel_vals[p] = v; sel_idx[p] = cand_idx[i]; }
    } else if (bin == bin1){
      int q = atomicAdd(&hdr[1], 1);
      if (q < EQCAP){ eq_vals[q] = v; eq_idx[q] = cand_idx[i]; }
    }
  }
}

// ---------------- K3d: refine boundary bin + zero-fill + gather ---------------
__global__ __launch_bounds__(1024) void k3d_kernel(
    const int* hdr, const float* __restrict__ eq_vals, const int* __restrict__ eq_idx,
    float* sel_vals, int* sel_idx,
    const float* __restrict__ refp, const float* __restrict__ srcp,
    float* sel_ref, float* sel_src)
{
  __shared__ int hist[2048];
  __shared__ int eqsh[2048];
  __shared__ int wtot[16];
  __shared__ int bpair[2];
  __shared__ int sh[2];
  const int t = threadIdx.x, lane = t & 63, wv = t >> 6;
  const int bin1 = hdr[4];
  int nAbove = hdr[2]; if (nAbove > LIMIT) nAbove = LIMIT;

  auto find_boundary = [&](int need){
    int i0 = 2047 - 2*t, i1 = 2046 - 2*t;
    int g0 = hist[i0], g1 = hist[i1];
    int local = g0 + g1;
    int incl = local;
    for (int off = 1; off < 64; off <<= 1){ int y = __shfl_up(incl, off); if (lane >= off) incl += y; }
    if (lane == 63) wtot[wv] = incl;
    __syncthreads();
    int wbase = 0;
    for (int w = 0; w < wv; w++) wbase += wtot[w];
    int P_prev = wbase + incl - local;
    int P0 = P_prev + g0;
    if (P0 >= need && P_prev < need){ bpair[0] = i0; bpair[1] = need - P_prev; }
    int P1 = P0 + g1;
    if (P1 >= need && P0 < need){ bpair[0] = i1; bpair[1] = need - P0; }
    __syncthreads();
  };

  bool done = false;
  if (bin1 < 0){
    for (int i = t; i < LIMIT; i += 1024)
      if (i >= nAbove){ sel_vals[i] = 0.f; sel_idx[i] = 0; }
    done = true;
  }
  int neq = 0, need = 0;
  if (!done){
    neq = hdr[1]; if (neq > EQCAP) neq = EQCAP;
    need = hdr[5];
    if (need >= neq){
      for (int i = t; i < neq; i += 1024){ sel_vals[nAbove+i] = eq_vals[i]; sel_idx[nAbove+i] = eq_idx[i]; }
      for (int i = t; i < LIMIT; i += 1024)
        if (i >= nAbove + neq){ sel_vals[i] = 0.f; sel_idx[i] = 0; }
      done = true;
    }
  }
  if (!done){
    for (int i = t; i < 2048; i += 1024) hist[i] = 0;
    __syncthreads();
    for (int i = t; i < neq; i += 1024)
      atomicAdd(&hist[(__float_as_uint(eq_vals[i]) >> 9) & 0x7FF], 1);
    __syncthreads();
    find_boundary(need);
    int binA = bpair[0], need2 = bpair[1];
    __syncthreads();
    for (int i = t; i < 2048; i += 1024) hist[i] = 0;
    __syncthreads();
    for (int i = t; i < neq; i += 1024){
      unsigned k = __float_as_uint(eq_vals[i]);
      if ((int)((k >> 9) & 0x7FF) == binA) atomicAdd(&hist[k & 0x1FF], 1);
    }
    __syncthreads();
    find_boundary(need2);
    unsigned Tlow = (((unsigned)binA) << 9) | (unsigned)bpair[0];
    unsigned Tkey = (((unsigned)bin1) << 20) | Tlow;
    if (t == 0){ sh[0] = 0; sh[1] = 0; }
    __syncthreads();
    for (int i = t; i < neq; i += 1024){
      unsigned k = __float_as_uint(eq_vals[i]);
      unsigned k20 = k & 0xFFFFF;
      if (k20 > Tlow){
        int p = atomicAdd(&sh[0], 1);
        sel_vals[nAbove + p] = eq_vals[i]; sel_idx[nAbove + p] = eq_idx[i];
      } else if (k20 == Tlow){
        int q = atomicAdd(&sh[1], 1);
        if (q < 2048) eqsh[q] = eq_idx[i];
      }
    }
    __syncthreads();
    if (t == 0){
      int na2 = sh[0];
      int ne2 = sh[1]; if (ne2 > 2048) ne2 = 2048;
      int take = need - na2; if (take > ne2) take = ne2; if (take < 0) take = 0;
      if (nAbove + na2 + take > LIMIT) take = LIMIT - nAbove - na2;
      for (int j = 0; j < take; j++){
        int mi = j;
        for (int l2 = j+1; l2 < ne2; l2++) if (eqsh[l2] < eqsh[mi]) mi = l2;
        int tmp = eqsh[j]; eqsh[j] = eqsh[mi]; eqsh[mi] = tmp;
        sel_vals[nAbove + na2 + j] = __uint_as_float(Tkey);
        sel_idx[nAbove + na2 + j] = eqsh[j];
      }
      for (int j = nAbove + na2 + take; j < LIMIT; j++){ sel_vals[j] = 0.f; sel_idx[j] = 0; }
    }
  }
  __syncthreads();
  for (int p = t; p < LIMIT; p += 1024){
    int idx = sel_idx[p];
    int b = idx >> 14, rr = (idx >> 7) & 127, ss = idx & 127;
#pragma unroll
    for (int c = 0; c < 3; c++){
      sel_ref[p*3+c] = refp[(b*NN+rr)*3+c];
      sel_src[p*3+c] = srcp[(b*NN+ss)*3+c];
    }
  }
}

// ---------------- K45: per-block Kabsch + inlier counts + last-block refine ---
// __launch_bounds__(256, 1): R11's default budget squeezed VGPR to 52, forcing
// the refine phase's 16 accumulators to scratch (~90us tail on one CU).
// Float accumulators (matches float32 JAX reference) + relaxed budget.
__global__ __launch_bounds__(256, 1) void k45_kernel(
    const float* __restrict__ Hsr, float* __restrict__ localT,
    const float* __restrict__ sel_vals, const float* __restrict__ sel_ref,
    const float* __restrict__ sel_src, const int* __restrict__ pcount,
    int* counts, int* hdr, float* out)
{
  __shared__ float Tsh[12];
  __shared__ int ired[4];
  __shared__ int lastsh;
  __shared__ float fred[4][16];
  __shared__ long long lred[4];
  __shared__ float RT[12];
  __shared__ int sbest;
  const int b = blockIdx.x, t = threadIdx.x, lane = t & 63, wv = t >> 6;

  if (t == 0){
    const float* o = &Hsr[b*15];
    float r00,r01,r02,r10,r11,r12,r20,r21,r22;
    kabsch9(o[0],o[1],o[2], o[3],o[4],o[5], o[6],o[7],o[8],
            r00,r01,r02,r10,r11,r12,r20,r21,r22);
    Tsh[0]=r00; Tsh[1]=r01; Tsh[2]=r02;
    Tsh[3]=r10; Tsh[4]=r11; Tsh[5]=r12;
    Tsh[6]=r20; Tsh[7]=r21; Tsh[8]=r22;
    Tsh[9]  = o[12] - (r00*o[9] + r01*o[10] + r02*o[11]);
    Tsh[10] = o[13] - (r10*o[9] + r11*o[10] + r12*o[11]);
    Tsh[11] = o[14] - (r20*o[9] + r21*o[10] + r22*o[11]);
  }
  __syncthreads();
  if (t < 12) localT[b*12 + t] = Tsh[t];

  {
    float R00=Tsh[0],R01=Tsh[1],R02=Tsh[2],R10=Tsh[3],R11=Tsh[4],R12=Tsh[5];
    float R20=Tsh[6],R21=Tsh[7],R22=Tsh[8];
    float tx=Tsh[9], ty=Tsh[10], tz=Tsh[11];
    int c = 0;
    for (int p = t; p < LIMIT; p += 256){
      float v = sel_vals[p];
      if (!(v > 0.f)) continue;
      float sx=sel_src[p*3], sy=sel_src[p*3+1], sz=sel_src[p*3+2];
      float rx=sel_ref[p*3], ry=sel_ref[p*3+1], rz=sel_ref[p*3+2];
      float ax = R00*sx + R01*sy + R02*sz + tx;
      float ay = R10*sx + R11*sy + R12*sz + ty;
      float az = R20*sx + R21*sy + R22*sz + tz;
      float dx = rx-ax, dy = ry-ay, dz = rz-az;
      if (sqrtf(dx*dx + dy*dy + dz*dz) < 0.1f) c++;
    }
    for (int off2 = 32; off2 > 0; off2 >>= 1) c += __shfl_down(c, off2);
    if (lane == 0) ired[wv] = c;
    __syncthreads();
    if (t == 0){
      counts[b] = (pcount[b] >= 3) ? (ired[0]+ired[1]+ired[2]+ired[3]) : -1;
      __threadfence();
      int d = atomicAdd(&hdr[6], 1);
      lastsh = (d == BB - 1) ? 1 : 0;
    }
    __syncthreads();
    if (!lastsh) return;
    __threadfence();
  }

  {
    long long key = (long long)0x8000000000000000LL;
    for (int bb = t; bb < BB; bb += 256){
      long long kk = ((long long)(counts[bb] + 2) << 32) | (long long)(511 - bb);
      if (kk > key) key = kk;
    }
    for (int off2 = 32; off2 > 0; off2 >>= 1){ long long o = __shfl_down(key, off2); if (o > key) key = o; }
    if (lane == 0) lred[wv] = key;
    __syncthreads();
    if (t == 0){
      long long m = lred[0];
#pragma unroll
      for (int w = 1; w < 4; w++) if (lred[w] > m) m = lred[w];
      sbest = 511 - (int)(m & 0xFFFFFFFFLL);
    }
    __syncthreads();
    if (t < 12) RT[t] = localT[sbest*12 + t];
    __syncthreads();

    for (int iter = 0; iter < 5; iter++){
      float R00=RT[0],R01=RT[1],R02=RT[2];
      float R10=RT[3],R11=RT[4],R12=RT[5];
      float R20=RT[6],R21=RT[7],R22=RT[8];
      float tx=RT[9], ty=RT[10], tz=RT[11];
      // 16 float accumulators as scalars (reference is float32 JAX)
      float a0=0.f,a1=0.f,a2=0.f,a3=0.f,a4=0.f,a5=0.f,a6=0.f,a7=0.f;
      float a8=0.f,a9=0.f,a10=0.f,a11=0.f,a12=0.f,a13=0.f,a14=0.f,a15=0.f;
      for (int p = t; p < LIMIT; p += 256){
        float v = sel_vals[p];
        if (!(v > 0.f)) continue;
        float sx=sel_src[p*3], sy=sel_src[p*3+1], sz=sel_src[p*3+2];
        float rx=sel_ref[p*3], ry=sel_ref[p*3+1], rz=sel_ref[p*3+2];
        float ax = R00*sx + R01*sy + R02*sz + tx;
        float ay = R10*sx + R11*sy + R12*sz + ty;
        float az = R20*sx + R21*sy + R22*sz + tz;
        float dx = rx-ax, dy = ry-ay, dz = rz-az;
        if (sqrtf(dx*dx + dy*dy + dz*dz) < 0.1f){
          a0 += v;
          a1 += v*sx; a2 += v*sy; a3 += v*sz;
          a4 += v*rx; a5 += v*ry; a6 += v*rz;
          a7  += v*sx*rx; a8  += v*sx*ry; a9  += v*sx*rz;
          a10 += v*sy*rx; a11 += v*sy*ry; a12 += v*sy*rz;
          a13 += v*sz*rx; a14 += v*sz*ry; a15 += v*sz*rz;
        }
      }
#define WRED(VAL, IDX) { float v_ = (VAL); \
      for (int o_ = 32; o_ > 0; o_ >>= 1) v_ += __shfl_down(v_, o_); \
      if (lane == 0) fred[wv][IDX] = v_; }
      WRED(a0, 0)  WRED(a1, 1)  WRED(a2, 2)  WRED(a3, 3)
      WRED(a4, 4)  WRED(a5, 5)  WRED(a6, 6)  WRED(a7, 7)
      WRED(a8, 8)  WRED(a9, 9)  WRED(a10,10) WRED(a11,11)
      WRED(a12,12) WRED(a13,13) WRED(a14,14) WRED(a15,15)
#undef WRED
      __syncthreads();
      if (t == 0){
        float tot[16];
#pragma unroll
        for (int k = 0; k < 16; k++) tot[k] = fred[0][k]+fred[1][k]+fred[2][k]+fred[3][k];
        float W = tot[0], denom = W + 1e-5f;
        float inv = 1.f / denom;
        float s = W * inv;
        float scx = tot[1]*inv, scy = tot[2]*inv, scz = tot[3]*inv;
        float rcx = tot[4]*inv, rcy = tot[5]*inv, rcz = tot[6]*inv;
        float f = 2.f - s;
        float h00 = tot[7]*inv  - f*scx*rcx;
        float h01 = tot[8]*inv  - f*scx*rcy;
        float h02 = tot[9]*inv  - f*scx*rcz;
        float h10 = tot[10]*inv - f*scy*rcx;
        float h11 = tot[11]*inv - f*scy*rcy;
        float h12 = tot[12]*inv - f*scy*rcz;
        float h20 = tot[13]*inv - f*scz*rcx;
        float h21 = tot[14]*inv - f*scz*rcy;
        float h22 = tot[15]*inv - f*scz*rcz;
        float r00,r01,r02,r10,r11,r12,r20,r21,r22;
        kabsch9(h00,h01,h02,h10,h11,h12,h20,h21,h22,
                r00,r01,r02,r10,r11,r12,r20,r21,r22);
        RT[0]=r00; RT[1]=r01; RT[2]=r02;
        RT[3]=r10; RT[4]=r11; RT[5]=r12;
        RT[6]=r20; RT[7]=r21; RT[8]=r22;
        RT[9]  = rcx - (r00*scx + r01*scy + r02*scz);
        RT[10] = rcy - (r10*scx + r11*scy + r12*scz);
        RT[11] = rcz - (r20*scx + r21*scy + r22*scz);
      }
      __syncthreads();
    }
    if (t == 0){
      out[0]=RT[0];  out[1]=RT[1];  out[2]=RT[2];  out[3]=RT[9];
      out[4]=RT[3];  out[5]=RT[4];  out[6]=RT[5];  out[7]=RT[10];
      out[8]=RT[6];  out[9]=RT[7];  out[10]=RT[8]; out[11]=RT[11];
      out[12]=0.f; out[13]=0.f; out[14]=0.f; out[15]=1.f;
    }
  }
}

// ---------------- host launcher -----------------------------------------------
extern "C" void kernel_launch(void* const* d_in, const int* in_sizes, int n_in,
                              void* d_out, int out_size, void* d_ws, size_t ws_size,
                              hipStream_t stream){
  const float* score = (const float*)d_in[0];
  const float* refp  = (const float*)d_in[1];
  const float* srcp  = (const float*)d_in[2];
  const void*  rmask = d_in[3];
  const void*  smask = d_in[4];

  char* ws = (char*)d_ws;
  size_t off = 0;
  int* hdr = (int*)(ws + off);            off += 256;
  int* hist = (int*)(ws + off);           off += (size_t)NBIN1*4;
  float* cand_vals = (float*)(ws + off);  off += (size_t)CAND_CAP*4;
  int* cand_idx = (int*)(ws + off);       off += (size_t)CAND_CAP*4;
  float* eq_vals = (float*)(ws + off);    off += (size_t)EQCAP*4;
  int* eq_idx = (int*)(ws + off);         off += (size_t)EQCAP*4;
  float* c3g = (float*)(ws + off);        off += (size_t)BB*NN*4;
  float* Hsr = (float*)(ws + off);        off += (size_t)BB*15*4;
  int* pcount = (int*)(ws + off);         off += (size_t)BB*4;
  float* localT = (float*)(ws + off);     off += (size_t)BB*12*4;
  float* sel_vals = (float*)(ws + off);   off += (size_t)LIMIT*4;
  int* sel_idx = (int*)(ws + off);        off += (size_t)LIMIT*4;
  float* sel_ref = (float*)(ws + off);    off += (size_t)LIMIT*3*4;
  float* sel_src = (float*)(ws + off);    off += (size_t)LIMIT*3*4;
  int* counts = (int*)(ws + off);         off += (size_t)BB*4;

  hipMemsetAsync(ws, 0, 256 + (size_t)NBIN1*4, stream);
  hipLaunchKernelGGL(k1a_kernel, dim3(BB), dim3(128), 0, stream, score, c3g);
  hipLaunchKernelGGL(k1b_kernel, dim3(BB), dim3(256), 0, stream,
                     score, refp, srcp, rmask, smask, c3g,
                     hdr, cand_vals, cand_idx, Hsr, pcount);
  hipLaunchKernelGGL(k3a_kernel, dim3(64), dim3(256), 0, stream, hdr, cand_vals, hist);
  hipLaunchKernelGGL(k3c_kernel, dim3(64), dim3(256), 0, stream,
                     hdr, hist, cand_vals, cand_idx, sel_vals, sel_idx, eq_vals, eq_idx);
  hipLaunchKernelGGL(k3d_kernel, dim3(1), dim3(1024), 0, stream,
                     hdr, eq_vals, eq_idx, sel_vals, sel_idx, refp, srcp, sel_ref, sel_src);
  hipLaunchKernelGGL(k45_kernel, dim3(BB), dim3(256), 0, stream,
                     Hsr, localT, sel_vals, sel_ref, sel_src, pcount, counts, hdr, (float*)d_out);
}

// Round 13
// 220.772 us; speedup vs baseline: 2.9606x; 1.2771x over previous
//
#include <hip/hip_runtime.h>
#include <math.h>

#define BB 512
#define NN 128
#define CAND_CAP (512*384)
#define LIMIT 2048
#define EQCAP 16384
#define NBIN1 4096

// ---------------- mask decode (int32 / byte / float32 robustness) -------------
__device__ inline bool read_mask(const void* p, int i, int mode){
  if (mode == 0) return ((const int*)p)[i] != 0;
  if (mode == 1) return ((const unsigned char*)p)[i] != 0;
  return ((const float*)p)[i] != 0.0f;
}

__device__ inline float fast_rcp(float x){ return __builtin_amdgcn_rcpf(x); }
__device__ inline float fast_rsq(float x){ return __builtin_amdgcn_rsqf(x); }

// ---------------- fp32 Kabsch, SCALAR-ONLY interface --------------------------
__device__ __forceinline__ void kabsch9(
    float h00, float h01, float h02,
    float h10, float h11, float h12,
    float h20, float h21, float h22,
    float& r00, float& r01, float& r02,
    float& r10, float& r11, float& r12,
    float& r20, float& r21, float& r22)
{
  float s00 = h00*h00 + h10*h10 + h20*h20;
  float s01 = h00*h01 + h10*h11 + h20*h21;
  float s02 = h00*h02 + h10*h12 + h20*h22;
  float s11 = h01*h01 + h11*h11 + h21*h21;
  float s12 = h01*h02 + h11*h12 + h21*h22;
  float s22 = h02*h02 + h12*h12 + h22*h22;
  float v00=1.f,v01=0.f,v02=0.f, v10=0.f,v11=1.f,v12=0.f, v20=0.f,v21=0.f,v22=1.f;
  for (int sweep = 0; sweep < 10; sweep++){
    float off  = s01*s01 + s02*s02 + s12*s12;
    float base = s00*s00 + s11*s11 + s22*s22;
    if (off <= base*1e-14f + 1e-36f) break;
    if (fabsf(s01) > 1e-30f){
      float tau = (s11 - s00) * fast_rcp(2.f*s01);
      float tt  = (tau >= 0.f ? 1.f : -1.f) * fast_rcp(fabsf(tau) + sqrtf(1.f + tau*tau));
      float c = fast_rsq(1.f + tt*tt), s = tt*c;
      float n00 = c*c*s00 - 2.f*c*s*s01 + s*s*s11;
      float n11 = s*s*s00 + 2.f*c*s*s01 + c*c*s11;
      float n02 = c*s02 - s*s12;
      float n12 = s*s02 + c*s12;
      s00=n00; s11=n11; s01=0.f; s02=n02; s12=n12;
      float a,b;
      a=v00; b=v01; v00=c*a-s*b; v01=s*a+c*b;
      a=v10; b=v11; v10=c*a-s*b; v11=s*a+c*b;
      a=v20; b=v21; v20=c*a-s*b; v21=s*a+c*b;
    }
    if (fabsf(s02) > 1e-30f){
      float tau = (s22 - s00) * fast_rcp(2.f*s02);
      float tt  = (tau >= 0.f ? 1.f : -1.f) * fast_rcp(fabsf(tau) + sqrtf(1.f + tau*tau));
      float c = fast_rsq(1.f + tt*tt), s = tt*c;
      float n00 = c*c*s00 - 2.f*c*s*s02 + s*s*s22;
      float n22 = s*s*s00 + 2.f*c*s*s02 + c*c*s22;
      float n01 = c*s01 - s*s12;
      float n12 = s*s01 + c*s12;
      s00=n00; s22=n22; s02=0.f; s01=n01; s12=n12;
      float a,b;
      a=v00; b=v02; v00=c*a-s*b; v02=s*a+c*b;
      a=v10; b=v12; v10=c*a-s*b; v12=s*a+c*b;
      a=v20; b=v22; v20=c*a-s*b; v22=s*a+c*b;
    }
    if (fabsf(s12) > 1e-30f){
      float tau = (s22 - s11) * fast_rcp(2.f*s12);
      float tt  = (tau >= 0.f ? 1.f : -1.f) * fast_rcp(fabsf(tau) + sqrtf(1.f + tau*tau));
      float c = fast_rsq(1.f + tt*tt), s = tt*c;
      float n11 = c*c*s11 - 2.f*c*s*s12 + s*s*s22;
      float n22 = s*s*s11 + 2.f*c*s*s12 + c*c*s22;
      float n01 = c*s01 - s*s02;
      float n02 = s*s01 + c*s02;
      s11=n11; s22=n22; s12=0.f; s01=n01; s02=n02;
      float a,b;
      a=v01; b=v02; v01=c*a-s*b; v02=s*a+c*b;
      a=v11; b=v12; v11=c*a-s*b; v12=s*a+c*b;
      a=v21; b=v22; v21=c*a-s*b; v22=s*a+c*b;
    }
  }
  float l0=s00, l1=s11, l2=s22;
  float a0=v00, a1=v10, a2=v20;
  float b0=v01, b1=v11, b2=v21;
  float c0=v02, c1=v12, c2=v22;
  if (l0 < l1){ float x; x=l0;l0=l1;l1=x; x=a0;a0=b0;b0=x; x=a1;a1=b1;b1=x; x=a2;a2=b2;b2=x; }
  if (l0 < l2){ float x; x=l0;l0=l2;l2=x; x=a0;a0=c0;c0=x; x=a1;a1=c1;c1=x; x=a2;a2=c2;c2=x; }
  if (l1 < l2){ float x; x=l1;l1=l2;l2=x; x=b0;b0=c0;c0=x; x=b1;b1=c1;c1=x; x=b2;b2=c2;c2=x; }
  float sig0 = sqrtf(fmaxf(l0, 0.f));
  if (!(sig0 > 1e-12f)){
    r00=1.f; r01=0.f; r02=0.f; r10=0.f; r11=1.f; r12=0.f; r20=0.f; r21=0.f; r22=1.f;
    return;
  }
  float u0x = h00*a0 + h01*a1 + h02*a2;
  float u0y = h10*a0 + h11*a1 + h12*a2;
  float u0z = h20*a0 + h21*a1 + h22*a2;
  float in0 = fast_rsq(u0x*u0x + u0y*u0y + u0z*u0z);
  u0x *= in0; u0y *= in0; u0z *= in0;
  float u1x = h00*b0 + h01*b1 + h02*b2;
  float u1y = h10*b0 + h11*b1 + h12*b2;
  float u1z = h20*b0 + h21*b1 + h22*b2;
  float dp = u1x*u0x + u1y*u0y + u1z*u0z;
  u1x -= dp*u0x; u1y -= dp*u0y; u1z -= dp*u0z;
  float d1 = u1x*u1x + u1y*u1y + u1z*u1z;
  if (sqrtf(d1) > sig0*1e-5f){
    float in1 = fast_rsq(d1);
    u1x *= in1; u1y *= in1; u1z *= in1;
  } else {
    float au0 = fabsf(u0x), au1 = fabsf(u0y), au2 = fabsf(u0z);
    float e0 = 0.f, e1 = 0.f, e2 = 0.f;
    if (au0 <= au1 && au0 <= au2) e0 = 1.f; else if (au1 <= au2) e1 = 1.f; else e2 = 1.f;
    float d2 = e0*u0x + e1*u0y + e2*u0z;
    u1x = e0 - d2*u0x; u1y = e1 - d2*u0y; u1z = e2 - d2*u0z;
    float nn = fast_rsq(u1x*u1x + u1y*u1y + u1z*u1z);
    u1x *= nn; u1y *= nn; u1z *= nn;
  }
  float u2x = u0y*u1z - u0z*u1y;
  float u2y = u0z*u1x - u0x*u1z;
  float u2z = u0x*u1y - u0y*u1x;
  float cxv = b1*c2 - b2*c1;
  float cyv = b2*c0 - b0*c2;
  float czv = b0*c1 - b1*c0;
  float detV = a0*cxv + a1*cyv + a2*czv;
  float dd = (detV >= 0.f) ? 1.f : -1.f;
  float w2x = dd*u2x, w2y = dd*u2y, w2z = dd*u2z;
  r00=a0*u0x + b0*u1x + c0*w2x;  r01=a0*u0y + b0*u1y + c0*w2y;  r02=a0*u0z + b0*u1z + c0*w2z;
  r10=a1*u0x + b1*u1x + c1*w2x;  r11=a1*u0y + b1*u1y + c1*w2y;  r12=a1*u0z + b1*u1z + c1*w2z;
  r20=a2*u0x + b2*u1x + c2*w2x;  r21=a2*u0y + b2*u1y + c2*w2y;  r22=a2*u0z + b2*u1z + c2*w2z;
}

// ---------------- K1: fused col-top3 + row-top3 + stats + candidates ----------
// 256 threads. Phase A: thread (h=t>>7, c=t&127) scans 64 rows of col c with
// BRANCHLESS top-3 (min/max only -> compiler keeps loads in flight; R12's
// branchy per-column kernel was 1 wave/SIMD latency-serial at 87us). LDS merge
// of half-triples -> c3sh. Phase B: R12 k1b body, reading L2-hot score.
__global__ __launch_bounds__(256) void k1_kernel(
    const float* __restrict__ score, const float* __restrict__ refp,
    const float* __restrict__ srcp, const void* __restrict__ rmaskp,
    const void* __restrict__ smaskp,
    int* hdr, float* cand_vals, int* cand_idx,
    float* Hsr, int* pcount)
{
  __shared__ float parts[2][NN][3];
  __shared__ float srcsh[NN*3];
  __shared__ float refsh[NN*3];
  __shared__ float c3sh[NN];
  __shared__ unsigned char smk[NN], rmk[NN];
  __shared__ float candv[4][96];
  __shared__ int   candi[4][96];
  __shared__ int   wcnt[4];
  __shared__ int   woff[4];
  __shared__ int   bbase;
  __shared__ float red[4][17];
  __shared__ int smode;
  const int b = blockIdx.x, t = threadIdx.x;
  const int w = t >> 6, l = t & 63;

  if (t < 64){
    unsigned v = ((const unsigned*)rmaskp)[t];
    bool n01 = !(v == 0u || v == 1u);
    bool nf  = !(v == 0u || v == 0x3F800000u);
    unsigned long long b01 = __ballot(n01), bf = __ballot(nf);
    if (t == 0) smode = (b01 == 0ull) ? 0 : ((bf == 0ull) ? 2 : 1);
  }
  if (t < 4) wcnt[t] = 0;
  for (int i = t; i < NN*3; i += 256){
    srcsh[i] = srcp[b*NN*3 + i];
    refsh[i] = refp[b*NN*3 + i];
  }

  // ---- phase A: column partial top-3 (coalesced, branchless) ----
  {
    const int c = t & 127, h = t >> 7;
    float a1=-1e30f, a2=-1e30f, a3=-1e30f;
    const float* colp = score + (size_t)b*NN*NN + (size_t)(h*64)*NN + c;
#pragma unroll 8
    for (int i = 0; i < 64; i++){
      float v = colp[i*NN];
      float m = fminf(a1, v);
      a1 = fmaxf(a1, v);
      a3 = fmaxf(a3, fminf(a2, m));
      a2 = fmaxf(a2, m);
    }
    parts[h][c][0]=a1; parts[h][c][1]=a2; parts[h][c][2]=a3;
  }
  __syncthreads();    // parts + smode + srcsh/refsh ready
  if (t < NN){
    float a1=parts[0][t][0], a2=parts[0][t][1], a3=parts[0][t][2];
    float b1=parts[1][t][0], b2=parts[1][t][1], b3=parts[1][t][2];
    // third-largest of union of two sorted triples
    c3sh[t] = fmaxf(fmaxf(fminf(a1,b2), fminf(a2,b1)), fmaxf(a3,b3));
    int mode = smode;
    smk[t] = read_mask(smaskp, b*NN + t, mode) ? 1 : 0;
    rmk[t] = read_mask(rmaskp, b*NN + t, mode) ? 1 : 0;
  }
  __syncthreads();

  // ---- phase B: wave w rows [w*32,w*32+32), lane l cols l, l+64 (L2-hot) ----
  float cn0=0.f, A0=0.f, Rx0=0.f, Ry0=0.f, Rz0=0.f;
  float cn1=0.f, A1=0.f, Rx1=0.f, Ry1=0.f, Rz1=0.f;
  const float c3_0 = c3sh[l], c3_1 = c3sh[l + 64];
  const int sm0 = smk[l], sm1 = smk[l + 64];

  const float* base = score + (size_t)b*NN*NN;
  for (int rr = 0; rr < 32; rr++){
    const int r = w*32 + rr;
    const float v0 = base[r*NN + l];
    const float v1 = base[r*NN + l + 64];
    // row top-3 via butterfly merge of sorted triples
    float a1 = fmaxf(v0, v1), a2 = fminf(v0, v1), a3 = -1e30f;
#pragma unroll
    for (int st = 0; st < 6; st++){
      const int mask = 1 << st;
      float o1 = __shfl_xor(a1, mask);
      float o2 = __shfl_xor(a2, mask);
      float o3 = __shfl_xor(a3, mask);
      float m1 = fmaxf(a1, o1);
      float m2 = fmaxf(fminf(a1, o1), fmaxf(a2, o2));
      float m3 = fmaxf(fmaxf(fminf(a1, o2), fminf(a2, o1)), fmaxf(a3, o3));
      a1 = m1; a2 = m2; a3 = m3;
    }
    const float r3 = a3;
    const bool rmv = rmk[r] != 0;
    const float rx = refsh[r*3+0], ry = refsh[r*3+1], rz = refsh[r*3+2];
    float e0 = 0.f, e1 = 0.f;
    bool k0 = false, k1 = false;
    if (rmv && sm0 && v0 >= r3 && v0 >= c3_0){
      e0 = expf(v0); k0 = (e0 > 0.05f);
    }
    if (rmv && sm1 && v1 >= r3 && v1 >= c3_1){
      e1 = expf(v1); k1 = (e1 > 0.05f);
    }
    if (k0){ cn0 += 1.f; A0 += e0; Rx0 += e0*rx; Ry0 += e0*ry; Rz0 += e0*rz; }
    if (k1){ cn1 += 1.f; A1 += e1; Rx1 += e1*rx; Ry1 += e1*ry; Rz1 += e1*rz; }
    unsigned long long B0 = __ballot(k0);
    unsigned long long B1 = __ballot(k1);
    int n0 = __popcll(B0), n1 = __popcll(B1);
    if (n0 + n1 > 0){
      int wb = 0;
      if (l == 0){ wb = wcnt[w]; wcnt[w] = wb + n0 + n1; }
      wb = __shfl(wb, 0);
      unsigned long long lt = (l == 0) ? 0ull : (~0ull >> (64 - l));
      if (k0){
        int pos = wb + (int)__popcll(B0 & lt);
        if (pos < 96){ candv[w][pos] = e0; candi[w][pos] = (b<<14)|(r<<7)|l; }
      }
      if (k1){
        int pos = wb + n0 + (int)__popcll(B1 & lt);
        if (pos < 96){ candv[w][pos] = e1; candi[w][pos] = (b<<14)|(r<<7)|(l+64); }
      }
    }
  }
  // block-level candidate copy-out: ONE global atomic per block
  __syncthreads();
  if (t == 0){
    int c0 = wcnt[0] > 96 ? 96 : wcnt[0];
    int c1 = wcnt[1] > 96 ? 96 : wcnt[1];
    int c2 = wcnt[2] > 96 ? 96 : wcnt[2];
    int c3 = wcnt[3] > 96 ? 96 : wcnt[3];
    woff[0] = 0; woff[1] = c0; woff[2] = c0 + c1; woff[3] = c0 + c1 + c2;
    bbase = atomicAdd(&hdr[0], c0 + c1 + c2 + c3);
  }
  __syncthreads();
  {
    int total = wcnt[w]; if (total > 96) total = 96;
    int gbase = bbase + woff[w];
    for (int i = l; i < total; i += 64){
      int pos = gbase + i;
      if (pos < CAND_CAP){ cand_vals[pos] = candv[w][i]; cand_idx[pos] = candi[w][i]; }
    }
  }
  // expand 10 accumulators -> 17 stats (src is lane-invariant per column slot)
  {
    const float sx0 = srcsh[l*3+0], sy0 = srcsh[l*3+1], sz0 = srcsh[l*3+2];
    const float sx1 = srcsh[(l+64)*3+0], sy1 = srcsh[(l+64)*3+1], sz1 = srcsh[(l+64)*3+2];
#define WSUM(VAL, IDX) { float v_ = (VAL); \
    for (int o_ = 32; o_ > 0; o_ >>= 1) v_ += __shfl_down(v_, o_); \
    if (l == 0) red[w][IDX] = v_; }
    WSUM(cn0 + cn1, 0)
    WSUM(A0 + A1, 1)
    WSUM(Rx0 + Rx1, 2)
    WSUM(Ry0 + Ry1, 3)
    WSUM(Rz0 + Rz1, 4)
    WSUM(A0*sx0 + A1*sx1, 5)
    WSUM(A0*sy0 + A1*sy1, 6)
    WSUM(A0*sz0 + A1*sz1, 7)
    WSUM(sx0*Rx0 + sx1*Rx1, 8)
    WSUM(sx0*Ry0 + sx1*Ry1, 9)
    WSUM(sx0*Rz0 + sx1*Rz1, 10)
    WSUM(sy0*Rx0 + sy1*Rx1, 11)
    WSUM(sy0*Ry0 + sy1*Ry1, 12)
    WSUM(sy0*Rz0 + sy1*Rz1, 13)
    WSUM(sz0*Rx0 + sz1*Rx1, 14)
    WSUM(sz0*Ry0 + sz1*Ry1, 15)
    WSUM(sz0*Rz0 + sz1*Rz1, 16)
#undef WSUM
  }
  __syncthreads();
  if (t == 0){
    float tot[17];
#pragma unroll
    for (int k = 0; k < 17; k++)
      tot[k] = red[0][k] + red[1][k] + red[2][k] + red[3][k];
    float Wm = tot[1];
    float denom = Wm + 1e-5f;
    float idenom = 1.f / denom;
    float s = Wm * idenom;
    float rcv[3] = { tot[2]*idenom, tot[3]*idenom, tot[4]*idenom };
    float scv[3] = { tot[5]*idenom, tot[6]*idenom, tot[7]*idenom };
    float* o = &Hsr[b*15];
#pragma unroll
    for (int c = 0; c < 3; c++)
#pragma unroll
      for (int d = 0; d < 3; d++)
        o[c*3+d] = tot[8 + c*3 + d]*idenom - (2.f - s)*scv[c]*rcv[d];
    o[9]=scv[0]; o[10]=scv[1]; o[11]=scv[2];
    o[12]=rcv[0]; o[13]=rcv[1]; o[14]=rcv[2];
    pcount[b] = (int)(tot[0] + 0.5f);
  }
}

// ---------------- K3a: grid histogram of top-12 key bits (LDS-local first) ----
__global__ __launch_bounds__(256) void k3a_kernel(
    const int* hdr, const float* __restrict__ cand_vals, int* hist)
{
  __shared__ int lh[NBIN1];
  int t = threadIdx.x;
  int Nc = hdr[0]; if (Nc > CAND_CAP) Nc = CAND_CAP;
  for (int j = t; j < NBIN1; j += 256) lh[j] = 0;
  __syncthreads();
  for (int i = blockIdx.x*256 + t; i < Nc; i += gridDim.x*256)
    atomicAdd(&lh[__float_as_uint(cand_vals[i]) >> 20], 1);
  __syncthreads();
  for (int j = t; j < NBIN1; j += 256)
    if (lh[j]) atomicAdd(&hist[j], lh[j]);
}

// ---------------- K3c: parallel per-block boundary-find + grid partition ------
__global__ __launch_bounds__(256) void k3c_kernel(
    int* hdr, const int* __restrict__ hist,
    const float* __restrict__ cand_vals, const int* __restrict__ cand_idx,
    float* sel_vals, int* sel_idx, float* eq_vals, int* eq_idx)
{
  __shared__ int wtot[4];
  __shared__ int sb[2];
  const int t = threadIdx.x, lane = t & 63, wv = t >> 6;
  int Nc = hdr[0]; if (Nc > CAND_CAP) Nc = CAND_CAP;
  if (Nc <= LIMIT){
    if (t == 0){ sb[0] = -1; sb[1] = 0; if (blockIdx.x == 0){ hdr[4] = -1; hdr[5] = 0; } }
    __syncthreads();
  } else {
    const int chunkIdx = 255 - t;
    int csum = 0;
    for (int j = 0; j < 16; j++) csum += hist[chunkIdx*16 + j];
    int incl = csum;
    for (int off = 1; off < 64; off <<= 1){ int y = __shfl_up(incl, off); if (lane >= off) incl += y; }
    if (lane == 63) wtot[wv] = incl;
    __syncthreads();
    int wbase = 0;
    for (int w = 0; w < wv; w++) wbase += wtot[w];
    int P = wbase + incl;
    int P_prev = P - csum;
    if (P_prev < LIMIT && P >= LIMIT){
      int cum = P_prev, bin1 = chunkIdx*16, need = 0;
      for (int b2 = chunkIdx*16 + 15; b2 >= chunkIdx*16; b2--){
        int h = hist[b2];
        if (cum + h >= LIMIT){ bin1 = b2; need = LIMIT - cum; break; }
        cum += h;
      }
      sb[0] = bin1; sb[1] = need;
      if (blockIdx.x == 0){ hdr[4] = bin1; hdr[5] = need; }
    }
    __syncthreads();
  }
  int bin1 = sb[0];
  for (int i = blockIdx.x*256 + t; i < Nc; i += gridDim.x*256){
    float v = cand_vals[i];
    if (bin1 < 0){
      int p = atomicAdd(&hdr[2], 1);
      if (p < LIMIT){ sel_vals[p] = v; sel_idx[p] = cand_idx[i]; }
      continue;
    }
    int bin = (int)(__float_as_uint(v) >> 20);
    if (bin > bin1){
      int p = atomicAdd(&hdr[2], 1);
      if (p < LIMIT){ sel_vals[p] = v; sel_idx[p] = cand_idx[i]; }
    } else if (bin == bin1){
      int q = atomicAdd(&hdr[1], 1);
      if (q < EQCAP){ eq_vals[q] = v; eq_idx[q] = cand_idx[i]; }
    }
  }
}

// ---------------- K3d: refine boundary bin + zero-fill + gather ---------------
__global__ __launch_bounds__(1024) void k3d_kernel(
    const int* hdr, const float* __restrict__ eq_vals, const int* __restrict__ eq_idx,
    float* sel_vals, int* sel_idx,
    const float* __restrict__ refp, const float* __restrict__ srcp,
    float* sel_ref, float* sel_src)
{
  __shared__ int hist[2048];
  __shared__ int eqsh[2048];
  __shared__ int wtot[16];
  __shared__ int bpair[2];
  __shared__ int sh[2];
  const int t = threadIdx.x, lane = t & 63, wv = t >> 6;
  const int bin1 = hdr[4];
  int nAbove = hdr[2]; if (nAbove > LIMIT) nAbove = LIMIT;

  auto find_boundary = [&](int need){
    int i0 = 2047 - 2*t, i1 = 2046 - 2*t;
    int g0 = hist[i0], g1 = hist[i1];
    int local = g0 + g1;
    int incl = local;
    for (int off = 1; off < 64; off <<= 1){ int y = __shfl_up(incl, off); if (lane >= off) incl += y; }
    if (lane == 63) wtot[wv] = incl;
    __syncthreads();
    int wbase = 0;
    for (int w = 0; w < wv; w++) wbase += wtot[w];
    int P_prev = wbase + incl - local;
    int P0 = P_prev + g0;
    if (P0 >= need && P_prev < need){ bpair[0] = i0; bpair[1] = need - P_prev; }
    int P1 = P0 + g1;
    if (P1 >= need && P0 < need){ bpair[0] = i1; bpair[1] = need - P0; }
    __syncthreads();
  };

  bool done = false;
  if (bin1 < 0){
    for (int i = t; i < LIMIT; i += 1024)
      if (i >= nAbove){ sel_vals[i] = 0.f; sel_idx[i] = 0; }
    done = true;
  }
  int neq = 0, need = 0;
  if (!done){
    neq = hdr[1]; if (neq > EQCAP) neq = EQCAP;
    need = hdr[5];
    if (need >= neq){
      for (int i = t; i < neq; i += 1024){ sel_vals[nAbove+i] = eq_vals[i]; sel_idx[nAbove+i] = eq_idx[i]; }
      for (int i = t; i < LIMIT; i += 1024)
        if (i >= nAbove + neq){ sel_vals[i] = 0.f; sel_idx[i] = 0; }
      done = true;
    }
  }
  if (!done){
    for (int i = t; i < 2048; i += 1024) hist[i] = 0;
    __syncthreads();
    for (int i = t; i < neq; i += 1024)
      atomicAdd(&hist[(__float_as_uint(eq_vals[i]) >> 9) & 0x7FF], 1);
    __syncthreads();
    find_boundary(need);
    int binA = bpair[0], need2 = bpair[1];
    __syncthreads();
    for (int i = t; i < 2048; i += 1024) hist[i] = 0;
    __syncthreads();
    for (int i = t; i < neq; i += 1024){
      unsigned k = __float_as_uint(eq_vals[i]);
      if ((int)((k >> 9) & 0x7FF) == binA) atomicAdd(&hist[k & 0x1FF], 1);
    }
    __syncthreads();
    find_boundary(need2);
    unsigned Tlow = (((unsigned)binA) << 9) | (unsigned)bpair[0];
    unsigned Tkey = (((unsigned)bin1) << 20) | Tlow;
    if (t == 0){ sh[0] = 0; sh[1] = 0; }
    __syncthreads();
    for (int i = t; i < neq; i += 1024){
      unsigned k = __float_as_uint(eq_vals[i]);
      unsigned k20 = k & 0xFFFFF;
      if (k20 > Tlow){
        int p = atomicAdd(&sh[0], 1);
        sel_vals[nAbove + p] = eq_vals[i]; sel_idx[nAbove + p] = eq_idx[i];
      } else if (k20 == Tlow){
        int q = atomicAdd(&sh[1], 1);
        if (q < 2048) eqsh[q] = eq_idx[i];
      }
    }
    __syncthreads();
    if (t == 0){
      int na2 = sh[0];
      int ne2 = sh[1]; if (ne2 > 2048) ne2 = 2048;
      int take = need - na2; if (take > ne2) take = ne2; if (take < 0) take = 0;
      if (nAbove + na2 + take > LIMIT) take = LIMIT - nAbove - na2;
      for (int j = 0; j < take; j++){
        int mi = j;
        for (int l2 = j+1; l2 < ne2; l2++) if (eqsh[l2] < eqsh[mi]) mi = l2;
        int tmp = eqsh[j]; eqsh[j] = eqsh[mi]; eqsh[mi] = tmp;
        sel_vals[nAbove + na2 + j] = __uint_as_float(Tkey);
        sel_idx[nAbove + na2 + j] = eqsh[j];
      }
      for (int j = nAbove + na2 + take; j < LIMIT; j++){ sel_vals[j] = 0.f; sel_idx[j] = 0; }
    }
  }
  __syncthreads();
  for (int p = t; p < LIMIT; p += 1024){
    int idx = sel_idx[p];
    int b = idx >> 14, rr = (idx >> 7) & 127, ss = idx & 127;
#pragma unroll
    for (int c = 0; c < 3; c++){
      sel_ref[p*3+c] = refp[(b*NN+rr)*3+c];
      sel_src[p*3+c] = srcp[(b*NN+ss)*3+c];
    }
  }
}

// ---------------- K45: per-block Kabsch + inlier counts + last-block refine ---
__global__ __launch_bounds__(256, 1) void k45_kernel(
    const float* __restrict__ Hsr, float* __restrict__ localT,
    const float* __restrict__ sel_vals, const float* __restrict__ sel_ref,
    const float* __restrict__ sel_src, const int* __restrict__ pcount,
    int* counts, int* hdr, float* out)
{
  __shared__ float Tsh[12];
  __shared__ int ired[4];
  __shared__ int lastsh;
  __shared__ float fred[4][16];
  __shared__ long long lred[4];
  __shared__ float RT[12];
  __shared__ int sbest;
  const int b = blockIdx.x, t = threadIdx.x, lane = t & 63, wv = t >> 6;

  if (t == 0){
    const float* o = &Hsr[b*15];
    float r00,r01,r02,r10,r11,r12,r20,r21,r22;
    kabsch9(o[0],o[1],o[2], o[3],o[4],o[5], o[6],o[7],o[8],
            r00,r01,r02,r10,r11,r12,r20,r21,r22);
    Tsh[0]=r00; Tsh[1]=r01; Tsh[2]=r02;
    Tsh[3]=r10; Tsh[4]=r11; Tsh[5]=r12;
    Tsh[6]=r20; Tsh[7]=r21; Tsh[8]=r22;
    Tsh[9]  = o[12] - (r00*o[9] + r01*o[10] + r02*o[11]);
    Tsh[10] = o[13] - (r10*o[9] + r11*o[10] + r12*o[11]);
    Tsh[11] = o[14] - (r20*o[9] + r21*o[10] + r22*o[11]);
  }
  __syncthreads();
  if (t < 12) localT[b*12 + t] = Tsh[t];

  {
    float R00=Tsh[0],R01=Tsh[1],R02=Tsh[2],R10=Tsh[3],R11=Tsh[4],R12=Tsh[5];
    float R20=Tsh[6],R21=Tsh[7],R22=Tsh[8];
    float tx=Tsh[9], ty=Tsh[10], tz=Tsh[11];
    int c = 0;
    for (int p = t; p < LIMIT; p += 256){
      float v = sel_vals[p];
      if (!(v > 0.f)) continue;
      float sx=sel_src[p*3], sy=sel_src[p*3+1], sz=sel_src[p*3+2];
      float rx=sel_ref[p*3], ry=sel_ref[p*3+1], rz=sel_ref[p*3+2];
      float ax = R00*sx + R01*sy + R02*sz + tx;
      float ay = R10*sx + R11*sy + R12*sz + ty;
      float az = R20*sx + R21*sy + R22*sz + tz;
      float dx = rx-ax, dy = ry-ay, dz = rz-az;
      if (sqrtf(dx*dx + dy*dy + dz*dz) < 0.1f) c++;
    }
    for (int off2 = 32; off2 > 0; off2 >>= 1) c += __shfl_down(c, off2);
    if (lane == 0) ired[wv] = c;
    __syncthreads();
    if (t == 0){
      counts[b] = (pcount[b] >= 3) ? (ired[0]+ired[1]+ired[2]+ired[3]) : -1;
      __threadfence();
      int d = atomicAdd(&hdr[6], 1);
      lastsh = (d == BB - 1) ? 1 : 0;
    }
    __syncthreads();
    if (!lastsh) return;
    __threadfence();
  }

  {
    long long key = (long long)0x8000000000000000LL;
    for (int bb = t; bb < BB; bb += 256){
      long long kk = ((long long)(counts[bb] + 2) << 32) | (long long)(511 - bb);
      if (kk > key) key = kk;
    }
    for (int off2 = 32; off2 > 0; off2 >>= 1){ long long o = __shfl_down(key, off2); if (o > key) key = o; }
    if (lane == 0) lred[wv] = key;
    __syncthreads();
    if (t == 0){
      long long m = lred[0];
#pragma unroll
      for (int w = 1; w < 4; w++) if (lred[w] > m) m = lred[w];
      sbest = 511 - (int)(m & 0xFFFFFFFFLL);
    }
    __syncthreads();
    if (t < 12) RT[t] = localT[sbest*12 + t];
    __syncthreads();

    for (int iter = 0; iter < 5; iter++){
      float R00=RT[0],R01=RT[1],R02=RT[2];
      float R10=RT[3],R11=RT[4],R12=RT[5];
      float R20=RT[6],R21=RT[7],R22=RT[8];
      float tx=RT[9], ty=RT[10], tz=RT[11];
      float a0=0.f,a1=0.f,a2=0.f,a3=0.f,a4=0.f,a5=0.f,a6=0.f,a7=0.f;
      float a8=0.f,a9=0.f,a10=0.f,a11=0.f,a12=0.f,a13=0.f,a14=0.f,a15=0.f;
      for (int p = t; p < LIMIT; p += 256){
        float v = sel_vals[p];
        if (!(v > 0.f)) continue;
        float sx=sel_src[p*3], sy=sel_src[p*3+1], sz=sel_src[p*3+2];
        float rx=sel_ref[p*3], ry=sel_ref[p*3+1], rz=sel_ref[p*3+2];
        float ax = R00*sx + R01*sy + R02*sz + tx;
        float ay = R10*sx + R11*sy + R12*sz + ty;
        float az = R20*sx + R21*sy + R22*sz + tz;
        float dx = rx-ax, dy = ry-ay, dz = rz-az;
        if (sqrtf(dx*dx + dy*dy + dz*dz) < 0.1f){
          a0 += v;
          a1 += v*sx; a2 += v*sy; a3 += v*sz;
          a4 += v*rx; a5 += v*ry; a6 += v*rz;
          a7  += v*sx*rx; a8  += v*sx*ry; a9  += v*sx*rz;
          a10 += v*sy*rx; a11 += v*sy*ry; a12 += v*sy*rz;
          a13 += v*sz*rx; a14 += v*sz*ry; a15 += v*sz*rz;
        }
      }
#define WRED(VAL, IDX) { float v_ = (VAL); \
      for (int o_ = 32; o_ > 0; o_ >>= 1) v_ += __shfl_down(v_, o_); \
      if (lane == 0) fred[wv][IDX] = v_; }
      WRED(a0, 0)  WRED(a1, 1)  WRED(a2, 2)  WRED(a3, 3)
      WRED(a4, 4)  WRED(a5, 5)  WRED(a6, 6)  WRED(a7, 7)
      WRED(a8, 8)  WRED(a9, 9)  WRED(a10,10) WRED(a11,11)
      WRED(a12,12) WRED(a13,13) WRED(a14,14) WRED(a15,15)
#undef WRED
      __syncthreads();
      if (t == 0){
        float tot[16];
#pragma unroll
        for (int k = 0; k < 16; k++) tot[k] = fred[0][k]+fred[1][k]+fred[2][k]+fred[3][k];
        float W = tot[0], denom = W + 1e-5f;
        float inv = 1.f / denom;
        float s = W * inv;
        float scx = tot[1]*inv, scy = tot[2]*inv, scz = tot[3]*inv;
        float rcx = tot[4]*inv, rcy = tot[5]*inv, rcz = tot[6]*inv;
        float f = 2.f - s;
        float h00 = tot[7]*inv  - f*scx*rcx;
        float h01 = tot[8]*inv  - f*scx*rcy;
        float h02 = tot[9]*inv  - f*scx*rcz;
        float h10 = tot[10]*inv - f*scy*rcx;
        float h11 = tot[11]*inv - f*scy*rcy;
        float h12 = tot[12]*inv - f*scy*rcz;
        float h20 = tot[13]*inv - f*scz*rcx;
        float h21 = tot[14]*inv - f*scz*rcy;
        float h22 = tot[15]*inv - f*scz*rcz;
        float r00,r01,r02,r10,r11,r12,r20,r21,r22;
        kabsch9(h00,h01,h02,h10,h11,h12,h20,h21,h22,
                r00,r01,r02,r10,r11,r12,r20,r21,r22);
        RT[0]=r00; RT[1]=r01; RT[2]=r02;
        RT[3]=r10; RT[4]=r11; RT[5]=r12;
        RT[6]=r20; RT[7]=r21; RT[8]=r22;
        RT[9]  = rcx - (r00*scx + r01*scy + r02*scz);
        RT[10] = rcy - (r10*scx + r11*scy + r12*scz);
        RT[11] = rcz - (r20*scx + r21*scy + r22*scz);
      }
      __syncthreads();
    }
    if (t == 0){
      out[0]=RT[0];  out[1]=RT[1];  out[2]=RT[2];  out[3]=RT[9];
      out[4]=RT[3];  out[5]=RT[4];  out[6]=RT[5];  out[7]=RT[10];
      out[8]=RT[6];  out[9]=RT[7];  out[10]=RT[8]; out[11]=RT[11];
      out[12]=0.f; out[13]=0.f; out[14]=0.f; out[15]=1.f;
    }
  }
}

// ---------------- host launcher -----------------------------------------------
extern "C" void kernel_launch(void* const* d_in, const int* in_sizes, int n_in,
                              void* d_out, int out_size, void* d_ws, size_t ws_size,
                              hipStream_t stream){
  const float* score = (const float*)d_in[0];
  const float* refp  = (const float*)d_in[1];
  const float* srcp  = (const float*)d_in[2];
  const void*  rmask = d_in[3];
  const void*  smask = d_in[4];

  char* ws = (char*)d_ws;
  size_t off = 0;
  int* hdr = (int*)(ws + off);            off += 256;
  int* hist = (int*)(ws + off);           off += (size_t)NBIN1*4;
  float* cand_vals = (float*)(ws + off);  off += (size_t)CAND_CAP*4;
  int* cand_idx = (int*)(ws + off);       off += (size_t)CAND_CAP*4;
  float* eq_vals = (float*)(ws + off);    off += (size_t)EQCAP*4;
  int* eq_idx = (int*)(ws + off);         off += (size_t)EQCAP*4;
  float* Hsr = (float*)(ws + off);        off += (size_t)BB*15*4;
  int* pcount = (int*)(ws + off);         off += (size_t)BB*4;
  float* localT = (float*)(ws + off);     off += (size_t)BB*12*4;
  float* sel_vals = (float*)(ws + off);   off += (size_t)LIMIT*4;
  int* sel_idx = (int*)(ws + off);        off += (size_t)LIMIT*4;
  float* sel_ref = (float*)(ws + off);    off += (size_t)LIMIT*3*4;
  float* sel_src = (float*)(ws + off);    off += (size_t)LIMIT*3*4;
  int* counts = (int*)(ws + off);         off += (size_t)BB*4;

  hipMemsetAsync(ws, 0, 256 + (size_t)NBIN1*4, stream);
  hipLaunchKernelGGL(k1_kernel, dim3(BB), dim3(256), 0, stream,
                     score, refp, srcp, rmask, smask,
                     hdr, cand_vals, cand_idx, Hsr, pcount);
  hipLaunchKernelGGL(k3a_kernel, dim3(64), dim3(256), 0, stream, hdr, cand_vals, hist);
  hipLaunchKernelGGL(k3c_kernel, dim3(64), dim3(256), 0, stream,
                     hdr, hist, cand_vals, cand_idx, sel_vals, sel_idx, eq_vals, eq_idx);
  hipLaunchKernelGGL(k3d_kernel, dim3(1), dim3(1024), 0, stream,
                     hdr, eq_vals, eq_idx, sel_vals, sel_idx, refp, srcp, sel_ref, sel_src);
  hipLaunchKernelGGL(k45_kernel, dim3(BB), dim3(256), 0, stream,
                     Hsr, localT, sel_vals, sel_ref, sel_src, pcount, counts, hdr, (float*)d_out);
}

// Round 14
// 210.321 us; speedup vs baseline: 3.1077x; 1.0497x over previous
//
#include <hip/hip_runtime.h>
#include <math.h>

#define BB 512
#define NN 128
#define CAND_CAP (512*384)
#define LIMIT 2048
#define EQCAP 16384
#define NBIN1 4096

// ---------------- mask decode (int32 / byte / float32 robustness) -------------
__device__ inline bool read_mask(const void* p, int i, int mode){
  if (mode == 0) return ((const int*)p)[i] != 0;
  if (mode == 1) return ((const unsigned char*)p)[i] != 0;
  return ((const float*)p)[i] != 0.0f;
}

__device__ inline float fast_rcp(float x){ return __builtin_amdgcn_rcpf(x); }
__device__ inline float fast_rsq(float x){ return __builtin_amdgcn_rsqf(x); }

// ---------------- fp32 Kabsch, SCALAR-ONLY interface --------------------------
__device__ __forceinline__ void kabsch9(
    float h00, float h01, float h02,
    float h10, float h11, float h12,
    float h20, float h21, float h22,
    float& r00, float& r01, float& r02,
    float& r10, float& r11, float& r12,
    float& r20, float& r21, float& r22)
{
  float s00 = h00*h00 + h10*h10 + h20*h20;
  float s01 = h00*h01 + h10*h11 + h20*h21;
  float s02 = h00*h02 + h10*h12 + h20*h22;
  float s11 = h01*h01 + h11*h11 + h21*h21;
  float s12 = h01*h02 + h11*h12 + h21*h22;
  float s22 = h02*h02 + h12*h12 + h22*h22;
  float v00=1.f,v01=0.f,v02=0.f, v10=0.f,v11=1.f,v12=0.f, v20=0.f,v21=0.f,v22=1.f;
  for (int sweep = 0; sweep < 10; sweep++){
    float off  = s01*s01 + s02*s02 + s12*s12;
    float base = s00*s00 + s11*s11 + s22*s22;
    if (off <= base*1e-14f + 1e-36f) break;
    if (fabsf(s01) > 1e-30f){
      float tau = (s11 - s00) * fast_rcp(2.f*s01);
      float tt  = (tau >= 0.f ? 1.f : -1.f) * fast_rcp(fabsf(tau) + sqrtf(1.f + tau*tau));
      float c = fast_rsq(1.f + tt*tt), s = tt*c;
      float n00 = c*c*s00 - 2.f*c*s*s01 + s*s*s11;
      float n11 = s*s*s00 + 2.f*c*s*s01 + c*c*s11;
      float n02 = c*s02 - s*s12;
      float n12 = s*s02 + c*s12;
      s00=n00; s11=n11; s01=0.f; s02=n02; s12=n12;
      float a,b;
      a=v00; b=v01; v00=c*a-s*b; v01=s*a+c*b;
      a=v10; b=v11; v10=c*a-s*b; v11=s*a+c*b;
      a=v20; b=v21; v20=c*a-s*b; v21=s*a+c*b;
    }
    if (fabsf(s02) > 1e-30f){
      float tau = (s22 - s00) * fast_rcp(2.f*s02);
      float tt  = (tau >= 0.f ? 1.f : -1.f) * fast_rcp(fabsf(tau) + sqrtf(1.f + tau*tau));
      float c = fast_rsq(1.f + tt*tt), s = tt*c;
      float n00 = c*c*s00 - 2.f*c*s*s02 + s*s*s22;
      float n22 = s*s*s00 + 2.f*c*s*s02 + c*c*s22;
      float n01 = c*s01 - s*s12;
      float n12 = s*s01 + c*s12;
      s00=n00; s22=n22; s02=0.f; s01=n01; s12=n12;
      float a,b;
      a=v00; b=v02; v00=c*a-s*b; v02=s*a+c*b;
      a=v10; b=v12; v10=c*a-s*b; v12=s*a+c*b;
      a=v20; b=v22; v20=c*a-s*b; v22=s*a+c*b;
    }
    if (fabsf(s12) > 1e-30f){
      float tau = (s22 - s11) * fast_rcp(2.f*s12);
      float tt  = (tau >= 0.f ? 1.f : -1.f) * fast_rcp(fabsf(tau) + sqrtf(1.f + tau*tau));
      float c = fast_rsq(1.f + tt*tt), s = tt*c;
      float n11 = c*c*s11 - 2.f*c*s*s12 + s*s*s22;
      float n22 = s*s*s11 + 2.f*c*s*s12 + c*c*s22;
      float n01 = c*s01 - s*s02;
      float n02 = s*s01 + c*s02;
      s11=n11; s22=n22; s12=0.f; s01=n01; s02=n02;
      float a,b;
      a=v01; b=v02; v01=c*a-s*b; v02=s*a+c*b;
      a=v11; b=v12; v11=c*a-s*b; v12=s*a+c*b;
      a=v21; b=v22; v21=c*a-s*b; v22=s*a+c*b;
    }
  }
  float l0=s00, l1=s11, l2=s22;
  float a0=v00, a1=v10, a2=v20;
  float b0=v01, b1=v11, b2=v21;
  float c0=v02, c1=v12, c2=v22;
  if (l0 < l1){ float x; x=l0;l0=l1;l1=x; x=a0;a0=b0;b0=x; x=a1;a1=b1;b1=x; x=a2;a2=b2;b2=x; }
  if (l0 < l2){ float x; x=l0;l0=l2;l2=x; x=a0;a0=c0;c0=x; x=a1;a1=c1;c1=x; x=a2;a2=c2;c2=x; }
  if (l1 < l2){ float x; x=l1;l1=l2;l2=x; x=b0;b0=c0;c0=x; x=b1;b1=c1;c1=x; x=b2;b2=c2;c2=x; }
  float sig0 = sqrtf(fmaxf(l0, 0.f));
  if (!(sig0 > 1e-12f)){
    r00=1.f; r01=0.f; r02=0.f; r10=0.f; r11=1.f; r12=0.f; r20=0.f; r21=0.f; r22=1.f;
    return;
  }
  float u0x = h00*a0 + h01*a1 + h02*a2;
  float u0y = h10*a0 + h11*a1 + h12*a2;
  float u0z = h20*a0 + h21*a1 + h22*a2;
  float in0 = fast_rsq(u0x*u0x + u0y*u0y + u0z*u0z);
  u0x *= in0; u0y *= in0; u0z *= in0;
  float u1x = h00*b0 + h01*b1 + h02*b2;
  float u1y = h10*b0 + h11*b1 + h12*b2;
  float u1z = h20*b0 + h21*b1 + h22*b2;
  float dp = u1x*u0x + u1y*u0y + u1z*u0z;
  u1x -= dp*u0x; u1y -= dp*u0y; u1z -= dp*u0z;
  float d1 = u1x*u1x + u1y*u1y + u1z*u1z;
  if (sqrtf(d1) > sig0*1e-5f){
    float in1 = fast_rsq(d1);
    u1x *= in1; u1y *= in1; u1z *= in1;
  } else {
    float au0 = fabsf(u0x), au1 = fabsf(u0y), au2 = fabsf(u0z);
    float e0 = 0.f, e1 = 0.f, e2 = 0.f;
    if (au0 <= au1 && au0 <= au2) e0 = 1.f; else if (au1 <= au2) e1 = 1.f; else e2 = 1.f;
    float d2 = e0*u0x + e1*u0y + e2*u0z;
    u1x = e0 - d2*u0x; u1y = e1 - d2*u0y; u1z = e2 - d2*u0z;
    float nn = fast_rsq(u1x*u1x + u1y*u1y + u1z*u1z);
    u1x *= nn; u1y *= nn; u1z *= nn;
  }
  float u2x = u0y*u1z - u0z*u1y;
  float u2y = u0z*u1x - u0x*u1z;
  float u2z = u0x*u1y - u0y*u1x;
  float cxv = b1*c2 - b2*c1;
  float cyv = b2*c0 - b0*c2;
  float czv = b0*c1 - b1*c0;
  float detV = a0*cxv + a1*cyv + a2*czv;
  float dd = (detV >= 0.f) ? 1.f : -1.f;
  float w2x = dd*u2x, w2y = dd*u2y, w2z = dd*u2z;
  r00=a0*u0x + b0*u1x + c0*w2x;  r01=a0*u0y + b0*u1y + c0*w2y;  r02=a0*u0z + b0*u1z + c0*w2z;
  r10=a1*u0x + b1*u1x + c1*w2x;  r11=a1*u0y + b1*u1y + c1*w2y;  r12=a1*u0z + b1*u1z + c1*w2z;
  r20=a2*u0x + b2*u1x + c2*w2x;  r21=a2*u0y + b2*u1y + c2*w2y;  r22=a2*u0z + b2*u1z + c2*w2z;
}

// ---------------- K1: fused col-top3 + row-top3 + stats + candidates ----------
__global__ __launch_bounds__(256) void k1_kernel(
    const float* __restrict__ score, const float* __restrict__ refp,
    const float* __restrict__ srcp, const void* __restrict__ rmaskp,
    const void* __restrict__ smaskp,
    int* hdr, float* cand_vals, int* cand_idx,
    float* Hsr, int* pcount)
{
  __shared__ float parts[2][NN][3];
  __shared__ float srcsh[NN*3];
  __shared__ float refsh[NN*3];
  __shared__ float c3sh[NN];
  __shared__ unsigned char smk[NN], rmk[NN];
  __shared__ float candv[4][96];
  __shared__ int   candi[4][96];
  __shared__ int   wcnt[4];
  __shared__ int   woff[4];
  __shared__ int   bbase;
  __shared__ float red[4][17];
  __shared__ int smode;
  const int b = blockIdx.x, t = threadIdx.x;
  const int w = t >> 6, l = t & 63;

  if (t < 64){
    unsigned v = ((const unsigned*)rmaskp)[t];
    bool n01 = !(v == 0u || v == 1u);
    bool nf  = !(v == 0u || v == 0x3F800000u);
    unsigned long long b01 = __ballot(n01), bf = __ballot(nf);
    if (t == 0) smode = (b01 == 0ull) ? 0 : ((bf == 0ull) ? 2 : 1);
  }
  if (t < 4) wcnt[t] = 0;
  for (int i = t; i < NN*3; i += 256){
    srcsh[i] = srcp[b*NN*3 + i];
    refsh[i] = refp[b*NN*3 + i];
  }

  // ---- phase A: column partial top-3 (coalesced, branchless) ----
  {
    const int c = t & 127, h = t >> 7;
    float a1=-1e30f, a2=-1e30f, a3=-1e30f;
    const float* colp = score + (size_t)b*NN*NN + (size_t)(h*64)*NN + c;
#pragma unroll 8
    for (int i = 0; i < 64; i++){
      float v = colp[i*NN];
      float m = fminf(a1, v);
      a1 = fmaxf(a1, v);
      a3 = fmaxf(a3, fminf(a2, m));
      a2 = fmaxf(a2, m);
    }
    parts[h][c][0]=a1; parts[h][c][1]=a2; parts[h][c][2]=a3;
  }
  __syncthreads();    // parts + smode + srcsh/refsh ready
  if (t < NN){
    float a1=parts[0][t][0], a2=parts[0][t][1], a3=parts[0][t][2];
    float b1=parts[1][t][0], b2=parts[1][t][1], b3=parts[1][t][2];
    c3sh[t] = fmaxf(fmaxf(fminf(a1,b2), fminf(a2,b1)), fmaxf(a3,b3));
    int mode = smode;
    smk[t] = read_mask(smaskp, b*NN + t, mode) ? 1 : 0;
    rmk[t] = read_mask(rmaskp, b*NN + t, mode) ? 1 : 0;
  }
  __syncthreads();

  // ---- phase B: wave w rows [w*32,w*32+32), lane l cols l, l+64 (L2-hot) ----
  float cn0=0.f, A0=0.f, Rx0=0.f, Ry0=0.f, Rz0=0.f;
  float cn1=0.f, A1=0.f, Rx1=0.f, Ry1=0.f, Rz1=0.f;
  const float c3_0 = c3sh[l], c3_1 = c3sh[l + 64];
  const int sm0 = smk[l], sm1 = smk[l + 64];

  const float* base = score + (size_t)b*NN*NN;
  for (int rr = 0; rr < 32; rr++){
    const int r = w*32 + rr;
    const float v0 = base[r*NN + l];
    const float v1 = base[r*NN + l + 64];
    float a1 = fmaxf(v0, v1), a2 = fminf(v0, v1), a3 = -1e30f;
#pragma unroll
    for (int st = 0; st < 6; st++){
      const int mask = 1 << st;
      float o1 = __shfl_xor(a1, mask);
      float o2 = __shfl_xor(a2, mask);
      float o3 = __shfl_xor(a3, mask);
      float m1 = fmaxf(a1, o1);
      float m2 = fmaxf(fminf(a1, o1), fmaxf(a2, o2));
      float m3 = fmaxf(fmaxf(fminf(a1, o2), fminf(a2, o1)), fmaxf(a3, o3));
      a1 = m1; a2 = m2; a3 = m3;
    }
    const float r3 = a3;
    const bool rmv = rmk[r] != 0;
    const float rx = refsh[r*3+0], ry = refsh[r*3+1], rz = refsh[r*3+2];
    float e0 = 0.f, e1 = 0.f;
    bool k0 = false, k1 = false;
    if (rmv && sm0 && v0 >= r3 && v0 >= c3_0){
      e0 = expf(v0); k0 = (e0 > 0.05f);
    }
    if (rmv && sm1 && v1 >= r3 && v1 >= c3_1){
      e1 = expf(v1); k1 = (e1 > 0.05f);
    }
    if (k0){ cn0 += 1.f; A0 += e0; Rx0 += e0*rx; Ry0 += e0*ry; Rz0 += e0*rz; }
    if (k1){ cn1 += 1.f; A1 += e1; Rx1 += e1*rx; Ry1 += e1*ry; Rz1 += e1*rz; }
    unsigned long long B0 = __ballot(k0);
    unsigned long long B1 = __ballot(k1);
    int n0 = __popcll(B0), n1 = __popcll(B1);
    if (n0 + n1 > 0){
      int wb = 0;
      if (l == 0){ wb = wcnt[w]; wcnt[w] = wb + n0 + n1; }
      wb = __shfl(wb, 0);
      unsigned long long lt = (l == 0) ? 0ull : (~0ull >> (64 - l));
      if (k0){
        int pos = wb + (int)__popcll(B0 & lt);
        if (pos < 96){ candv[w][pos] = e0; candi[w][pos] = (b<<14)|(r<<7)|l; }
      }
      if (k1){
        int pos = wb + n0 + (int)__popcll(B1 & lt);
        if (pos < 96){ candv[w][pos] = e1; candi[w][pos] = (b<<14)|(r<<7)|(l+64); }
      }
    }
  }
  // block-level candidate copy-out: ONE global atomic per block
  __syncthreads();
  if (t == 0){
    int c0 = wcnt[0] > 96 ? 96 : wcnt[0];
    int c1 = wcnt[1] > 96 ? 96 : wcnt[1];
    int c2 = wcnt[2] > 96 ? 96 : wcnt[2];
    int c3 = wcnt[3] > 96 ? 96 : wcnt[3];
    woff[0] = 0; woff[1] = c0; woff[2] = c0 + c1; woff[3] = c0 + c1 + c2;
    bbase = atomicAdd(&hdr[0], c0 + c1 + c2 + c3);
  }
  __syncthreads();
  {
    int total = wcnt[w]; if (total > 96) total = 96;
    int gbase = bbase + woff[w];
    for (int i = l; i < total; i += 64){
      int pos = gbase + i;
      if (pos < CAND_CAP){ cand_vals[pos] = candv[w][i]; cand_idx[pos] = candi[w][i]; }
    }
  }
  // expand 10 accumulators -> 17 stats (src is lane-invariant per column slot)
  {
    const float sx0 = srcsh[l*3+0], sy0 = srcsh[l*3+1], sz0 = srcsh[l*3+2];
    const float sx1 = srcsh[(l+64)*3+0], sy1 = srcsh[(l+64)*3+1], sz1 = srcsh[(l+64)*3+2];
#define WSUM(VAL, IDX) { float v_ = (VAL); \
    for (int o_ = 32; o_ > 0; o_ >>= 1) v_ += __shfl_down(v_, o_); \
    if (l == 0) red[w][IDX] = v_; }
    WSUM(cn0 + cn1, 0)
    WSUM(A0 + A1, 1)
    WSUM(Rx0 + Rx1, 2)
    WSUM(Ry0 + Ry1, 3)
    WSUM(Rz0 + Rz1, 4)
    WSUM(A0*sx0 + A1*sx1, 5)
    WSUM(A0*sy0 + A1*sy1, 6)
    WSUM(A0*sz0 + A1*sz1, 7)
    WSUM(sx0*Rx0 + sx1*Rx1, 8)
    WSUM(sx0*Ry0 + sx1*Ry1, 9)
    WSUM(sx0*Rz0 + sx1*Rz1, 10)
    WSUM(sy0*Rx0 + sy1*Rx1, 11)
    WSUM(sy0*Ry0 + sy1*Ry1, 12)
    WSUM(sy0*Rz0 + sy1*Rz1, 13)
    WSUM(sz0*Rx0 + sz1*Rx1, 14)
    WSUM(sz0*Ry0 + sz1*Ry1, 15)
    WSUM(sz0*Rz0 + sz1*Rz1, 16)
#undef WSUM
  }
  __syncthreads();
  if (t == 0){
    float tot[17];
#pragma unroll
    for (int k = 0; k < 17; k++)
      tot[k] = red[0][k] + red[1][k] + red[2][k] + red[3][k];
    float Wm = tot[1];
    float denom = Wm + 1e-5f;
    float idenom = 1.f / denom;
    float s = Wm * idenom;
    float rcv[3] = { tot[2]*idenom, tot[3]*idenom, tot[4]*idenom };
    float scv[3] = { tot[5]*idenom, tot[6]*idenom, tot[7]*idenom };
    float* o = &Hsr[b*15];
#pragma unroll
    for (int c = 0; c < 3; c++)
#pragma unroll
      for (int d = 0; d < 3; d++)
        o[c*3+d] = tot[8 + c*3 + d]*idenom - (2.f - s)*scv[c]*rcv[d];
    o[9]=scv[0]; o[10]=scv[1]; o[11]=scv[2];
    o[12]=rcv[0]; o[13]=rcv[1]; o[14]=rcv[2];
    pcount[b] = (int)(tot[0] + 0.5f);
  }
}

// ---------------- K3a: grid histogram of top-12 key bits (LDS-local first) ----
__global__ __launch_bounds__(256) void k3a_kernel(
    const int* hdr, const float* __restrict__ cand_vals, int* hist)
{
  __shared__ int lh[NBIN1];
  int t = threadIdx.x;
  int Nc = hdr[0]; if (Nc > CAND_CAP) Nc = CAND_CAP;
  for (int j = t; j < NBIN1; j += 256) lh[j] = 0;
  __syncthreads();
  for (int i = blockIdx.x*256 + t; i < Nc; i += gridDim.x*256)
    atomicAdd(&lh[__float_as_uint(cand_vals[i]) >> 20], 1);
  __syncthreads();
  for (int j = t; j < NBIN1; j += 256)
    if (lh[j]) atomicAdd(&hist[j], lh[j]);
}

// ---------------- K3c: 512 parallel Kabsch + boundary-find + grid partition ---
__global__ __launch_bounds__(256) void k3c_kernel(
    int* hdr, const int* __restrict__ hist,
    const float* __restrict__ cand_vals, const int* __restrict__ cand_idx,
    const float* __restrict__ Hsr, float* __restrict__ localT,
    float* sel_vals, int* sel_idx, float* eq_vals, int* eq_idx)
{
  __shared__ int wtot[4];
  __shared__ int sb[2];
  const int t = threadIdx.x, lane = t & 63, wv = t >> 6;

  // phase 0: lanes 0..7 compute 8 batches' local transforms (SIMD-parallel,
  // register kabsch9) — moved out of the k4 critical path (was per-block serial)
  if (t < 8){
    const int bb = blockIdx.x*8 + t;
    const float* o = &Hsr[bb*15];
    float r00,r01,r02,r10,r11,r12,r20,r21,r22;
    kabsch9(o[0],o[1],o[2], o[3],o[4],o[5], o[6],o[7],o[8],
            r00,r01,r02,r10,r11,r12,r20,r21,r22);
    float* T = &localT[bb*12];
    T[0]=r00; T[1]=r01; T[2]=r02;
    T[3]=r10; T[4]=r11; T[5]=r12;
    T[6]=r20; T[7]=r21; T[8]=r22;
    T[9]  = o[12] - (r00*o[9] + r01*o[10] + r02*o[11]);
    T[10] = o[13] - (r10*o[9] + r11*o[10] + r12*o[11]);
    T[11] = o[14] - (r20*o[9] + r21*o[10] + r22*o[11]);
  }

  int Nc = hdr[0]; if (Nc > CAND_CAP) Nc = CAND_CAP;
  if (Nc <= LIMIT){
    if (t == 0){ sb[0] = -1; sb[1] = 0; if (blockIdx.x == 0){ hdr[4] = -1; hdr[5] = 0; } }
    __syncthreads();
  } else {
    const int chunkIdx = 255 - t;
    int csum = 0;
    for (int j = 0; j < 16; j++) csum += hist[chunkIdx*16 + j];
    int incl = csum;
    for (int off = 1; off < 64; off <<= 1){ int y = __shfl_up(incl, off); if (lane >= off) incl += y; }
    if (lane == 63) wtot[wv] = incl;
    __syncthreads();
    int wbase = 0;
    for (int w = 0; w < wv; w++) wbase += wtot[w];
    int P = wbase + incl;
    int P_prev = P - csum;
    if (P_prev < LIMIT && P >= LIMIT){
      int cum = P_prev, bin1 = chunkIdx*16, need = 0;
      for (int b2 = chunkIdx*16 + 15; b2 >= chunkIdx*16; b2--){
        int h = hist[b2];
        if (cum + h >= LIMIT){ bin1 = b2; need = LIMIT - cum; break; }
        cum += h;
      }
      sb[0] = bin1; sb[1] = need;
      if (blockIdx.x == 0){ hdr[4] = bin1; hdr[5] = need; }
    }
    __syncthreads();
  }
  int bin1 = sb[0];
  for (int i = blockIdx.x*256 + t; i < Nc; i += gridDim.x*256){
    float v = cand_vals[i];
    if (bin1 < 0){
      int p = atomicAdd(&hdr[2], 1);
      if (p < LIMIT){ sel_vals[p] = v; sel_idx[p] = cand_idx[i]; }
      continue;
    }
    int bin = (int)(__float_as_uint(v) >> 20);
    if (bin > bin1){
      int p = atomicAdd(&hdr[2], 1);
      if (p < LIMIT){ sel_vals[p] = v; sel_idx[p] = cand_idx[i]; }
    } else if (bin == bin1){
      int q = atomicAdd(&hdr[1], 1);
      if (q < EQCAP){ eq_vals[q] = v; eq_idx[q] = cand_idx[i]; }
    }
  }
}

// ---------------- K3d: refine boundary bin + zero-fill + gather ---------------
__global__ __launch_bounds__(1024) void k3d_kernel(
    const int* hdr, const float* __restrict__ eq_vals, const int* __restrict__ eq_idx,
    float* sel_vals, int* sel_idx,
    const float* __restrict__ refp, const float* __restrict__ srcp,
    float* sel_ref, float* sel_src)
{
  __shared__ int hist[2048];
  __shared__ int eqsh[2048];
  __shared__ int wtot[16];
  __shared__ int bpair[2];
  __shared__ int sh[2];
  const int t = threadIdx.x, lane = t & 63, wv = t >> 6;
  const int bin1 = hdr[4];
  int nAbove = hdr[2]; if (nAbove > LIMIT) nAbove = LIMIT;

  auto find_boundary = [&](int need){
    int i0 = 2047 - 2*t, i1 = 2046 - 2*t;
    int g0 = hist[i0], g1 = hist[i1];
    int local = g0 + g1;
    int incl = local;
    for (int off = 1; off < 64; off <<= 1){ int y = __shfl_up(incl, off); if (lane >= off) incl += y; }
    if (lane == 63) wtot[wv] = incl;
    __syncthreads();
    int wbase = 0;
    for (int w = 0; w < wv; w++) wbase += wtot[w];
    int P_prev = wbase + incl - local;
    int P0 = P_prev + g0;
    if (P0 >= need && P_prev < need){ bpair[0] = i0; bpair[1] = need - P_prev; }
    int P1 = P0 + g1;
    if (P1 >= need && P0 < need){ bpair[0] = i1; bpair[1] = need - P0; }
    __syncthreads();
  };

  bool done = false;
  if (bin1 < 0){
    for (int i = t; i < LIMIT; i += 1024)
      if (i >= nAbove){ sel_vals[i] = 0.f; sel_idx[i] = 0; }
    done = true;
  }
  int neq = 0, need = 0;
  if (!done){
    neq = hdr[1]; if (neq > EQCAP) neq = EQCAP;
    need = hdr[5];
    if (need >= neq){
      for (int i = t; i < neq; i += 1024){ sel_vals[nAbove+i] = eq_vals[i]; sel_idx[nAbove+i] = eq_idx[i]; }
      for (int i = t; i < LIMIT; i += 1024)
        if (i >= nAbove + neq){ sel_vals[i] = 0.f; sel_idx[i] = 0; }
      done = true;
    }
  }
  if (!done){
    for (int i = t; i < 2048; i += 1024) hist[i] = 0;
    __syncthreads();
    for (int i = t; i < neq; i += 1024)
      atomicAdd(&hist[(__float_as_uint(eq_vals[i]) >> 9) & 0x7FF], 1);
    __syncthreads();
    find_boundary(need);
    int binA = bpair[0], need2 = bpair[1];
    __syncthreads();
    for (int i = t; i < 2048; i += 1024) hist[i] = 0;
    __syncthreads();
    for (int i = t; i < neq; i += 1024){
      unsigned k = __float_as_uint(eq_vals[i]);
      if ((int)((k >> 9) & 0x7FF) == binA) atomicAdd(&hist[k & 0x1FF], 1);
    }
    __syncthreads();
    find_boundary(need2);
    unsigned Tlow = (((unsigned)binA) << 9) | (unsigned)bpair[0];
    unsigned Tkey = (((unsigned)bin1) << 20) | Tlow;
    if (t == 0){ sh[0] = 0; sh[1] = 0; }
    __syncthreads();
    for (int i = t; i < neq; i += 1024){
      unsigned k = __float_as_uint(eq_vals[i]);
      unsigned k20 = k & 0xFFFFF;
      if (k20 > Tlow){
        int p = atomicAdd(&sh[0], 1);
        sel_vals[nAbove + p] = eq_vals[i]; sel_idx[nAbove + p] = eq_idx[i];
      } else if (k20 == Tlow){
        int q = atomicAdd(&sh[1], 1);
        if (q < 2048) eqsh[q] = eq_idx[i];
      }
    }
    __syncthreads();
    if (t == 0){
      int na2 = sh[0];
      int ne2 = sh[1]; if (ne2 > 2048) ne2 = 2048;
      int take = need - na2; if (take > ne2) take = ne2; if (take < 0) take = 0;
      if (nAbove + na2 + take > LIMIT) take = LIMIT - nAbove - na2;
      for (int j = 0; j < take; j++){
        int mi = j;
        for (int l2 = j+1; l2 < ne2; l2++) if (eqsh[l2] < eqsh[mi]) mi = l2;
        int tmp = eqsh[j]; eqsh[j] = eqsh[mi]; eqsh[mi] = tmp;
        sel_vals[nAbove + na2 + j] = __uint_as_float(Tkey);
        sel_idx[nAbove + na2 + j] = eqsh[j];
      }
      for (int j = nAbove + na2 + take; j < LIMIT; j++){ sel_vals[j] = 0.f; sel_idx[j] = 0; }
    }
  }
  __syncthreads();
  for (int p = t; p < LIMIT; p += 1024){
    int idx = sel_idx[p];
    int b = idx >> 14, rr = (idx >> 7) & 127, ss = idx & 127;
#pragma unroll
    for (int c = 0; c < 3; c++){
      sel_ref[p*3+c] = refp[(b*NN+rr)*3+c];
      sel_src[p*3+c] = srcp[(b*NN+ss)*3+c];
    }
  }
}

// ---------------- K4: per-batch inlier counts (no fences, no atomics) ---------
__global__ __launch_bounds__(256) void k4_kernel(
    const float* __restrict__ localT, const float* __restrict__ sel_vals,
    const float* __restrict__ sel_ref, const float* __restrict__ sel_src,
    const int* __restrict__ pcount, int* counts)
{
  __shared__ float Tsh[12];
  __shared__ int ired[4];
  const int b = blockIdx.x, t = threadIdx.x, lane = t & 63, wv = t >> 6;
  if (t < 12) Tsh[t] = localT[b*12 + t];
  __syncthreads();
  float R00=Tsh[0],R01=Tsh[1],R02=Tsh[2],R10=Tsh[3],R11=Tsh[4],R12=Tsh[5];
  float R20=Tsh[6],R21=Tsh[7],R22=Tsh[8];
  float tx=Tsh[9], ty=Tsh[10], tz=Tsh[11];
  int c = 0;
  for (int p = t; p < LIMIT; p += 256){
    float v = sel_vals[p];
    if (!(v > 0.f)) continue;
    float sx=sel_src[p*3], sy=sel_src[p*3+1], sz=sel_src[p*3+2];
    float rx=sel_ref[p*3], ry=sel_ref[p*3+1], rz=sel_ref[p*3+2];
    float ax = R00*sx + R01*sy + R02*sz + tx;
    float ay = R10*sx + R11*sy + R12*sz + ty;
    float az = R20*sx + R21*sy + R22*sz + tz;
    float dx = rx-ax, dy = ry-ay, dz = rz-az;
    if (sqrtf(dx*dx + dy*dy + dz*dz) < 0.1f) c++;
  }
  for (int off2 = 32; off2 > 0; off2 >>= 1) c += __shfl_down(c, off2);
  if (lane == 0) ired[wv] = c;
  __syncthreads();
  if (t == 0) counts[b] = (pcount[b] >= 3) ? (ired[0]+ired[1]+ired[2]+ired[3]) : -1;
}

// ---------------- K5: argmax best + 5x weighted Procrustes --------------------
__global__ __launch_bounds__(256, 1) void k5_kernel(
    const int* __restrict__ counts, const float* __restrict__ localT,
    const float* __restrict__ sel_vals, const float* __restrict__ sel_ref,
    const float* __restrict__ sel_src, float* out)
{
  __shared__ float fred[4][16];
  __shared__ long long lred[4];
  __shared__ float RT[12];
  __shared__ int sbest;
  const int t = threadIdx.x, lane = t & 63, wv = t >> 6;

  long long key = (long long)0x8000000000000000LL;
  for (int bb = t; bb < BB; bb += 256){
    long long kk = ((long long)(counts[bb] + 2) << 32) | (long long)(511 - bb);
    if (kk > key) key = kk;
  }
  for (int off2 = 32; off2 > 0; off2 >>= 1){ long long o = __shfl_down(key, off2); if (o > key) key = o; }
  if (lane == 0) lred[wv] = key;
  __syncthreads();
  if (t == 0){
    long long m = lred[0];
#pragma unroll
    for (int w = 1; w < 4; w++) if (lred[w] > m) m = lred[w];
    sbest = 511 - (int)(m & 0xFFFFFFFFLL);
  }
  __syncthreads();
  if (t < 12) RT[t] = localT[sbest*12 + t];
  __syncthreads();

  for (int iter = 0; iter < 5; iter++){
    float R00=RT[0],R01=RT[1],R02=RT[2];
    float R10=RT[3],R11=RT[4],R12=RT[5];
    float R20=RT[6],R21=RT[7],R22=RT[8];
    float tx=RT[9], ty=RT[10], tz=RT[11];
    float a0=0.f,a1=0.f,a2=0.f,a3=0.f,a4=0.f,a5=0.f,a6=0.f,a7=0.f;
    float a8=0.f,a9=0.f,a10=0.f,a11=0.f,a12=0.f,a13=0.f,a14=0.f,a15=0.f;
    for (int p = t; p < LIMIT; p += 256){
      float v = sel_vals[p];
      if (!(v > 0.f)) continue;
      float sx=sel_src[p*3], sy=sel_src[p*3+1], sz=sel_src[p*3+2];
      float rx=sel_ref[p*3], ry=sel_ref[p*3+1], rz=sel_ref[p*3+2];
      float ax = R00*sx + R01*sy + R02*sz + tx;
      float ay = R10*sx + R11*sy + R12*sz + ty;
      float az = R20*sx + R21*sy + R22*sz + tz;
      float dx = rx-ax, dy = ry-ay, dz = rz-az;
      if (sqrtf(dx*dx + dy*dy + dz*dz) < 0.1f){
        a0 += v;
        a1 += v*sx; a2 += v*sy; a3 += v*sz;
        a4 += v*rx; a5 += v*ry; a6 += v*rz;
        a7  += v*sx*rx; a8  += v*sx*ry; a9  += v*sx*rz;
        a10 += v*sy*rx; a11 += v*sy*ry; a12 += v*sy*rz;
        a13 += v*sz*rx; a14 += v*sz*ry; a15 += v*sz*rz;
      }
    }
#define WRED(VAL, IDX) { float v_ = (VAL); \
    for (int o_ = 32; o_ > 0; o_ >>= 1) v_ += __shfl_down(v_, o_); \
    if (lane == 0) fred[wv][IDX] = v_; }
    WRED(a0, 0)  WRED(a1, 1)  WRED(a2, 2)  WRED(a3, 3)
    WRED(a4, 4)  WRED(a5, 5)  WRED(a6, 6)  WRED(a7, 7)
    WRED(a8, 8)  WRED(a9, 9)  WRED(a10,10) WRED(a11,11)
    WRED(a12,12) WRED(a13,13) WRED(a14,14) WRED(a15,15)
#undef WRED
    __syncthreads();
    if (t == 0){
      float tot[16];
#pragma unroll
      for (int k = 0; k < 16; k++) tot[k] = fred[0][k]+fred[1][k]+fred[2][k]+fred[3][k];
      float W = tot[0], denom = W + 1e-5f;
      float inv = 1.f / denom;
      float s = W * inv;
      float scx = tot[1]*inv, scy = tot[2]*inv, scz = tot[3]*inv;
      float rcx = tot[4]*inv, rcy = tot[5]*inv, rcz = tot[6]*inv;
      float f = 2.f - s;
      float h00 = tot[7]*inv  - f*scx*rcx;
      float h01 = tot[8]*inv  - f*scx*rcy;
      float h02 = tot[9]*inv  - f*scx*rcz;
      float h10 = tot[10]*inv - f*scy*rcx;
      float h11 = tot[11]*inv - f*scy*rcy;
      float h12 = tot[12]*inv - f*scy*rcz;
      float h20 = tot[13]*inv - f*scz*rcx;
      float h21 = tot[14]*inv - f*scz*rcy;
      float h22 = tot[15]*inv - f*scz*rcz;
      float r00,r01,r02,r10,r11,r12,r20,r21,r22;
      kabsch9(h00,h01,h02,h10,h11,h12,h20,h21,h22,
              r00,r01,r02,r10,r11,r12,r20,r21,r22);
      RT[0]=r00; RT[1]=r01; RT[2]=r02;
      RT[3]=r10; RT[4]=r11; RT[5]=r12;
      RT[6]=r20; RT[7]=r21; RT[8]=r22;
      RT[9]  = rcx - (r00*scx + r01*scy + r02*scz);
      RT[10] = rcy - (r10*scx + r11*scy + r12*scz);
      RT[11] = rcz - (r20*scx + r21*scy + r22*scz);
    }
    __syncthreads();
  }
  if (t == 0){
    out[0]=RT[0];  out[1]=RT[1];  out[2]=RT[2];  out[3]=RT[9];
    out[4]=RT[3];  out[5]=RT[4];  out[6]=RT[5];  out[7]=RT[10];
    out[8]=RT[6];  out[9]=RT[7];  out[10]=RT[8]; out[11]=RT[11];
    out[12]=0.f; out[13]=0.f; out[14]=0.f; out[15]=1.f;
  }
}

// ---------------- host launcher -----------------------------------------------
extern "C" void kernel_launch(void* const* d_in, const int* in_sizes, int n_in,
                              void* d_out, int out_size, void* d_ws, size_t ws_size,
                              hipStream_t stream){
  const float* score = (const float*)d_in[0];
  const float* refp  = (const float*)d_in[1];
  const float* srcp  = (const float*)d_in[2];
  const void*  rmask = d_in[3];
  const void*  smask = d_in[4];

  char* ws = (char*)d_ws;
  size_t off = 0;
  int* hdr = (int*)(ws + off);            off += 256;
  int* hist = (int*)(ws + off);           off += (size_t)NBIN1*4;
  float* cand_vals = (float*)(ws + off);  off += (size_t)CAND_CAP*4;
  int* cand_idx = (int*)(ws + off);       off += (size_t)CAND_CAP*4;
  float* eq_vals = (float*)(ws + off);    off += (size_t)EQCAP*4;
  int* eq_idx = (int*)(ws + off);         off += (size_t)EQCAP*4;
  float* Hsr = (float*)(ws + off);        off += (size_t)BB*15*4;
  int* pcount = (int*)(ws + off);         off += (size_t)BB*4;
  float* localT = (float*)(ws + off);     off += (size_t)BB*12*4;
  float* sel_vals = (float*)(ws + off);   off += (size_t)LIMIT*4;
  int* sel_idx = (int*)(ws + off);        off += (size_t)LIMIT*4;
  float* sel_ref = (float*)(ws + off);    off += (size_t)LIMIT*3*4;
  float* sel_src = (float*)(ws + off);    off += (size_t)LIMIT*3*4;
  int* counts = (int*)(ws + off);         off += (size_t)BB*4;

  hipMemsetAsync(ws, 0, 256 + (size_t)NBIN1*4, stream);
  hipLaunchKernelGGL(k1_kernel, dim3(BB), dim3(256), 0, stream,
                     score, refp, srcp, rmask, smask,
                     hdr, cand_vals, cand_idx, Hsr, pcount);
  hipLaunchKernelGGL(k3a_kernel, dim3(64), dim3(256), 0, stream, hdr, cand_vals, hist);
  hipLaunchKernelGGL(k3c_kernel, dim3(64), dim3(256), 0, stream,
                     hdr, hist, cand_vals, cand_idx, Hsr, localT,
                     sel_vals, sel_idx, eq_vals, eq_idx);
  hipLaunchKernelGGL(k3d_kernel, dim3(1), dim3(1024), 0, stream,
                     hdr, eq_vals, eq_idx, sel_vals, sel_idx, refp, srcp, sel_ref, sel_src);
  hipLaunchKernelGGL(k4_kernel, dim3(BB), dim3(256), 0, stream,
                     localT, sel_vals, sel_ref, sel_src, pcount, counts);
  hipLaunchKernelGGL(k5_kernel, dim3(1), dim3(256), 0, stream,
                     counts, localT, sel_vals, sel_ref, sel_src, (float*)d_out);
}